// Round 9
// baseline (340.541 us; speedup 1.0000x reference)
//
#include <hip/hip_runtime.h>
#include <hip/hip_bf16.h>
#include <math.h>

#define L_DIM 1024
#define DM 1024
#define DI 2048
#define NS 64

typedef __attribute__((ext_vector_type(8))) short short8;
typedef __attribute__((ext_vector_type(4))) float f32x4;

// round-to-nearest-even f32 -> bf16 bits
__device__ __forceinline__ ushort bf16u(float f)
{
    unsigned u = __float_as_uint(f);
    unsigned r = (u + 0x7fffu + ((u >> 16) & 1u)) >> 16;
    return (ushort)r;
}

__device__ __forceinline__ void gld16(const ushort* g, const ushort* l)
{
    __builtin_amdgcn_global_load_lds(
        (const __attribute__((address_space(1))) unsigned int*)g,
        (__attribute__((address_space(3))) unsigned int*)l, 16, 0, 0);
}

// ---------------- RMSNorm row factors ----------------------------------------
__global__ __launch_bounds__(256) void k_rmsfac(const float* __restrict__ x,
                                                float* __restrict__ rinv)
{
    int row = blockIdx.x;
    float4 v = ((const float4*)(x + (size_t)row * DM))[threadIdx.x];
    float ss = v.x*v.x + v.y*v.y + v.z*v.z + v.w*v.w;
    #pragma unroll
    for (int m = 32; m; m >>= 1) ss += __shfl_xor(ss, m, 64);
    __shared__ float red[4];
    if ((threadIdx.x & 63) == 0) red[threadIdx.x >> 6] = ss;
    __syncthreads();
    if (threadIdx.x == 0) {
        float tot = red[0] + red[1] + red[2] + red[3];
        rinv[row] = rsqrtf(tot * (1.0f / DM) + 1e-6f);
    }
}

// ---------------- generic f32 -> bf16 cast (8 elems/thread) ------------------
__global__ __launch_bounds__(256) void k_cast(const float* __restrict__ s,
                                              ushort* __restrict__ d, int n8)
{
    int i = blockIdx.x * 256 + threadIdx.x;
    if (i >= n8) return;
    float4 a = ((const float4*)s)[2*i], b = ((const float4*)s)[2*i+1];
    ((ushort4*)d)[2*i]   = make_ushort4(bf16u(a.x), bf16u(a.y), bf16u(a.z), bf16u(a.w));
    ((ushort4*)d)[2*i+1] = make_ushort4(bf16u(b.x), bf16u(b.y), bf16u(b.z), bf16u(b.w));
}

// ---------------- xn = bf16(x * rinv[row] * norm_w[k])  [2048][1024] ---------
__global__ __launch_bounds__(256) void k_cast_xn(const float* __restrict__ x,
    const float* __restrict__ rinv, const float* __restrict__ nw,
    ushort* __restrict__ d)
{
    int i = blockIdx.x * 256 + threadIdx.x;      // 262144 total
    int row = i >> 7, cb = (i & 127) * 8;
    float ri = rinv[row];
    const float* xp = x + (size_t)row * DM + cb;
    float4 a = *(const float4*)xp, b = *(const float4*)(xp + 4);
    float4 wa = *(const float4*)(nw + cb), wb = *(const float4*)(nw + cb + 4);
    ushort* dp = d + (size_t)row * DM + cb;
    *(ushort4*)dp = make_ushort4(bf16u(a.x*ri*wa.x), bf16u(a.y*ri*wa.y),
                                 bf16u(a.z*ri*wa.z), bf16u(a.w*ri*wa.w));
    *(ushort4*)(dp+4) = make_ushort4(bf16u(b.x*ri*wb.x), bf16u(b.y*ri*wb.y),
                                     bf16u(b.z*ri*wb.z), bf16u(b.w*ri*wb.w));
}

// ---------------- MFMA NT GEMM: C[m][n] = sum_k A[m][k]*Bw[n][k] -------------
template<int MODE>
__global__ __launch_bounds__(256) void k_mfma(
    const ushort* __restrict__ Abf, const ushort* __restrict__ Bbf0,
    const ushort* __restrict__ Bbf1, float* __restrict__ C0,
    float* __restrict__ C1, const float* __restrict__ bias,
    const float* __restrict__ skip, int Kdim, int ldc)
{
    __shared__ __align__(16) ushort As[128*32];
    __shared__ __align__(16) ushort Bs[128*32];
    const int t = threadIdx.x, w = t >> 6, lane = t & 63;
    const int nt = blockIdx.x, mt = blockIdx.y;
    const int mBase = mt * 128, nBase = nt * 128;
    const bool isXP = (MODE == 1) && (nt == 16);
    const ushort* __restrict__ Bbf = isXP ? Bbf1 : Bbf0;
    const int wr = (w >> 1) * 64, wc = (w & 1) * 64;
    const int sR = lane >> 2, sK = (lane & 3) * 8;

    f32x4 acc[4][4];
    #pragma unroll
    for (int i = 0; i < 4; ++i)
        #pragma unroll
        for (int j = 0; j < 4; ++j)
            acc[i][j] = (f32x4){0.f, 0.f, 0.f, 0.f};

    for (int kt = 0; kt < Kdim; kt += 32) {
        #pragma unroll
        for (int s = 0; s < 2; ++s) {
            int tr = w*32 + s*16 + sR;
            gld16(Abf + (size_t)(mBase + tr) * Kdim + kt + sK,
                  As + (w*32 + s*16) * 32);
            int gr = isXP ? (tr < 63 ? tr : 63) : (nBase + tr);
            gld16(Bbf + (size_t)gr * Kdim + kt + sK,
                  Bs + (w*32 + s*16) * 32);
        }
        __syncthreads();
        short8 af[4], bfr[4];
        #pragma unroll
        for (int f = 0; f < 4; ++f) {
            af[f]  = *(const short8*)(As + (wr + f*16 + (lane & 15))*32 + (lane >> 4)*8);
            bfr[f] = *(const short8*)(Bs + (wc + f*16 + (lane & 15))*32 + (lane >> 4)*8);
        }
        #pragma unroll
        for (int mi = 0; mi < 4; ++mi)
            #pragma unroll
            for (int ni = 0; ni < 4; ++ni)
                acc[mi][ni] = __builtin_amdgcn_mfma_f32_16x16x32_bf16(
                    af[mi], bfr[ni], acc[mi][ni], 0, 0, 0);
        __syncthreads();
    }

    const int rb = (lane >> 4) * 4, cbl = lane & 15;
    #pragma unroll
    for (int mi = 0; mi < 4; ++mi) {
        #pragma unroll
        for (int ni = 0; ni < 4; ++ni) {
            int ltcol = wc + ni*16 + cbl;
            int col = nBase + ltcol;
            #pragma unroll
            for (int j = 0; j < 4; ++j) {
                int row = mBase + wr + mi*16 + rb + j;
                float v = acc[mi][ni][j];
                if constexpr (MODE == 0) {
                    C0[(size_t)row * ldc + col] = v;
                } else if constexpr (MODE == 1) {
                    if (isXP) {
                        if (ltcol < NS) C1[(size_t)row * NS + ltcol] = v;
                    } else {
                        float z = v + bias[col];
                        C0[(size_t)row * ldc + col] =
                            (z > 20.f) ? z : logf(1.f + expf(z));
                    }
                } else {
                    C0[(size_t)row * ldc + col] = v + skip[(size_t)row * ldc + col];
                }
            }
        }
    }
}

// ---------------- causal depthwise conv1d (K=4) + SiLU, f32 + bf16 out -------
__global__ __launch_bounds__(256) void k_conv(const float* __restrict__ xr,
    const float* __restrict__ cw, const float* __restrict__ cb,
    float* __restrict__ xc, ushort* __restrict__ xcb)
{
    int gid = blockIdx.x * 256 + threadIdx.x;      // [0, 2*1024*512)
    int d = (gid & 511) * 4;
    int tt = (gid >> 9) & 1023;
    int b = gid >> 19;
    float4 w[4];
    #pragma unroll
    for (int c = 0; c < 4; ++c) w[c] = *(const float4*)(cw + (size_t)(d + c) * 4);
    float4 acc = *(const float4*)(cb + d);
    const float* base = xr + (size_t)b * L_DIM * (2*DI) + d;
    #pragma unroll
    for (int j = 0; j < 4; ++j) {
        int ti = tt - 3 + j;
        if (ti < 0) continue;
        float4 xv = *(const float4*)(base + (size_t)ti * (2*DI));
        const float* w0 = (const float*)&w[0];
        const float* w1 = (const float*)&w[1];
        const float* w2 = (const float*)&w[2];
        const float* w3 = (const float*)&w[3];
        acc.x = fmaf(w0[j], xv.x, acc.x);
        acc.y = fmaf(w1[j], xv.y, acc.y);
        acc.z = fmaf(w2[j], xv.z, acc.z);
        acc.w = fmaf(w3[j], xv.w, acc.w);
    }
    acc.x = acc.x / (1.f + expf(-acc.x));
    acc.y = acc.y / (1.f + expf(-acc.y));
    acc.z = acc.z / (1.f + expf(-acc.z));
    acc.w = acc.w / (1.f + expf(-acc.w));
    size_t o = (size_t)(b * L_DIM + tt) * DI + d;
    *(float4*)(xc + o) = acc;
    *(ushort4*)(xcb + o) = make_ushort4(bf16u(acc.x), bf16u(acc.y),
                                        bf16u(acc.z), bf16u(acc.w));
}

// ---------------- tiled transpose: dst[c][r] = src[r][c], batched ------------
__global__ __launch_bounds__(256) void k_tr(const float* __restrict__ src,
    float* __restrict__ dst, int srs, int drs, size_t sB, size_t dB)
{
    __shared__ float tile[64][65];
    const int r0 = blockIdx.y * 64, c0 = blockIdx.x * 64;
    const float* s = src + blockIdx.z * sB;
    float* d = dst + blockIdx.z * dB;
    const int tx = threadIdx.x & 15, ty = threadIdx.x >> 4;
    #pragma unroll
    for (int p = 0; p < 4; ++p) {
        float4 v = *(const float4*)(s + (size_t)(r0 + ty + p*16) * srs + c0 + tx*4);
        tile[ty + p*16][tx*4+0] = v.x; tile[ty + p*16][tx*4+1] = v.y;
        tile[ty + p*16][tx*4+2] = v.z; tile[ty + p*16][tx*4+3] = v.w;
    }
    __syncthreads();
    #pragma unroll
    for (int p = 0; p < 4; ++p) {
        int oc = ty + p*16;
        float4 v = make_float4(tile[tx*4+0][oc], tile[tx*4+1][oc],
                               tile[tx*4+2][oc], tile[tx*4+3][oc]);
        *(float4*)(d + (size_t)(c0 + oc) * drs + r0 + tx*4) = v;
    }
}

// ------ back-transpose yt[b][d][t] -> y_bf[b*t][d], fused silu(res) gate -----
__global__ __launch_bounds__(256) void k_trg(const float* __restrict__ yt,
    const float* __restrict__ xr, ushort* __restrict__ ybf)
{
    __shared__ float tile[64][65];
    const int r0 = blockIdx.y * 64, c0 = blockIdx.x * 64;   // r=d, c=t
    const int z = blockIdx.z;
    const float* s = yt + (size_t)z * DI * L_DIM;
    const int tx = threadIdx.x & 15, ty = threadIdx.x >> 4;
    #pragma unroll
    for (int p = 0; p < 4; ++p) {
        float4 v = *(const float4*)(s + (size_t)(r0 + ty + p*16) * L_DIM + c0 + tx*4);
        tile[ty + p*16][tx*4+0] = v.x; tile[ty + p*16][tx*4+1] = v.y;
        tile[ty + p*16][tx*4+2] = v.z; tile[ty + p*16][tx*4+3] = v.w;
    }
    __syncthreads();
    #pragma unroll
    for (int p = 0; p < 4; ++p) {
        int oc = ty + p*16;                       // local t index
        int row = z * L_DIM + c0 + oc;            // global (b*t) row
        float4 v = make_float4(tile[tx*4+0][oc], tile[tx*4+1][oc],
                               tile[tx*4+2][oc], tile[tx*4+3][oc]);
        float4 g = *(const float4*)(xr + (size_t)row * (2*DI) + DI + r0 + tx*4);
        v.x *= g.x / (1.f + expf(-g.x));
        v.y *= g.y / (1.f + expf(-g.y));
        v.z *= g.z / (1.f + expf(-g.z));
        v.w *= g.w / (1.f + expf(-g.w));
        *(ushort4*)(ybf + (size_t)row * DI + r0 + tx*4) =
            make_ushort4(bf16u(v.x), bf16u(v.y), bf16u(v.z), bf16u(v.w));
    }
}

// ---------------- selective scan v7: fully hand-scheduled 4-step group -------
// One asm block per 4 steps: 8 readlane -> 4 mul -> 4 v_exp -> 4 p-mul ->
// fma/mov chain -> 24 DPP (4 interleaved chains) -> 4 rl63 -> 4 writelane.
// All mandatory hazards (SGPR-read gap, TRANS->use, VGPR-write->DPP-read)
// satisfied by instruction spacing; zero s_nops. Temps in clobbered
// v40-v51 / s24-s35 to keep operand count low.
__global__ __launch_bounds__(256) void k_scan7(const float* __restrict__ dtt,
    const float* __restrict__ xct, const float* __restrict__ Bss,
    const float* __restrict__ A_log, const float* __restrict__ Dp,
    float* __restrict__ yt)
{
    __shared__ float Bsh[64][68];
    const int lane = threadIdx.x & 63;
    const int widx = threadIdx.x >> 6;
    const int b = blockIdx.x >> 9;
    const int d = (blockIdx.x & 511) * 4 + widx;
    const float aL2 = -expf(A_log[(size_t)d * NS + lane]) * 1.44269504f;
    const float Dv = Dp[d];
    const float* dtp = dtt + ((size_t)b * DI + d) * L_DIM;
    const float* xcp = xct + ((size_t)b * DI + d) * L_DIM;
    const float* Bp  = Bss + (size_t)b * L_DIM * NS;
    float* yp = yt + ((size_t)b * DI + d) * L_DIM;
    const int lr = threadIdx.x >> 2;
    const int lc = (threadIdx.x & 3) * 16;
    float h = 0.f;

    for (int t0 = 0; t0 < L_DIM; t0 += 64) {
        const float* bsrc = Bp + (size_t)(t0 + lr) * NS + lc;
        float4 b0 = *(const float4*)(bsrc);
        float4 b1 = *(const float4*)(bsrc + 4);
        float4 b2 = *(const float4*)(bsrc + 8);
        float4 b3 = *(const float4*)(bsrc + 12);
        float dt_v = dtp[t0 + lane];
        float xc_v = xcp[t0 + lane];
        __syncthreads();
        *(float4*)&Bsh[lr][lc]      = b0;
        *(float4*)&Bsh[lr][lc + 4]  = b1;
        *(float4*)&Bsh[lr][lc + 8]  = b2;
        *(float4*)&Bsh[lr][lc + 12] = b3;
        __syncthreads();
        float y_v = 0.f;
        #pragma unroll
        for (int q = 0; q < 64; q += 4) {
            float bq0 = Bsh[q+0][lane];
            float bq1 = Bsh[q+1][lane];
            float bq2 = Bsh[q+2][lane];
            float bq3 = Bsh[q+3][lane];
            asm volatile(
                "v_readlane_b32 s24, %3, %9\n\t"
                "v_readlane_b32 s28, %4, %9\n\t"
                "v_readlane_b32 s25, %3, %10\n\t"
                "v_readlane_b32 s29, %4, %10\n\t"
                "v_readlane_b32 s26, %3, %11\n\t"
                "v_readlane_b32 s30, %4, %11\n\t"
                "v_readlane_b32 s27, %3, %12\n\t"
                "v_readlane_b32 s31, %4, %12\n\t"
                "v_mul_f32 v44, s24, %2\n\t"
                "v_mul_f32 v45, s25, %2\n\t"
                "v_mul_f32 v46, s26, %2\n\t"
                "v_mul_f32 v47, s27, %2\n\t"
                "v_exp_f32 v44, v44\n\t"
                "v_exp_f32 v45, v45\n\t"
                "v_exp_f32 v46, v46\n\t"
                "v_exp_f32 v47, v47\n\t"
                "v_mul_f32 v48, s28, %5\n\t"
                "v_mul_f32 v49, s29, %6\n\t"
                "v_mul_f32 v50, s30, %7\n\t"
                "v_mul_f32 v51, s31, %8\n\t"
                "v_fma_f32 %0, v44, %0, v48\n\t"
                "v_mov_b32 v40, %0\n\t"
                "v_fma_f32 %0, v45, %0, v49\n\t"
                "v_mov_b32 v41, %0\n\t"
                "v_fma_f32 %0, v46, %0, v50\n\t"
                "v_mov_b32 v42, %0\n\t"
                "v_fma_f32 %0, v47, %0, v51\n\t"
                "v_mov_b32 v43, %0\n\t"
                "v_add_f32_dpp v40, v40, v40 row_shr:1 row_mask:0xf bank_mask:0xf\n\t"
                "v_add_f32_dpp v41, v41, v41 row_shr:1 row_mask:0xf bank_mask:0xf\n\t"
                "v_add_f32_dpp v42, v42, v42 row_shr:1 row_mask:0xf bank_mask:0xf\n\t"
                "v_add_f32_dpp v43, v43, v43 row_shr:1 row_mask:0xf bank_mask:0xf\n\t"
                "v_add_f32_dpp v40, v40, v40 row_shr:2 row_mask:0xf bank_mask:0xf\n\t"
                "v_add_f32_dpp v41, v41, v41 row_shr:2 row_mask:0xf bank_mask:0xf\n\t"
                "v_add_f32_dpp v42, v42, v42 row_shr:2 row_mask:0xf bank_mask:0xf\n\t"
                "v_add_f32_dpp v43, v43, v43 row_shr:2 row_mask:0xf bank_mask:0xf\n\t"
                "v_add_f32_dpp v40, v40, v40 row_shr:4 row_mask:0xf bank_mask:0xf\n\t"
                "v_add_f32_dpp v41, v41, v41 row_shr:4 row_mask:0xf bank_mask:0xf\n\t"
                "v_add_f32_dpp v42, v42, v42 row_shr:4 row_mask:0xf bank_mask:0xf\n\t"
                "v_add_f32_dpp v43, v43, v43 row_shr:4 row_mask:0xf bank_mask:0xf\n\t"
                "v_add_f32_dpp v40, v40, v40 row_shr:8 row_mask:0xf bank_mask:0xf\n\t"
                "v_add_f32_dpp v41, v41, v41 row_shr:8 row_mask:0xf bank_mask:0xf\n\t"
                "v_add_f32_dpp v42, v42, v42 row_shr:8 row_mask:0xf bank_mask:0xf\n\t"
                "v_add_f32_dpp v43, v43, v43 row_shr:8 row_mask:0xf bank_mask:0xf\n\t"
                "v_add_f32_dpp v40, v40, v40 row_bcast:15 row_mask:0xa bank_mask:0xf\n\t"
                "v_add_f32_dpp v41, v41, v41 row_bcast:15 row_mask:0xa bank_mask:0xf\n\t"
                "v_add_f32_dpp v42, v42, v42 row_bcast:15 row_mask:0xa bank_mask:0xf\n\t"
                "v_add_f32_dpp v43, v43, v43 row_bcast:15 row_mask:0xa bank_mask:0xf\n\t"
                "v_add_f32_dpp v40, v40, v40 row_bcast:31 row_mask:0xc bank_mask:0xf\n\t"
                "v_add_f32_dpp v41, v41, v41 row_bcast:31 row_mask:0xc bank_mask:0xf\n\t"
                "v_add_f32_dpp v42, v42, v42 row_bcast:31 row_mask:0xc bank_mask:0xf\n\t"
                "v_add_f32_dpp v43, v43, v43 row_bcast:31 row_mask:0xc bank_mask:0xf\n\t"
                "v_readlane_b32 s32, v40, 63\n\t"
                "v_readlane_b32 s33, v41, 63\n\t"
                "v_readlane_b32 s34, v42, 63\n\t"
                "v_readlane_b32 s35, v43, 63\n\t"
                "v_writelane_b32 %1, s32, %9\n\t"
                "v_writelane_b32 %1, s33, %10\n\t"
                "v_writelane_b32 %1, s34, %11\n\t"
                "v_writelane_b32 %1, s35, %12"
                : "+v"(h), "+v"(y_v)
                : "v"(aL2), "v"(dt_v), "v"(xc_v),
                  "v"(bq0), "v"(bq1), "v"(bq2), "v"(bq3),
                  "i"(q+0), "i"(q+1), "i"(q+2), "i"(q+3)
                : "v40","v41","v42","v43","v44","v45","v46","v47",
                  "v48","v49","v50","v51",
                  "s24","s25","s26","s27","s28","s29","s30","s31",
                  "s32","s33","s34","s35");
        }
        yp[t0 + lane] = fmaf(Dv, xc_v, y_v);
    }
}

extern "C" void kernel_launch(void* const* d_in, const int* in_sizes, int n_in,
                              void* d_out, int out_size, void* d_ws, size_t ws_size,
                              hipStream_t stream)
{
    const float* x        = (const float*)d_in[0];
    const float* norm_w   = (const float*)d_in[1];
    const float* in_projw = (const float*)d_in[2];
    const float* conv_w   = (const float*)d_in[3];
    const float* conv_b   = (const float*)d_in[4];
    const float* x_projw  = (const float*)d_in[5];
    const float* dt_w     = (const float*)d_in[6];
    const float* dt_b     = (const float*)d_in[7];
    const float* A_log    = (const float*)d_in[8];
    const float* D_param  = (const float*)d_in[9];
    const float* out_projw= (const float*)d_in[10];
    float* out = (float*)d_out;

    float* ws   = (float*)d_ws;
    float* rinv = ws;                               // 4096 (pad)
    float* xr   = rinv + 4096;                      // 8M f32
    float* xc   = xr + (size_t)8*1024*1024;         // 4M f32
    float* dtb  = xc + (size_t)4*1024*1024;         // 4M f32 (yt alias)
    float* Bss  = dtb + (size_t)4*1024*1024;        // 128K f32
    float* dtt  = Bss + 131072;                     // 4M f32
    float* xct  = dtt + (size_t)4*1024*1024;        // 4M f32
    ushort* xn_bf  = (ushort*)(xct + (size_t)4*1024*1024); // 2M u16
    ushort* xc_bf  = xn_bf + (size_t)2*1024*1024;          // 4M u16
    ushort* xpw_bf = xc_bf + (size_t)4*1024*1024;          // 128K u16
    // aliases into dead regions:
    ushort* inpw_bf = (ushort*)dtt;   // dead before dtt written
    ushort* dtw_bf  = (ushort*)xct;   // dead before xct written
    ushort* opw_bf  = xn_bf;          // xn dead after GEMM0
    ushort* y_bf    = (ushort*)xc;    // xc dead after transpose
    float* yt = dtb;

    k_rmsfac<<<2048, 256, 0, stream>>>(x, rinv);
    k_cast_xn<<<1024, 256, 0, stream>>>(x, rinv, norm_w, xn_bf);
    k_cast<<<2048, 256, 0, stream>>>(in_projw, inpw_bf, 524288);
    k_mfma<0><<<dim3(32, 16), 256, 0, stream>>>(xn_bf, inpw_bf, nullptr,
                                                xr, nullptr, nullptr, nullptr, 1024, 4096);
    k_conv<<<4096, 256, 0, stream>>>(xr, conv_w, conv_b, xc, xc_bf);
    k_cast<<<2048, 256, 0, stream>>>(dt_w, dtw_bf, 524288);
    k_cast<<<64, 256, 0, stream>>>(x_projw + (size_t)64*2048, xpw_bf, 16384);
    k_mfma<1><<<dim3(17, 16), 256, 0, stream>>>(xc_bf, dtw_bf, xpw_bf,
                                                dtb, Bss, dt_b, nullptr, 2048, 2048);
    k_tr<<<dim3(32, 16, 2), 256, 0, stream>>>(dtb, dtt, DI, L_DIM,
                                              (size_t)L_DIM*DI, (size_t)DI*L_DIM);
    k_tr<<<dim3(32, 16, 2), 256, 0, stream>>>(xc, xct, DI, L_DIM,
                                              (size_t)L_DIM*DI, (size_t)DI*L_DIM);
    k_scan7<<<1024, 256, 0, stream>>>(dtt, xct, Bss, A_log, D_param, yt);
    k_cast<<<1024, 256, 0, stream>>>(out_projw, opw_bf, 262144);
    k_trg<<<dim3(16, 32, 2), 256, 0, stream>>>(yt, xr, y_bf);
    k_mfma<2><<<dim3(8, 16), 256, 0, stream>>>(y_bf, opw_bf, nullptr,
                                               out, nullptr, nullptr, x, 2048, 1024);
}

// Round 10
// 321.384 us; speedup vs baseline: 1.0596x; 1.0596x over previous
//
#include <hip/hip_runtime.h>
#include <hip/hip_bf16.h>
#include <math.h>

#define L_DIM 1024
#define DM 1024
#define DI 2048
#define NS 64

typedef __attribute__((ext_vector_type(8))) short short8;
typedef __attribute__((ext_vector_type(4))) float f32x4;

// round-to-nearest-even f32 -> bf16 bits
__device__ __forceinline__ ushort bf16u(float f)
{
    unsigned u = __float_as_uint(f);
    unsigned r = (u + 0x7fffu + ((u >> 16) & 1u)) >> 16;
    return (ushort)r;
}

__device__ __forceinline__ void gld16(const ushort* g, const ushort* l)
{
    __builtin_amdgcn_global_load_lds(
        (const __attribute__((address_space(1))) unsigned int*)g,
        (__attribute__((address_space(3))) unsigned int*)l, 16, 0, 0);
}

// -------- fused RMSNorm + bf16 cast: xn = bf16(x*rinv[row]*norm_w[k]) --------
__global__ __launch_bounds__(256) void k_rms_xn(const float* __restrict__ x,
    const float* __restrict__ nw, ushort* __restrict__ d)
{
    int row = blockIdx.x;
    const float* xp = x + (size_t)row * DM;
    float4 v = ((const float4*)xp)[threadIdx.x];
    float ss = v.x*v.x + v.y*v.y + v.z*v.z + v.w*v.w;
    #pragma unroll
    for (int m = 32; m; m >>= 1) ss += __shfl_xor(ss, m, 64);
    __shared__ float red[4];
    if ((threadIdx.x & 63) == 0) red[threadIdx.x >> 6] = ss;
    __syncthreads();
    float tot = red[0] + red[1] + red[2] + red[3];
    float ri = rsqrtf(tot * (1.0f / DM) + 1e-6f);
    float4 wv = ((const float4*)nw)[threadIdx.x];
    ((ushort4*)(d + (size_t)row * DM))[threadIdx.x] =
        make_ushort4(bf16u(v.x*ri*wv.x), bf16u(v.y*ri*wv.y),
                     bf16u(v.z*ri*wv.z), bf16u(v.w*ri*wv.w));
}

// ---------------- all weight casts in ONE dispatch ---------------------------
__device__ __forceinline__ void cast8(const float* __restrict__ s,
                                      ushort* __restrict__ d, int i)
{
    float4 a = ((const float4*)s)[2*i], b = ((const float4*)s)[2*i+1];
    ((ushort4*)d)[2*i]   = make_ushort4(bf16u(a.x), bf16u(a.y), bf16u(a.z), bf16u(a.w));
    ((ushort4*)d)[2*i+1] = make_ushort4(bf16u(b.x), bf16u(b.y), bf16u(b.z), bf16u(b.w));
}
__global__ __launch_bounds__(256) void k_castw(
    const float* __restrict__ s0, ushort* __restrict__ d0,   // in_projw 524288*8
    const float* __restrict__ s1, ushort* __restrict__ d1,   // dt_w     524288*8
    const float* __restrict__ s2, ushort* __restrict__ d2,   // x_projw  16384*8
    const float* __restrict__ s3, ushort* __restrict__ d3)   // out_projw 262144*8
{
    int i = blockIdx.x * 256 + threadIdx.x;                  // < 1327104
    if (i < 524288)       cast8(s0, d0, i);
    else if (i < 1048576) cast8(s1, d1, i - 524288);
    else if (i < 1064960) cast8(s2, d2, i - 1048576);
    else                  cast8(s3, d3, i - 1064960);
}

// ---------------- MFMA NT GEMM: C[m][n] = sum_k A[m][k]*Bw[n][k] -------------
template<int MODE>
__global__ __launch_bounds__(256) void k_mfma(
    const ushort* __restrict__ Abf, const ushort* __restrict__ Bbf0,
    const ushort* __restrict__ Bbf1, float* __restrict__ C0,
    float* __restrict__ C1, const float* __restrict__ bias,
    const float* __restrict__ skip, int Kdim, int ldc)
{
    __shared__ __align__(16) ushort As[128*32];
    __shared__ __align__(16) ushort Bs[128*32];
    const int t = threadIdx.x, w = t >> 6, lane = t & 63;
    const int nt = blockIdx.x, mt = blockIdx.y;
    const int mBase = mt * 128, nBase = nt * 128;
    const bool isXP = (MODE == 1) && (nt == 16);
    const ushort* __restrict__ Bbf = isXP ? Bbf1 : Bbf0;
    const int wr = (w >> 1) * 64, wc = (w & 1) * 64;
    const int sR = lane >> 2, sK = (lane & 3) * 8;

    f32x4 acc[4][4];
    #pragma unroll
    for (int i = 0; i < 4; ++i)
        #pragma unroll
        for (int j = 0; j < 4; ++j)
            acc[i][j] = (f32x4){0.f, 0.f, 0.f, 0.f};

    for (int kt = 0; kt < Kdim; kt += 32) {
        #pragma unroll
        for (int s = 0; s < 2; ++s) {
            int tr = w*32 + s*16 + sR;
            gld16(Abf + (size_t)(mBase + tr) * Kdim + kt + sK,
                  As + (w*32 + s*16) * 32);
            int gr = isXP ? (tr < 63 ? tr : 63) : (nBase + tr);
            gld16(Bbf + (size_t)gr * Kdim + kt + sK,
                  Bs + (w*32 + s*16) * 32);
        }
        __syncthreads();
        short8 af[4], bfr[4];
        #pragma unroll
        for (int f = 0; f < 4; ++f) {
            af[f]  = *(const short8*)(As + (wr + f*16 + (lane & 15))*32 + (lane >> 4)*8);
            bfr[f] = *(const short8*)(Bs + (wc + f*16 + (lane & 15))*32 + (lane >> 4)*8);
        }
        #pragma unroll
        for (int mi = 0; mi < 4; ++mi)
            #pragma unroll
            for (int ni = 0; ni < 4; ++ni)
                acc[mi][ni] = __builtin_amdgcn_mfma_f32_16x16x32_bf16(
                    af[mi], bfr[ni], acc[mi][ni], 0, 0, 0);
        __syncthreads();
    }

    const int rb = (lane >> 4) * 4, cbl = lane & 15;
    #pragma unroll
    for (int mi = 0; mi < 4; ++mi) {
        #pragma unroll
        for (int ni = 0; ni < 4; ++ni) {
            int ltcol = wc + ni*16 + cbl;
            int col = nBase + ltcol;
            #pragma unroll
            for (int j = 0; j < 4; ++j) {
                int row = mBase + wr + mi*16 + rb + j;
                float v = acc[mi][ni][j];
                if constexpr (MODE == 0) {
                    C0[(size_t)row * ldc + col] = v;
                } else if constexpr (MODE == 1) {
                    if (isXP) {
                        if (ltcol < NS) C1[(size_t)row * NS + ltcol] = v;
                    } else {
                        float z = v + bias[col];
                        C0[(size_t)row * ldc + col] =
                            (z > 20.f) ? z : logf(1.f + expf(z));
                    }
                } else {
                    C0[(size_t)row * ldc + col] = v + skip[(size_t)row * ldc + col];
                }
            }
        }
    }
}

// ---------------- causal depthwise conv1d (K=4) + SiLU, f32 + bf16 out -------
__global__ __launch_bounds__(256) void k_conv(const float* __restrict__ xr,
    const float* __restrict__ cw, const float* __restrict__ cb,
    float* __restrict__ xc, ushort* __restrict__ xcb)
{
    int gid = blockIdx.x * 256 + threadIdx.x;      // [0, 2*1024*512)
    int d = (gid & 511) * 4;
    int tt = (gid >> 9) & 1023;
    int b = gid >> 19;
    float4 w[4];
    #pragma unroll
    for (int c = 0; c < 4; ++c) w[c] = *(const float4*)(cw + (size_t)(d + c) * 4);
    float4 acc = *(const float4*)(cb + d);
    const float* base = xr + (size_t)b * L_DIM * (2*DI) + d;
    #pragma unroll
    for (int j = 0; j < 4; ++j) {
        int ti = tt - 3 + j;
        if (ti < 0) continue;
        float4 xv = *(const float4*)(base + (size_t)ti * (2*DI));
        const float* w0 = (const float*)&w[0];
        const float* w1 = (const float*)&w[1];
        const float* w2 = (const float*)&w[2];
        const float* w3 = (const float*)&w[3];
        acc.x = fmaf(w0[j], xv.x, acc.x);
        acc.y = fmaf(w1[j], xv.y, acc.y);
        acc.z = fmaf(w2[j], xv.z, acc.z);
        acc.w = fmaf(w3[j], xv.w, acc.w);
    }
    acc.x = acc.x / (1.f + expf(-acc.x));
    acc.y = acc.y / (1.f + expf(-acc.y));
    acc.z = acc.z / (1.f + expf(-acc.z));
    acc.w = acc.w / (1.f + expf(-acc.w));
    size_t o = (size_t)(b * L_DIM + tt) * DI + d;
    *(float4*)(xc + o) = acc;
    *(ushort4*)(xcb + o) = make_ushort4(bf16u(acc.x), bf16u(acc.y),
                                        bf16u(acc.z), bf16u(acc.w));
}

// -------- both transposes in ONE dispatch: z<2: dtb->dtt, z>=2: xc->xct ------
__global__ __launch_bounds__(256) void k_tr4(const float* __restrict__ dtb,
    float* __restrict__ dtt, const float* __restrict__ xc,
    float* __restrict__ xct)
{
    __shared__ float tile[64][65];
    const int r0 = blockIdx.y * 64, c0 = blockIdx.x * 64;
    const int z = blockIdx.z;
    const float* s;
    float* d;
    if (z < 2) { s = dtb + (size_t)z * L_DIM * DI;       d = dtt + (size_t)z * DI * L_DIM; }
    else       { s = xc  + (size_t)(z-2) * L_DIM * DI;   d = xct + (size_t)(z-2) * DI * L_DIM; }
    const int tx = threadIdx.x & 15, ty = threadIdx.x >> 4;
    #pragma unroll
    for (int p = 0; p < 4; ++p) {
        float4 v = *(const float4*)(s + (size_t)(r0 + ty + p*16) * DI + c0 + tx*4);
        tile[ty + p*16][tx*4+0] = v.x; tile[ty + p*16][tx*4+1] = v.y;
        tile[ty + p*16][tx*4+2] = v.z; tile[ty + p*16][tx*4+3] = v.w;
    }
    __syncthreads();
    #pragma unroll
    for (int p = 0; p < 4; ++p) {
        int oc = ty + p*16;
        float4 v = make_float4(tile[tx*4+0][oc], tile[tx*4+1][oc],
                               tile[tx*4+2][oc], tile[tx*4+3][oc]);
        *(float4*)(d + (size_t)(c0 + oc) * L_DIM + r0 + tx*4) = v;
    }
}

// ------ back-transpose yt[b][d][t] -> y_bf[b*t][d], fused silu(res) gate -----
__global__ __launch_bounds__(256) void k_trg(const float* __restrict__ yt,
    const float* __restrict__ xr, ushort* __restrict__ ybf)
{
    __shared__ float tile[64][65];
    const int r0 = blockIdx.y * 64, c0 = blockIdx.x * 64;   // r=d, c=t
    const int z = blockIdx.z;
    const float* s = yt + (size_t)z * DI * L_DIM;
    const int tx = threadIdx.x & 15, ty = threadIdx.x >> 4;
    #pragma unroll
    for (int p = 0; p < 4; ++p) {
        float4 v = *(const float4*)(s + (size_t)(r0 + ty + p*16) * L_DIM + c0 + tx*4);
        tile[ty + p*16][tx*4+0] = v.x; tile[ty + p*16][tx*4+1] = v.y;
        tile[ty + p*16][tx*4+2] = v.z; tile[ty + p*16][tx*4+3] = v.w;
    }
    __syncthreads();
    #pragma unroll
    for (int p = 0; p < 4; ++p) {
        int oc = ty + p*16;                       // local t index
        int row = z * L_DIM + c0 + oc;            // global (b*t) row
        float4 v = make_float4(tile[tx*4+0][oc], tile[tx*4+1][oc],
                               tile[tx*4+2][oc], tile[tx*4+3][oc]);
        float4 g = *(const float4*)(xr + (size_t)row * (2*DI) + DI + r0 + tx*4);
        v.x *= g.x / (1.f + expf(-g.x));
        v.y *= g.y / (1.f + expf(-g.y));
        v.z *= g.z / (1.f + expf(-g.z));
        v.w *= g.w / (1.f + expf(-g.w));
        *(ushort4*)(ybf + (size_t)row * DI + r0 + tx*4) =
            make_ushort4(bf16u(v.x), bf16u(v.y), bf16u(v.z), bf16u(v.w));
    }
}

__device__ __forceinline__ float rl(float v, int lane)
{
    return __int_as_float(__builtin_amdgcn_readlane(__float_as_int(v), lane));
}
// native 2^x — single v_exp_f32 (library exp2f is a multi-instruction call)
__device__ __forceinline__ float exp2_fast(float x)
{
    float r;
    asm("v_exp_f32 %0, %1" : "=v"(r) : "v"(x));
    return r;
}

// ---------------- selective scan v6 (proven 131 us) --------------------------
__global__ __launch_bounds__(256) void k_scan6(const float* __restrict__ dtt,
    const float* __restrict__ xct, const float* __restrict__ Bss,
    const float* __restrict__ A_log, const float* __restrict__ Dp,
    float* __restrict__ yt)
{
    __shared__ float Bsh[64][68];
    const int lane = threadIdx.x & 63;
    const int widx = threadIdx.x >> 6;
    const int b = blockIdx.x >> 9;
    const int d = (blockIdx.x & 511) * 4 + widx;
    const float aL2 = -expf(A_log[(size_t)d * NS + lane]) * 1.44269504f;
    const float Dv = Dp[d];
    const float* dtp = dtt + ((size_t)b * DI + d) * L_DIM;
    const float* xcp = xct + ((size_t)b * DI + d) * L_DIM;
    const float* Bp  = Bss + (size_t)b * L_DIM * NS;
    float* yp = yt + ((size_t)b * DI + d) * L_DIM;
    const int lr = threadIdx.x >> 2;
    const int lc = (threadIdx.x & 3) * 16;
    float h = 0.f;

    for (int t0 = 0; t0 < L_DIM; t0 += 64) {
        const float* bsrc = Bp + (size_t)(t0 + lr) * NS + lc;
        float4 b0 = *(const float4*)(bsrc);
        float4 b1 = *(const float4*)(bsrc + 4);
        float4 b2 = *(const float4*)(bsrc + 8);
        float4 b3 = *(const float4*)(bsrc + 12);
        float dt_v = dtp[t0 + lane];
        float xc_v = xcp[t0 + lane];
        __syncthreads();
        *(float4*)&Bsh[lr][lc]      = b0;
        *(float4*)&Bsh[lr][lc + 4]  = b1;
        *(float4*)&Bsh[lr][lc + 8]  = b2;
        *(float4*)&Bsh[lr][lc + 12] = b3;
        __syncthreads();
        float y_v = 0.f;
        #pragma unroll
        for (int q = 0; q < 64; q += 4) {
            float s0, s1, s2, s3;
            {
                float p, ad;
                p  = rl(xc_v, q+0) * Bsh[q+0][lane];
                ad = exp2_fast(aL2 * rl(dt_v, q+0));
                h = fmaf(ad, h, p); s0 = h;
                p  = rl(xc_v, q+1) * Bsh[q+1][lane];
                ad = exp2_fast(aL2 * rl(dt_v, q+1));
                h = fmaf(ad, h, p); s1 = h;
                p  = rl(xc_v, q+2) * Bsh[q+2][lane];
                ad = exp2_fast(aL2 * rl(dt_v, q+2));
                h = fmaf(ad, h, p); s2 = h;
                p  = rl(xc_v, q+3) * Bsh[q+3][lane];
                ad = exp2_fast(aL2 * rl(dt_v, q+3));
                h = fmaf(ad, h, p); s3 = h;
            }
            int tot0, tot1, tot2, tot3;
            asm("v_add_f32_dpp %0, %0, %0 row_shr:1 row_mask:0xf bank_mask:0xf\n\t"
                "v_add_f32_dpp %1, %1, %1 row_shr:1 row_mask:0xf bank_mask:0xf\n\t"
                "v_add_f32_dpp %2, %2, %2 row_shr:1 row_mask:0xf bank_mask:0xf\n\t"
                "v_add_f32_dpp %3, %3, %3 row_shr:1 row_mask:0xf bank_mask:0xf\n\t"
                "v_add_f32_dpp %0, %0, %0 row_shr:2 row_mask:0xf bank_mask:0xf\n\t"
                "v_add_f32_dpp %1, %1, %1 row_shr:2 row_mask:0xf bank_mask:0xf\n\t"
                "v_add_f32_dpp %2, %2, %2 row_shr:2 row_mask:0xf bank_mask:0xf\n\t"
                "v_add_f32_dpp %3, %3, %3 row_shr:2 row_mask:0xf bank_mask:0xf\n\t"
                "v_add_f32_dpp %0, %0, %0 row_shr:4 row_mask:0xf bank_mask:0xf\n\t"
                "v_add_f32_dpp %1, %1, %1 row_shr:4 row_mask:0xf bank_mask:0xf\n\t"
                "v_add_f32_dpp %2, %2, %2 row_shr:4 row_mask:0xf bank_mask:0xf\n\t"
                "v_add_f32_dpp %3, %3, %3 row_shr:4 row_mask:0xf bank_mask:0xf\n\t"
                "v_add_f32_dpp %0, %0, %0 row_shr:8 row_mask:0xf bank_mask:0xf\n\t"
                "v_add_f32_dpp %1, %1, %1 row_shr:8 row_mask:0xf bank_mask:0xf\n\t"
                "v_add_f32_dpp %2, %2, %2 row_shr:8 row_mask:0xf bank_mask:0xf\n\t"
                "v_add_f32_dpp %3, %3, %3 row_shr:8 row_mask:0xf bank_mask:0xf\n\t"
                "v_add_f32_dpp %0, %0, %0 row_bcast:15 row_mask:0xa bank_mask:0xf\n\t"
                "v_add_f32_dpp %1, %1, %1 row_bcast:15 row_mask:0xa bank_mask:0xf\n\t"
                "v_add_f32_dpp %2, %2, %2 row_bcast:15 row_mask:0xa bank_mask:0xf\n\t"
                "v_add_f32_dpp %3, %3, %3 row_bcast:15 row_mask:0xa bank_mask:0xf\n\t"
                "v_add_f32_dpp %0, %0, %0 row_bcast:31 row_mask:0xc bank_mask:0xf\n\t"
                "v_add_f32_dpp %1, %1, %1 row_bcast:31 row_mask:0xc bank_mask:0xf\n\t"
                "v_add_f32_dpp %2, %2, %2 row_bcast:31 row_mask:0xc bank_mask:0xf\n\t"
                "v_add_f32_dpp %3, %3, %3 row_bcast:31 row_mask:0xc bank_mask:0xf\n\t"
                "v_readlane_b32 %4, %0, 63\n\t"
                "v_readlane_b32 %5, %1, 63\n\t"
                "v_readlane_b32 %6, %2, 63\n\t"
                "v_readlane_b32 %7, %3, 63"
                : "+v"(s0), "+v"(s1), "+v"(s2), "+v"(s3),
                  "=s"(tot0), "=s"(tot1), "=s"(tot2), "=s"(tot3));
            asm("v_writelane_b32 %0, %1, %2"
                : "+v"(y_v) : "s"(tot0), "i"(q+0));
            asm("v_writelane_b32 %0, %1, %2"
                : "+v"(y_v) : "s"(tot1), "i"(q+1));
            asm("v_writelane_b32 %0, %1, %2"
                : "+v"(y_v) : "s"(tot2), "i"(q+2));
            asm("v_writelane_b32 %0, %1, %2"
                : "+v"(y_v) : "s"(tot3), "i"(q+3));
        }
        yp[t0 + lane] = fmaf(Dv, xc_v, y_v);
    }
}

extern "C" void kernel_launch(void* const* d_in, const int* in_sizes, int n_in,
                              void* d_out, int out_size, void* d_ws, size_t ws_size,
                              hipStream_t stream)
{
    const float* x        = (const float*)d_in[0];
    const float* norm_w   = (const float*)d_in[1];
    const float* in_projw = (const float*)d_in[2];
    const float* conv_w   = (const float*)d_in[3];
    const float* conv_b   = (const float*)d_in[4];
    const float* x_projw  = (const float*)d_in[5];
    const float* dt_w     = (const float*)d_in[6];
    const float* dt_b     = (const float*)d_in[7];
    const float* A_log    = (const float*)d_in[8];
    const float* D_param  = (const float*)d_in[9];
    const float* out_projw= (const float*)d_in[10];
    float* out = (float*)d_out;

    float* ws   = (float*)d_ws;
    float* xr   = ws;                               // 8M f32
    float* xc   = xr + (size_t)8*1024*1024;         // 4M f32
    float* dtb  = xc + (size_t)4*1024*1024;         // 4M f32 (yt alias)
    float* Bss  = dtb + (size_t)4*1024*1024;        // 128K f32
    float* dtt  = Bss + 131072;                     // 4M f32
    float* xct  = dtt + (size_t)4*1024*1024;        // 4M f32
    ushort* xn_bf  = (ushort*)(xct + (size_t)4*1024*1024); // 2M u16
    ushort* xc_bf  = xn_bf + (size_t)2*1024*1024;          // 4M u16
    ushort* xpw_bf = xc_bf + (size_t)4*1024*1024;          // 128K u16
    ushort* opw_bf = xpw_bf + 131072;                      // 2M u16 (own buffer)
    // aliases into dead regions:
    ushort* inpw_bf = (ushort*)dtt;   // dead before dtt written (post-GEMM0)
    ushort* dtw_bf  = (ushort*)xct;   // dead before xct written (post-GEMM1)
    ushort* y_bf    = (ushort*)xc;    // xc dead after transposes
    float* yt = dtb;

    // 1: all weight casts
    k_castw<<<5184, 256, 0, stream>>>(in_projw, inpw_bf, dt_w, dtw_bf,
                                      x_projw + (size_t)64*2048, xpw_bf,
                                      out_projw, opw_bf);
    // 2: fused RMSNorm + bf16 cast
    k_rms_xn<<<2048, 256, 0, stream>>>(x, norm_w, xn_bf);
    // 3: GEMM0: xr = xn @ in_proj^T   [2048][4096], K=1024
    k_mfma<0><<<dim3(32, 16), 256, 0, stream>>>(xn_bf, inpw_bf, nullptr,
                                                xr, nullptr, nullptr, nullptr, 1024, 4096);
    // 4: conv + SiLU
    k_conv<<<4096, 256, 0, stream>>>(xr, conv_w, conv_b, xc, xc_bf);
    // 5: GEMM1: dt = softplus(...) [2048][2048]; Bss = xc @ xp^T [2048][64]
    k_mfma<1><<<dim3(17, 16), 256, 0, stream>>>(xc_bf, dtw_bf, xpw_bf,
                                                dtb, Bss, dt_b, nullptr, 2048, 2048);
    // 6: both transposes, one dispatch
    k_tr4<<<dim3(32, 16, 4), 256, 0, stream>>>(dtb, dtt, xc, xct);
    // 7: scan
    k_scan6<<<1024, 256, 0, stream>>>(dtt, xct, Bss, A_log, D_param, yt);
    // 8: gated back-transpose -> bf16
    k_trg<<<dim3(16, 32, 2), 256, 0, stream>>>(yt, xr, y_bf);
    // 9: GEMM2: out = (y*silu(res)) @ out_proj^T + skip  [2048][1024], K=2048
    k_mfma<2><<<dim3(8, 16), 256, 0, stream>>>(y_bf, opw_bf, nullptr,
                                               out, nullptr, nullptr, x, 2048, 1024);
}

// Round 11
// 301.329 us; speedup vs baseline: 1.1301x; 1.0666x over previous
//
#include <hip/hip_runtime.h>
#include <hip/hip_bf16.h>
#include <math.h>

#define L_DIM 1024
#define DM 1024
#define DI 2048
#define NS 64

typedef __attribute__((ext_vector_type(8))) short short8;
typedef __attribute__((ext_vector_type(4))) float f32x4;

__device__ __forceinline__ ushort bf16u(float f)
{
    unsigned u = __float_as_uint(f);
    unsigned r = (u + 0x7fffu + ((u >> 16) & 1u)) >> 16;
    return (ushort)r;
}

__device__ __forceinline__ void gld16(const ushort* g, const ushort* l)
{
    __builtin_amdgcn_global_load_lds(
        (const __attribute__((address_space(1))) unsigned int*)g,
        (__attribute__((address_space(3))) unsigned int*)l, 16, 0, 0);
}

// -------- fused RMSNorm + bf16 cast ------------------------------------------
__global__ __launch_bounds__(256) void k_rms_xn(const float* __restrict__ x,
    const float* __restrict__ nw, ushort* __restrict__ d)
{
    int row = blockIdx.x;
    const float* xp = x + (size_t)row * DM;
    float4 v = ((const float4*)xp)[threadIdx.x];
    float ss = v.x*v.x + v.y*v.y + v.z*v.z + v.w*v.w;
    #pragma unroll
    for (int m = 32; m; m >>= 1) ss += __shfl_xor(ss, m, 64);
    __shared__ float red[4];
    if ((threadIdx.x & 63) == 0) red[threadIdx.x >> 6] = ss;
    __syncthreads();
    float tot = red[0] + red[1] + red[2] + red[3];
    float ri = rsqrtf(tot * (1.0f / DM) + 1e-6f);
    float4 wv = ((const float4*)nw)[threadIdx.x];
    ((ushort4*)(d + (size_t)row * DM))[threadIdx.x] =
        make_ushort4(bf16u(v.x*ri*wv.x), bf16u(v.y*ri*wv.y),
                     bf16u(v.z*ri*wv.z), bf16u(v.w*ri*wv.w));
}

// ---------------- all weight casts in ONE dispatch ---------------------------
__device__ __forceinline__ void cast8(const float* __restrict__ s,
                                      ushort* __restrict__ d, int i)
{
    float4 a = ((const float4*)s)[2*i], b = ((const float4*)s)[2*i+1];
    ((ushort4*)d)[2*i]   = make_ushort4(bf16u(a.x), bf16u(a.y), bf16u(a.z), bf16u(a.w));
    ((ushort4*)d)[2*i+1] = make_ushort4(bf16u(b.x), bf16u(b.y), bf16u(b.z), bf16u(b.w));
}
__global__ __launch_bounds__(256) void k_castw(
    const float* __restrict__ s0, ushort* __restrict__ d0,
    const float* __restrict__ s1, ushort* __restrict__ d1,
    const float* __restrict__ s2, ushort* __restrict__ d2,
    const float* __restrict__ s3, ushort* __restrict__ d3)
{
    int i = blockIdx.x * 256 + threadIdx.x;
    if (i < 524288)       cast8(s0, d0, i);
    else if (i < 1048576) cast8(s1, d1, i - 524288);
    else if (i < 1064960) cast8(s2, d2, i - 1048576);
    else                  cast8(s3, d3, i - 1064960);
}

// ---------------- MFMA NT GEMM, BK=64, XOR-swizzled LDS, XCD swizzle ---------
// LDS[row][c16] = G[row][c16 ^ (row&7)]  (c16 = 16B unit), achieved by
// pre-swizzling the per-lane GLOBAL k-offset (linear gld16 dest).
template<int MODE>
__global__ __launch_bounds__(256) void k_mfma(
    const ushort* __restrict__ Abf, const ushort* __restrict__ Bbf0,
    const ushort* __restrict__ Bbf1, float* __restrict__ C0,
    float* __restrict__ C1, const float* __restrict__ bias,
    const float* __restrict__ skip, int Kdim, int ldc)
{
    __shared__ __align__(16) ushort As[128*64];
    __shared__ __align__(16) ushort Bs[128*64];
    const int t = threadIdx.x, w = t >> 6, lane = t & 63;
    // XCD-aware block swizzle (all grids have nwg % 8 == 0)
    const int nwg = gridDim.x * gridDim.y;
    const int orig = blockIdx.y * gridDim.x + blockIdx.x;
    const int swz = (orig & 7) * (nwg >> 3) + (orig >> 3);
    const int nt = swz % gridDim.x, mt = swz / gridDim.x;
    const int mBase = mt * 128, nBase = nt * 128;
    const bool isXP = (MODE == 1) && (nt == 16);
    const ushort* __restrict__ Bbf = isXP ? Bbf1 : Bbf0;
    const int wr = (w >> 1) * 64, wc = (w & 1) * 64;
    const int sR = lane >> 3;                       // row within 8-row slab
    const int sK = ((lane & 7) ^ sR) * 8;           // pre-swizzled k offset

    f32x4 acc[4][4];
    #pragma unroll
    for (int i = 0; i < 4; ++i)
        #pragma unroll
        for (int j = 0; j < 4; ++j)
            acc[i][j] = (f32x4){0.f, 0.f, 0.f, 0.f};

    for (int kt = 0; kt < Kdim; kt += 64) {
        #pragma unroll
        for (int s = 0; s < 4; ++s) {
            int tr = w*8 + s*32 + sR;
            gld16(Abf + (size_t)(mBase + tr) * Kdim + kt + sK,
                  As + (w*8 + s*32) * 64);
            int gr = isXP ? (tr < 63 ? tr : 63) : (nBase + tr);
            gld16(Bbf + (size_t)gr * Kdim + kt + sK,
                  Bs + (w*8 + s*32) * 64);
        }
        __syncthreads();
        #pragma unroll
        for (int kk = 0; kk < 2; ++kk) {
            short8 af[4], bfr[4];
            #pragma unroll
            for (int f = 0; f < 4; ++f) {
                int ra = wr + f*16 + (lane & 15);
                int ca = (kk*4 + (lane >> 4)) ^ (ra & 7);
                af[f]  = *(const short8*)(As + ra*64 + ca*8);
                int rb2 = wc + f*16 + (lane & 15);
                int cb2 = (kk*4 + (lane >> 4)) ^ (rb2 & 7);
                bfr[f] = *(const short8*)(Bs + rb2*64 + cb2*8);
            }
            #pragma unroll
            for (int mi = 0; mi < 4; ++mi)
                #pragma unroll
                for (int ni = 0; ni < 4; ++ni)
                    acc[mi][ni] = __builtin_amdgcn_mfma_f32_16x16x32_bf16(
                        af[mi], bfr[ni], acc[mi][ni], 0, 0, 0);
        }
        __syncthreads();
    }

    const int rb = (lane >> 4) * 4, cbl = lane & 15;
    #pragma unroll
    for (int mi = 0; mi < 4; ++mi) {
        #pragma unroll
        for (int ni = 0; ni < 4; ++ni) {
            int ltcol = wc + ni*16 + cbl;
            int col = nBase + ltcol;
            #pragma unroll
            for (int j = 0; j < 4; ++j) {
                int row = mBase + wr + mi*16 + rb + j;
                float v = acc[mi][ni][j];
                if constexpr (MODE == 0) {
                    C0[(size_t)row * ldc + col] = v;
                } else if constexpr (MODE == 1) {
                    if (isXP) {
                        if (ltcol < NS) C1[(size_t)row * NS + ltcol] = v;
                    } else {
                        float z = v + bias[col];
                        C0[(size_t)row * ldc + col] =
                            (z > 20.f) ? z : logf(1.f + expf(z));
                    }
                } else {
                    C0[(size_t)row * ldc + col] = v + skip[(size_t)row * ldc + col];
                }
            }
        }
    }
}

// ---------------- causal depthwise conv1d (K=4) + SiLU -----------------------
__global__ __launch_bounds__(256) void k_conv(const float* __restrict__ xr,
    const float* __restrict__ cw, const float* __restrict__ cb,
    float* __restrict__ xc, ushort* __restrict__ xcb)
{
    int gid = blockIdx.x * 256 + threadIdx.x;
    int d = (gid & 511) * 4;
    int tt = (gid >> 9) & 1023;
    int b = gid >> 19;
    float4 w[4];
    #pragma unroll
    for (int c = 0; c < 4; ++c) w[c] = *(const float4*)(cw + (size_t)(d + c) * 4);
    float4 acc = *(const float4*)(cb + d);
    const float* base = xr + (size_t)b * L_DIM * (2*DI) + d;
    #pragma unroll
    for (int j = 0; j < 4; ++j) {
        int ti = tt - 3 + j;
        if (ti < 0) continue;
        float4 xv = *(const float4*)(base + (size_t)ti * (2*DI));
        const float* w0 = (const float*)&w[0];
        const float* w1 = (const float*)&w[1];
        const float* w2 = (const float*)&w[2];
        const float* w3 = (const float*)&w[3];
        acc.x = fmaf(w0[j], xv.x, acc.x);
        acc.y = fmaf(w1[j], xv.y, acc.y);
        acc.z = fmaf(w2[j], xv.z, acc.z);
        acc.w = fmaf(w3[j], xv.w, acc.w);
    }
    acc.x = acc.x / (1.f + expf(-acc.x));
    acc.y = acc.y / (1.f + expf(-acc.y));
    acc.z = acc.z / (1.f + expf(-acc.z));
    acc.w = acc.w / (1.f + expf(-acc.w));
    size_t o = (size_t)(b * L_DIM + tt) * DI + d;
    *(float4*)(xc + o) = acc;
    *(ushort4*)(xcb + o) = make_ushort4(bf16u(acc.x), bf16u(acc.y),
                                        bf16u(acc.z), bf16u(acc.w));
}

// -------- both transposes in ONE dispatch ------------------------------------
__global__ __launch_bounds__(256) void k_tr4(const float* __restrict__ dtb,
    float* __restrict__ dtt, const float* __restrict__ xc,
    float* __restrict__ xct)
{
    __shared__ float tile[64][65];
    const int r0 = blockIdx.y * 64, c0 = blockIdx.x * 64;
    const int z = blockIdx.z;
    const float* s;
    float* d;
    if (z < 2) { s = dtb + (size_t)z * L_DIM * DI;       d = dtt + (size_t)z * DI * L_DIM; }
    else       { s = xc  + (size_t)(z-2) * L_DIM * DI;   d = xct + (size_t)(z-2) * DI * L_DIM; }
    const int tx = threadIdx.x & 15, ty = threadIdx.x >> 4;
    #pragma unroll
    for (int p = 0; p < 4; ++p) {
        float4 v = *(const float4*)(s + (size_t)(r0 + ty + p*16) * DI + c0 + tx*4);
        tile[ty + p*16][tx*4+0] = v.x; tile[ty + p*16][tx*4+1] = v.y;
        tile[ty + p*16][tx*4+2] = v.z; tile[ty + p*16][tx*4+3] = v.w;
    }
    __syncthreads();
    #pragma unroll
    for (int p = 0; p < 4; ++p) {
        int oc = ty + p*16;
        float4 v = make_float4(tile[tx*4+0][oc], tile[tx*4+1][oc],
                               tile[tx*4+2][oc], tile[tx*4+3][oc]);
        *(float4*)(d + (size_t)(c0 + oc) * L_DIM + r0 + tx*4) = v;
    }
}

// ------ back-transpose + silu(res) gate + bf16 -------------------------------
__global__ __launch_bounds__(256) void k_trg(const float* __restrict__ yt,
    const float* __restrict__ xr, ushort* __restrict__ ybf)
{
    __shared__ float tile[64][65];
    const int r0 = blockIdx.y * 64, c0 = blockIdx.x * 64;
    const int z = blockIdx.z;
    const float* s = yt + (size_t)z * DI * L_DIM;
    const int tx = threadIdx.x & 15, ty = threadIdx.x >> 4;
    #pragma unroll
    for (int p = 0; p < 4; ++p) {
        float4 v = *(const float4*)(s + (size_t)(r0 + ty + p*16) * L_DIM + c0 + tx*4);
        tile[ty + p*16][tx*4+0] = v.x; tile[ty + p*16][tx*4+1] = v.y;
        tile[ty + p*16][tx*4+2] = v.z; tile[ty + p*16][tx*4+3] = v.w;
    }
    __syncthreads();
    #pragma unroll
    for (int p = 0; p < 4; ++p) {
        int oc = ty + p*16;
        int row = z * L_DIM + c0 + oc;
        float4 v = make_float4(tile[tx*4+0][oc], tile[tx*4+1][oc],
                               tile[tx*4+2][oc], tile[tx*4+3][oc]);
        float4 g = *(const float4*)(xr + (size_t)row * (2*DI) + DI + r0 + tx*4);
        v.x *= g.x / (1.f + expf(-g.x));
        v.y *= g.y / (1.f + expf(-g.y));
        v.z *= g.z / (1.f + expf(-g.z));
        v.w *= g.w / (1.f + expf(-g.w));
        *(ushort4*)(ybf + (size_t)row * DI + r0 + tx*4) =
            make_ushort4(bf16u(v.x), bf16u(v.y), bf16u(v.z), bf16u(v.w));
    }
}

__device__ __forceinline__ float rl(float v, int lane)
{
    return __int_as_float(__builtin_amdgcn_readlane(__float_as_int(v), lane));
}
__device__ __forceinline__ float exp2_fast(float x)
{
    float r;
    asm("v_exp_f32 %0, %1" : "=v"(r) : "v"(x));
    return r;
}

// ---------------- selective scan v8: dbuf B-staging, prefetch under compute --
__global__ __launch_bounds__(256) void k_scan8(const float* __restrict__ dtt,
    const float* __restrict__ xct, const float* __restrict__ Bss,
    const float* __restrict__ A_log, const float* __restrict__ Dp,
    float* __restrict__ yt)
{
    __shared__ float Bsh[2][64][68];
    const int lane = threadIdx.x & 63;
    const int widx = threadIdx.x >> 6;
    const int b = blockIdx.x >> 9;
    const int d = (blockIdx.x & 511) * 4 + widx;
    const float aL2 = -expf(A_log[(size_t)d * NS + lane]) * 1.44269504f;
    const float Dv = Dp[d];
    const float* dtp = dtt + ((size_t)b * DI + d) * L_DIM;
    const float* xcp = xct + ((size_t)b * DI + d) * L_DIM;
    const float* Bp  = Bss + (size_t)b * L_DIM * NS;
    float* yp = yt + ((size_t)b * DI + d) * L_DIM;
    const int lr = threadIdx.x >> 2;
    const int lc = (threadIdx.x & 3) * 16;
    float h = 0.f;

    // preload chunk 0
    const float* bs0 = Bp + (size_t)lr * NS + lc;
    float4 b0 = *(const float4*)(bs0);
    float4 b1 = *(const float4*)(bs0 + 4);
    float4 b2 = *(const float4*)(bs0 + 8);
    float4 b3 = *(const float4*)(bs0 + 12);
    float dt_v = dtp[lane];
    float xc_v = xcp[lane];
    int cur = 0;

    for (int t0 = 0; t0 < L_DIM; t0 += 64) {
        *(float4*)&Bsh[cur][lr][lc]      = b0;
        *(float4*)&Bsh[cur][lr][lc + 4]  = b1;
        *(float4*)&Bsh[cur][lr][lc + 8]  = b2;
        *(float4*)&Bsh[cur][lr][lc + 12] = b3;
        float dtv = dt_v, xcv = xc_v;
        __syncthreads();
        if (t0 + 64 < L_DIM) {          // issue next-chunk loads; results
            const float* bs = Bp + (size_t)(t0 + 64 + lr) * NS + lc;
            b0 = *(const float4*)(bs);  // consumed at next iter's LDS write
            b1 = *(const float4*)(bs + 4);
            b2 = *(const float4*)(bs + 8);
            b3 = *(const float4*)(bs + 12);
            dt_v = dtp[t0 + 64 + lane];
            xc_v = xcp[t0 + 64 + lane];
        }
        float y_v = 0.f;
        #pragma unroll
        for (int q = 0; q < 64; q += 4) {
            float s0, s1, s2, s3;
            {
                float p, ad;
                p  = rl(xcv, q+0) * Bsh[cur][q+0][lane];
                ad = exp2_fast(aL2 * rl(dtv, q+0));
                h = fmaf(ad, h, p); s0 = h;
                p  = rl(xcv, q+1) * Bsh[cur][q+1][lane];
                ad = exp2_fast(aL2 * rl(dtv, q+1));
                h = fmaf(ad, h, p); s1 = h;
                p  = rl(xcv, q+2) * Bsh[cur][q+2][lane];
                ad = exp2_fast(aL2 * rl(dtv, q+2));
                h = fmaf(ad, h, p); s2 = h;
                p  = rl(xcv, q+3) * Bsh[cur][q+3][lane];
                ad = exp2_fast(aL2 * rl(dtv, q+3));
                h = fmaf(ad, h, p); s3 = h;
            }
            int tot0, tot1, tot2, tot3;
            asm("v_add_f32_dpp %0, %0, %0 row_shr:1 row_mask:0xf bank_mask:0xf\n\t"
                "v_add_f32_dpp %1, %1, %1 row_shr:1 row_mask:0xf bank_mask:0xf\n\t"
                "v_add_f32_dpp %2, %2, %2 row_shr:1 row_mask:0xf bank_mask:0xf\n\t"
                "v_add_f32_dpp %3, %3, %3 row_shr:1 row_mask:0xf bank_mask:0xf\n\t"
                "v_add_f32_dpp %0, %0, %0 row_shr:2 row_mask:0xf bank_mask:0xf\n\t"
                "v_add_f32_dpp %1, %1, %1 row_shr:2 row_mask:0xf bank_mask:0xf\n\t"
                "v_add_f32_dpp %2, %2, %2 row_shr:2 row_mask:0xf bank_mask:0xf\n\t"
                "v_add_f32_dpp %3, %3, %3 row_shr:2 row_mask:0xf bank_mask:0xf\n\t"
                "v_add_f32_dpp %0, %0, %0 row_shr:4 row_mask:0xf bank_mask:0xf\n\t"
                "v_add_f32_dpp %1, %1, %1 row_shr:4 row_mask:0xf bank_mask:0xf\n\t"
                "v_add_f32_dpp %2, %2, %2 row_shr:4 row_mask:0xf bank_mask:0xf\n\t"
                "v_add_f32_dpp %3, %3, %3 row_shr:4 row_mask:0xf bank_mask:0xf\n\t"
                "v_add_f32_dpp %0, %0, %0 row_shr:8 row_mask:0xf bank_mask:0xf\n\t"
                "v_add_f32_dpp %1, %1, %1 row_shr:8 row_mask:0xf bank_mask:0xf\n\t"
                "v_add_f32_dpp %2, %2, %2 row_shr:8 row_mask:0xf bank_mask:0xf\n\t"
                "v_add_f32_dpp %3, %3, %3 row_shr:8 row_mask:0xf bank_mask:0xf\n\t"
                "v_add_f32_dpp %0, %0, %0 row_bcast:15 row_mask:0xa bank_mask:0xf\n\t"
                "v_add_f32_dpp %1, %1, %1 row_bcast:15 row_mask:0xa bank_mask:0xf\n\t"
                "v_add_f32_dpp %2, %2, %2 row_bcast:15 row_mask:0xa bank_mask:0xf\n\t"
                "v_add_f32_dpp %3, %3, %3 row_bcast:15 row_mask:0xa bank_mask:0xf\n\t"
                "v_add_f32_dpp %0, %0, %0 row_bcast:31 row_mask:0xc bank_mask:0xf\n\t"
                "v_add_f32_dpp %1, %1, %1 row_bcast:31 row_mask:0xc bank_mask:0xf\n\t"
                "v_add_f32_dpp %2, %2, %2 row_bcast:31 row_mask:0xc bank_mask:0xf\n\t"
                "v_add_f32_dpp %3, %3, %3 row_bcast:31 row_mask:0xc bank_mask:0xf\n\t"
                "v_readlane_b32 %4, %0, 63\n\t"
                "v_readlane_b32 %5, %1, 63\n\t"
                "v_readlane_b32 %6, %2, 63\n\t"
                "v_readlane_b32 %7, %3, 63"
                : "+v"(s0), "+v"(s1), "+v"(s2), "+v"(s3),
                  "=s"(tot0), "=s"(tot1), "=s"(tot2), "=s"(tot3));
            asm("v_writelane_b32 %0, %1, %2"
                : "+v"(y_v) : "s"(tot0), "i"(q+0));
            asm("v_writelane_b32 %0, %1, %2"
                : "+v"(y_v) : "s"(tot1), "i"(q+1));
            asm("v_writelane_b32 %0, %1, %2"
                : "+v"(y_v) : "s"(tot2), "i"(q+2));
            asm("v_writelane_b32 %0, %1, %2"
                : "+v"(y_v) : "s"(tot3), "i"(q+3));
        }
        yp[t0 + lane] = fmaf(Dv, xcv, y_v);
        cur ^= 1;
    }
}

extern "C" void kernel_launch(void* const* d_in, const int* in_sizes, int n_in,
                              void* d_out, int out_size, void* d_ws, size_t ws_size,
                              hipStream_t stream)
{
    const float* x        = (const float*)d_in[0];
    const float* norm_w   = (const float*)d_in[1];
    const float* in_projw = (const float*)d_in[2];
    const float* conv_w   = (const float*)d_in[3];
    const float* conv_b   = (const float*)d_in[4];
    const float* x_projw  = (const float*)d_in[5];
    const float* dt_w     = (const float*)d_in[6];
    const float* dt_b     = (const float*)d_in[7];
    const float* A_log    = (const float*)d_in[8];
    const float* D_param  = (const float*)d_in[9];
    const float* out_projw= (const float*)d_in[10];
    float* out = (float*)d_out;

    float* ws   = (float*)d_ws;
    float* xr   = ws;                               // 8M f32
    float* xc   = xr + (size_t)8*1024*1024;         // 4M f32
    float* dtb  = xc + (size_t)4*1024*1024;         // 4M f32 (yt alias)
    float* Bss  = dtb + (size_t)4*1024*1024;        // 128K f32
    float* dtt  = Bss + 131072;                     // 4M f32
    float* xct  = dtt + (size_t)4*1024*1024;        // 4M f32
    ushort* xn_bf  = (ushort*)(xct + (size_t)4*1024*1024); // 2M u16
    ushort* xc_bf  = xn_bf + (size_t)2*1024*1024;          // 4M u16
    ushort* xpw_bf = xc_bf + (size_t)4*1024*1024;          // 128K u16
    ushort* opw_bf = xpw_bf + 131072;                      // 2M u16
    ushort* inpw_bf = (ushort*)dtt;   // dead before dtt written (post-GEMM0)
    ushort* dtw_bf  = (ushort*)xct;   // dead before xct written (post-GEMM1)
    ushort* y_bf    = (ushort*)xc;    // xc dead after transposes
    float* yt = dtb;

    k_castw<<<5184, 256, 0, stream>>>(in_projw, inpw_bf, dt_w, dtw_bf,
                                      x_projw + (size_t)64*2048, xpw_bf,
                                      out_projw, opw_bf);
    k_rms_xn<<<2048, 256, 0, stream>>>(x, norm_w, xn_bf);
    k_mfma<0><<<dim3(32, 16), 256, 0, stream>>>(xn_bf, inpw_bf, nullptr,
                                                xr, nullptr, nullptr, nullptr, 1024, 4096);
    k_conv<<<4096, 256, 0, stream>>>(xr, conv_w, conv_b, xc, xc_bf);
    k_mfma<1><<<dim3(17, 16), 256, 0, stream>>>(xc_bf, dtw_bf, xpw_bf,
                                                dtb, Bss, dt_b, nullptr, 2048, 2048);
    k_tr4<<<dim3(32, 16, 4), 256, 0, stream>>>(dtb, dtt, xc, xct);
    k_scan8<<<1024, 256, 0, stream>>>(dtt, xct, Bss, A_log, D_param, yt);
    k_trg<<<dim3(16, 32, 2), 256, 0, stream>>>(yt, xr, y_bf);
    k_mfma<2><<<dim3(8, 16), 256, 0, stream>>>(y_bf, opw_bf, nullptr,
                                               out, nullptr, nullptr, x, 2048, 1024);
}

// Round 12
// 295.655 us; speedup vs baseline: 1.1518x; 1.0192x over previous
//
#include <hip/hip_runtime.h>
#include <hip/hip_bf16.h>
#include <math.h>

#define L_DIM 1024
#define DM 1024
#define DI 2048
#define NS 64

typedef __attribute__((ext_vector_type(8))) short short8;
typedef __attribute__((ext_vector_type(4))) float f32x4;

__device__ __forceinline__ ushort bf16u(float f)
{
    unsigned u = __float_as_uint(f);
    unsigned r = (u + 0x7fffu + ((u >> 16) & 1u)) >> 16;
    return (ushort)r;
}
__device__ __forceinline__ float bf2f(ushort u)
{
    return __uint_as_float((unsigned)u << 16);
}

__device__ __forceinline__ void gld16(const ushort* g, const ushort* l)
{
    __builtin_amdgcn_global_load_lds(
        (const __attribute__((address_space(1))) unsigned int*)g,
        (__attribute__((address_space(3))) unsigned int*)l, 16, 0, 0);
}

// -------- fused RMSNorm + bf16 cast ------------------------------------------
__global__ __launch_bounds__(256) void k_rms_xn(const float* __restrict__ x,
    const float* __restrict__ nw, ushort* __restrict__ d)
{
    int row = blockIdx.x;
    const float* xp = x + (size_t)row * DM;
    float4 v = ((const float4*)xp)[threadIdx.x];
    float ss = v.x*v.x + v.y*v.y + v.z*v.z + v.w*v.w;
    #pragma unroll
    for (int m = 32; m; m >>= 1) ss += __shfl_xor(ss, m, 64);
    __shared__ float red[4];
    if ((threadIdx.x & 63) == 0) red[threadIdx.x >> 6] = ss;
    __syncthreads();
    float tot = red[0] + red[1] + red[2] + red[3];
    float ri = rsqrtf(tot * (1.0f / DM) + 1e-6f);
    float4 wv = ((const float4*)nw)[threadIdx.x];
    ((ushort4*)(d + (size_t)row * DM))[threadIdx.x] =
        make_ushort4(bf16u(v.x*ri*wv.x), bf16u(v.y*ri*wv.y),
                     bf16u(v.z*ri*wv.z), bf16u(v.w*ri*wv.w));
}

// ---------------- all weight casts in ONE dispatch ---------------------------
__device__ __forceinline__ void cast8(const float* __restrict__ s,
                                      ushort* __restrict__ d, int i)
{
    float4 a = ((const float4*)s)[2*i], b = ((const float4*)s)[2*i+1];
    ((ushort4*)d)[2*i]   = make_ushort4(bf16u(a.x), bf16u(a.y), bf16u(a.z), bf16u(a.w));
    ((ushort4*)d)[2*i+1] = make_ushort4(bf16u(b.x), bf16u(b.y), bf16u(b.z), bf16u(b.w));
}
__global__ __launch_bounds__(256) void k_castw(
    const float* __restrict__ s0, ushort* __restrict__ d0,
    const float* __restrict__ s1, ushort* __restrict__ d1,
    const float* __restrict__ s2, ushort* __restrict__ d2,
    const float* __restrict__ s3, ushort* __restrict__ d3)
{
    int i = blockIdx.x * 256 + threadIdx.x;
    if (i < 524288)       cast8(s0, d0, i);
    else if (i < 1048576) cast8(s1, d1, i - 524288);
    else if (i < 1064960) cast8(s2, d2, i - 1048576);
    else                  cast8(s3, d3, i - 1064960);
}

// ---------------- MFMA NT GEMM, BK=64, XOR-swizzled LDS, XCD swizzle ---------
// MODE 0 writes bf16 output (C0b); MODE 1/2 write f32 (C0/C1).
template<int MODE>
__global__ __launch_bounds__(256) void k_mfma(
    const ushort* __restrict__ Abf, const ushort* __restrict__ Bbf0,
    const ushort* __restrict__ Bbf1, float* __restrict__ C0,
    ushort* __restrict__ C0b, float* __restrict__ C1,
    const float* __restrict__ bias, const float* __restrict__ skip,
    int Kdim, int ldc)
{
    __shared__ __align__(16) ushort As[128*64];
    __shared__ __align__(16) ushort Bs[128*64];
    const int t = threadIdx.x, w = t >> 6, lane = t & 63;
    const int nwg = gridDim.x * gridDim.y;
    const int orig = blockIdx.y * gridDim.x + blockIdx.x;
    const int swz = (orig & 7) * (nwg >> 3) + (orig >> 3);
    const int nt = swz % gridDim.x, mt = swz / gridDim.x;
    const int mBase = mt * 128, nBase = nt * 128;
    const bool isXP = (MODE == 1) && (nt == 16);
    const ushort* __restrict__ Bbf = isXP ? Bbf1 : Bbf0;
    const int wr = (w >> 1) * 64, wc = (w & 1) * 64;
    const int sR = lane >> 3;
    const int sK = ((lane & 7) ^ sR) * 8;

    f32x4 acc[4][4];
    #pragma unroll
    for (int i = 0; i < 4; ++i)
        #pragma unroll
        for (int j = 0; j < 4; ++j)
            acc[i][j] = (f32x4){0.f, 0.f, 0.f, 0.f};

    for (int kt = 0; kt < Kdim; kt += 64) {
        #pragma unroll
        for (int s = 0; s < 4; ++s) {
            int tr = w*8 + s*32 + sR;
            gld16(Abf + (size_t)(mBase + tr) * Kdim + kt + sK,
                  As + (w*8 + s*32) * 64);
            int gr = isXP ? (tr < 63 ? tr : 63) : (nBase + tr);
            gld16(Bbf + (size_t)gr * Kdim + kt + sK,
                  Bs + (w*8 + s*32) * 64);
        }
        __syncthreads();
        #pragma unroll
        for (int kk = 0; kk < 2; ++kk) {
            short8 af[4], bfr[4];
            #pragma unroll
            for (int f = 0; f < 4; ++f) {
                int ra = wr + f*16 + (lane & 15);
                int ca = (kk*4 + (lane >> 4)) ^ (ra & 7);
                af[f]  = *(const short8*)(As + ra*64 + ca*8);
                int rb2 = wc + f*16 + (lane & 15);
                int cb2 = (kk*4 + (lane >> 4)) ^ (rb2 & 7);
                bfr[f] = *(const short8*)(Bs + rb2*64 + cb2*8);
            }
            #pragma unroll
            for (int mi = 0; mi < 4; ++mi)
                #pragma unroll
                for (int ni = 0; ni < 4; ++ni)
                    acc[mi][ni] = __builtin_amdgcn_mfma_f32_16x16x32_bf16(
                        af[mi], bfr[ni], acc[mi][ni], 0, 0, 0);
        }
        __syncthreads();
    }

    const int rb = (lane >> 4) * 4, cbl = lane & 15;
    #pragma unroll
    for (int mi = 0; mi < 4; ++mi) {
        #pragma unroll
        for (int ni = 0; ni < 4; ++ni) {
            int ltcol = wc + ni*16 + cbl;
            int col = nBase + ltcol;
            #pragma unroll
            for (int j = 0; j < 4; ++j) {
                int row = mBase + wr + mi*16 + rb + j;
                float v = acc[mi][ni][j];
                if constexpr (MODE == 0) {
                    C0b[(size_t)row * ldc + col] = bf16u(v);
                } else if constexpr (MODE == 1) {
                    if (isXP) {
                        if (ltcol < NS) C1[(size_t)row * NS + ltcol] = v;
                    } else {
                        float z = v + bias[col];
                        C0[(size_t)row * ldc + col] =
                            (z > 20.f) ? z : logf(1.f + expf(z));
                    }
                } else {
                    C0[(size_t)row * ldc + col] = v + skip[(size_t)row * ldc + col];
                }
            }
        }
    }
}

// ---------------- causal depthwise conv1d (K=4) + SiLU, bf16 in --------------
__global__ __launch_bounds__(256) void k_conv(const ushort* __restrict__ xrb,
    const float* __restrict__ cw, const float* __restrict__ cb,
    float* __restrict__ xc, ushort* __restrict__ xcb)
{
    int gid = blockIdx.x * 256 + threadIdx.x;
    int d = (gid & 511) * 4;
    int tt = (gid >> 9) & 1023;
    int b = gid >> 19;
    float4 w[4];
    #pragma unroll
    for (int c = 0; c < 4; ++c) w[c] = *(const float4*)(cw + (size_t)(d + c) * 4);
    float4 acc = *(const float4*)(cb + d);
    const ushort* base = xrb + (size_t)b * L_DIM * (2*DI) + d;
    #pragma unroll
    for (int j = 0; j < 4; ++j) {
        int ti = tt - 3 + j;
        if (ti < 0) continue;
        ushort4 xu = *(const ushort4*)(base + (size_t)ti * (2*DI));
        const float* w0 = (const float*)&w[0];
        const float* w1 = (const float*)&w[1];
        const float* w2 = (const float*)&w[2];
        const float* w3 = (const float*)&w[3];
        acc.x = fmaf(w0[j], bf2f(xu.x), acc.x);
        acc.y = fmaf(w1[j], bf2f(xu.y), acc.y);
        acc.z = fmaf(w2[j], bf2f(xu.z), acc.z);
        acc.w = fmaf(w3[j], bf2f(xu.w), acc.w);
    }
    acc.x = acc.x / (1.f + expf(-acc.x));
    acc.y = acc.y / (1.f + expf(-acc.y));
    acc.z = acc.z / (1.f + expf(-acc.z));
    acc.w = acc.w / (1.f + expf(-acc.w));
    size_t o = (size_t)(b * L_DIM + tt) * DI + d;
    *(float4*)(xc + o) = acc;
    *(ushort4*)(xcb + o) = make_ushort4(bf16u(acc.x), bf16u(acc.y),
                                        bf16u(acc.z), bf16u(acc.w));
}

// -------- both transposes in ONE dispatch ------------------------------------
__global__ __launch_bounds__(256) void k_tr4(const float* __restrict__ dtb,
    float* __restrict__ dtt, const float* __restrict__ xc,
    float* __restrict__ xct)
{
    __shared__ float tile[64][65];
    const int r0 = blockIdx.y * 64, c0 = blockIdx.x * 64;
    const int z = blockIdx.z;
    const float* s;
    float* d;
    if (z < 2) { s = dtb + (size_t)z * L_DIM * DI;       d = dtt + (size_t)z * DI * L_DIM; }
    else       { s = xc  + (size_t)(z-2) * L_DIM * DI;   d = xct + (size_t)(z-2) * DI * L_DIM; }
    const int tx = threadIdx.x & 15, ty = threadIdx.x >> 4;
    #pragma unroll
    for (int p = 0; p < 4; ++p) {
        float4 v = *(const float4*)(s + (size_t)(r0 + ty + p*16) * DI + c0 + tx*4);
        tile[ty + p*16][tx*4+0] = v.x; tile[ty + p*16][tx*4+1] = v.y;
        tile[ty + p*16][tx*4+2] = v.z; tile[ty + p*16][tx*4+3] = v.w;
    }
    __syncthreads();
    #pragma unroll
    for (int p = 0; p < 4; ++p) {
        int oc = ty + p*16;
        float4 v = make_float4(tile[tx*4+0][oc], tile[tx*4+1][oc],
                               tile[tx*4+2][oc], tile[tx*4+3][oc]);
        *(float4*)(d + (size_t)(c0 + oc) * L_DIM + r0 + tx*4) = v;
    }
}

// ------ back-transpose + silu(res) gate (bf16 gate) + bf16 out ---------------
__global__ __launch_bounds__(256) void k_trg(const float* __restrict__ yt,
    const ushort* __restrict__ xrb, ushort* __restrict__ ybf)
{
    __shared__ float tile[64][65];
    const int r0 = blockIdx.y * 64, c0 = blockIdx.x * 64;
    const int z = blockIdx.z;
    const float* s = yt + (size_t)z * DI * L_DIM;
    const int tx = threadIdx.x & 15, ty = threadIdx.x >> 4;
    #pragma unroll
    for (int p = 0; p < 4; ++p) {
        float4 v = *(const float4*)(s + (size_t)(r0 + ty + p*16) * L_DIM + c0 + tx*4);
        tile[ty + p*16][tx*4+0] = v.x; tile[ty + p*16][tx*4+1] = v.y;
        tile[ty + p*16][tx*4+2] = v.z; tile[ty + p*16][tx*4+3] = v.w;
    }
    __syncthreads();
    #pragma unroll
    for (int p = 0; p < 4; ++p) {
        int oc = ty + p*16;
        int row = z * L_DIM + c0 + oc;
        float4 v = make_float4(tile[tx*4+0][oc], tile[tx*4+1][oc],
                               tile[tx*4+2][oc], tile[tx*4+3][oc]);
        ushort4 gu = *(const ushort4*)(xrb + (size_t)row * (2*DI) + DI + r0 + tx*4);
        float gx = bf2f(gu.x), gy = bf2f(gu.y), gz = bf2f(gu.z), gw = bf2f(gu.w);
        v.x *= gx / (1.f + expf(-gx));
        v.y *= gy / (1.f + expf(-gy));
        v.z *= gz / (1.f + expf(-gz));
        v.w *= gw / (1.f + expf(-gw));
        *(ushort4*)(ybf + (size_t)row * DI + r0 + tx*4) =
            make_ushort4(bf16u(v.x), bf16u(v.y), bf16u(v.z), bf16u(v.w));
    }
}

__device__ __forceinline__ float rl(float v, int lane)
{
    return __int_as_float(__builtin_amdgcn_readlane(__float_as_int(v), lane));
}
__device__ __forceinline__ float exp2_fast(float x)
{
    float r;
    asm("v_exp_f32 %0, %1" : "=v"(r) : "v"(x));
    return r;
}

// ---------------- selective scan v6b: group-loaded B (ds_read2 merge) --------
__global__ __launch_bounds__(256) void k_scan6(const float* __restrict__ dtt,
    const float* __restrict__ xct, const float* __restrict__ Bss,
    const float* __restrict__ A_log, const float* __restrict__ Dp,
    float* __restrict__ yt)
{
    __shared__ float Bsh[64][68];
    const int lane = threadIdx.x & 63;
    const int widx = threadIdx.x >> 6;
    const int b = blockIdx.x >> 9;
    const int d = (blockIdx.x & 511) * 4 + widx;
    const float aL2 = -expf(A_log[(size_t)d * NS + lane]) * 1.44269504f;
    const float Dv = Dp[d];
    const float* dtp = dtt + ((size_t)b * DI + d) * L_DIM;
    const float* xcp = xct + ((size_t)b * DI + d) * L_DIM;
    const float* Bp  = Bss + (size_t)b * L_DIM * NS;
    float* yp = yt + ((size_t)b * DI + d) * L_DIM;
    const int lr = threadIdx.x >> 2;
    const int lc = (threadIdx.x & 3) * 16;
    float h = 0.f;

    for (int t0 = 0; t0 < L_DIM; t0 += 64) {
        const float* bsrc = Bp + (size_t)(t0 + lr) * NS + lc;
        float4 b0 = *(const float4*)(bsrc);
        float4 b1 = *(const float4*)(bsrc + 4);
        float4 b2 = *(const float4*)(bsrc + 8);
        float4 b3 = *(const float4*)(bsrc + 12);
        float dt_v = dtp[t0 + lane];
        float xc_v = xcp[t0 + lane];
        __syncthreads();
        *(float4*)&Bsh[lr][lc]      = b0;
        *(float4*)&Bsh[lr][lc + 4]  = b1;
        *(float4*)&Bsh[lr][lc + 8]  = b2;
        *(float4*)&Bsh[lr][lc + 12] = b3;
        __syncthreads();
        float y_v = 0.f;
        #pragma unroll
        for (int q = 0; q < 64; q += 4) {
            // group-load B for 4 steps (adjacent rows -> ds_read2_b32 merge)
            float Bv0 = Bsh[q+0][lane];
            float Bv1 = Bsh[q+1][lane];
            float Bv2 = Bsh[q+2][lane];
            float Bv3 = Bsh[q+3][lane];
            float s0, s1, s2, s3;
            {
                float p, ad;
                p  = rl(xc_v, q+0) * Bv0;
                ad = exp2_fast(aL2 * rl(dt_v, q+0));
                h = fmaf(ad, h, p); s0 = h;
                p  = rl(xc_v, q+1) * Bv1;
                ad = exp2_fast(aL2 * rl(dt_v, q+1));
                h = fmaf(ad, h, p); s1 = h;
                p  = rl(xc_v, q+2) * Bv2;
                ad = exp2_fast(aL2 * rl(dt_v, q+2));
                h = fmaf(ad, h, p); s2 = h;
                p  = rl(xc_v, q+3) * Bv3;
                ad = exp2_fast(aL2 * rl(dt_v, q+3));
                h = fmaf(ad, h, p); s3 = h;
            }
            int tot0, tot1, tot2, tot3;
            asm("v_add_f32_dpp %0, %0, %0 row_shr:1 row_mask:0xf bank_mask:0xf\n\t"
                "v_add_f32_dpp %1, %1, %1 row_shr:1 row_mask:0xf bank_mask:0xf\n\t"
                "v_add_f32_dpp %2, %2, %2 row_shr:1 row_mask:0xf bank_mask:0xf\n\t"
                "v_add_f32_dpp %3, %3, %3 row_shr:1 row_mask:0xf bank_mask:0xf\n\t"
                "v_add_f32_dpp %0, %0, %0 row_shr:2 row_mask:0xf bank_mask:0xf\n\t"
                "v_add_f32_dpp %1, %1, %1 row_shr:2 row_mask:0xf bank_mask:0xf\n\t"
                "v_add_f32_dpp %2, %2, %2 row_shr:2 row_mask:0xf bank_mask:0xf\n\t"
                "v_add_f32_dpp %3, %3, %3 row_shr:2 row_mask:0xf bank_mask:0xf\n\t"
                "v_add_f32_dpp %0, %0, %0 row_shr:4 row_mask:0xf bank_mask:0xf\n\t"
                "v_add_f32_dpp %1, %1, %1 row_shr:4 row_mask:0xf bank_mask:0xf\n\t"
                "v_add_f32_dpp %2, %2, %2 row_shr:4 row_mask:0xf bank_mask:0xf\n\t"
                "v_add_f32_dpp %3, %3, %3 row_shr:4 row_mask:0xf bank_mask:0xf\n\t"
                "v_add_f32_dpp %0, %0, %0 row_shr:8 row_mask:0xf bank_mask:0xf\n\t"
                "v_add_f32_dpp %1, %1, %1 row_shr:8 row_mask:0xf bank_mask:0xf\n\t"
                "v_add_f32_dpp %2, %2, %2 row_shr:8 row_mask:0xf bank_mask:0xf\n\t"
                "v_add_f32_dpp %3, %3, %3 row_shr:8 row_mask:0xf bank_mask:0xf\n\t"
                "v_add_f32_dpp %0, %0, %0 row_bcast:15 row_mask:0xa bank_mask:0xf\n\t"
                "v_add_f32_dpp %1, %1, %1 row_bcast:15 row_mask:0xa bank_mask:0xf\n\t"
                "v_add_f32_dpp %2, %2, %2 row_bcast:15 row_mask:0xa bank_mask:0xf\n\t"
                "v_add_f32_dpp %3, %3, %3 row_bcast:15 row_mask:0xa bank_mask:0xf\n\t"
                "v_add_f32_dpp %0, %0, %0 row_bcast:31 row_mask:0xc bank_mask:0xf\n\t"
                "v_add_f32_dpp %1, %1, %1 row_bcast:31 row_mask:0xc bank_mask:0xf\n\t"
                "v_add_f32_dpp %2, %2, %2 row_bcast:31 row_mask:0xc bank_mask:0xf\n\t"
                "v_add_f32_dpp %3, %3, %3 row_bcast:31 row_mask:0xc bank_mask:0xf\n\t"
                "v_readlane_b32 %4, %0, 63\n\t"
                "v_readlane_b32 %5, %1, 63\n\t"
                "v_readlane_b32 %6, %2, 63\n\t"
                "v_readlane_b32 %7, %3, 63"
                : "+v"(s0), "+v"(s1), "+v"(s2), "+v"(s3),
                  "=s"(tot0), "=s"(tot1), "=s"(tot2), "=s"(tot3));
            asm("v_writelane_b32 %0, %1, %2"
                : "+v"(y_v) : "s"(tot0), "i"(q+0));
            asm("v_writelane_b32 %0, %1, %2"
                : "+v"(y_v) : "s"(tot1), "i"(q+1));
            asm("v_writelane_b32 %0, %1, %2"
                : "+v"(y_v) : "s"(tot2), "i"(q+2));
            asm("v_writelane_b32 %0, %1, %2"
                : "+v"(y_v) : "s"(tot3), "i"(q+3));
        }
        yp[t0 + lane] = fmaf(Dv, xc_v, y_v);
    }
}

extern "C" void kernel_launch(void* const* d_in, const int* in_sizes, int n_in,
                              void* d_out, int out_size, void* d_ws, size_t ws_size,
                              hipStream_t stream)
{
    const float* x        = (const float*)d_in[0];
    const float* norm_w   = (const float*)d_in[1];
    const float* in_projw = (const float*)d_in[2];
    const float* conv_w   = (const float*)d_in[3];
    const float* conv_b   = (const float*)d_in[4];
    const float* x_projw  = (const float*)d_in[5];
    const float* dt_w     = (const float*)d_in[6];
    const float* dt_b     = (const float*)d_in[7];
    const float* A_log    = (const float*)d_in[8];
    const float* D_param  = (const float*)d_in[9];
    const float* out_projw= (const float*)d_in[10];
    float* out = (float*)d_out;

    float* ws = (float*)d_ws;
    ushort* xr_bf = (ushort*)ws;                    // 8M u16 (16MB)
    float* xc   = ws + (size_t)4*1024*1024;         // 4M f32
    float* dtb  = xc + (size_t)4*1024*1024;         // 4M f32 (yt alias)
    float* Bss  = dtb + (size_t)4*1024*1024;        // 128K f32
    float* dtt  = Bss + 131072;                     // 4M f32
    float* xct  = dtt + (size_t)4*1024*1024;        // 4M f32
    ushort* xn_bf  = (ushort*)(xct + (size_t)4*1024*1024); // 2M u16
    ushort* xc_bf  = xn_bf + (size_t)2*1024*1024;          // 4M u16
    ushort* xpw_bf = xc_bf + (size_t)4*1024*1024;          // 128K u16
    ushort* opw_bf = xpw_bf + 131072;                      // 2M u16
    ushort* inpw_bf = (ushort*)dtt;   // dead before dtt written (post-GEMM1)
    ushort* dtw_bf  = (ushort*)xct;   // dead before xct written (post-GEMM1)
    ushort* y_bf    = (ushort*)xc;    // xc dead after transposes
    float* yt = dtb;

    k_castw<<<5184, 256, 0, stream>>>(in_projw, inpw_bf, dt_w, dtw_bf,
                                      x_projw + (size_t)64*2048, xpw_bf,
                                      out_projw, opw_bf);
    k_rms_xn<<<2048, 256, 0, stream>>>(x, norm_w, xn_bf);
    k_mfma<0><<<dim3(32, 16), 256, 0, stream>>>(xn_bf, inpw_bf, nullptr,
                                                nullptr, xr_bf, nullptr,
                                                nullptr, nullptr, 1024, 4096);
    k_conv<<<4096, 256, 0, stream>>>(xr_bf, conv_w, conv_b, xc, xc_bf);
    k_mfma<1><<<dim3(17, 16), 256, 0, stream>>>(xc_bf, dtw_bf, xpw_bf,
                                                dtb, nullptr, Bss,
                                                dt_b, nullptr, 2048, 2048);
    k_tr4<<<dim3(32, 16, 4), 256, 0, stream>>>(dtb, dtt, xc, xct);
    k_scan6<<<1024, 256, 0, stream>>>(dtt, xct, Bss, A_log, D_param, yt);
    k_trg<<<dim3(16, 32, 2), 256, 0, stream>>>(yt, xr_bf, y_bf);
    k_mfma<2><<<dim3(8, 16), 256, 0, stream>>>(y_bf, opw_bf, nullptr,
                                               out, nullptr, nullptr,
                                               nullptr, x, 2048, 1024);
}

// Round 13
// 273.779 us; speedup vs baseline: 1.2439x; 1.0799x over previous
//
#include <hip/hip_runtime.h>
#include <hip/hip_bf16.h>
#include <math.h>

#define L_DIM 1024
#define DM 1024
#define DI 2048
#define NS 64

typedef __attribute__((ext_vector_type(8))) short short8;
typedef __attribute__((ext_vector_type(4))) float f32x4;

__device__ __forceinline__ ushort bf16u(float f)
{
    unsigned u = __float_as_uint(f);
    unsigned r = (u + 0x7fffu + ((u >> 16) & 1u)) >> 16;
    return (ushort)r;
}
__device__ __forceinline__ float bf2f(ushort u)
{
    return __uint_as_float((unsigned)u << 16);
}

__device__ __forceinline__ void gld16(const ushort* g, const ushort* l)
{
    __builtin_amdgcn_global_load_lds(
        (const __attribute__((address_space(1))) unsigned int*)g,
        (__attribute__((address_space(3))) unsigned int*)l, 16, 0, 0);
}

// -------- fused RMSNorm + bf16 cast ------------------------------------------
__global__ __launch_bounds__(256) void k_rms_xn(const float* __restrict__ x,
    const float* __restrict__ nw, ushort* __restrict__ d)
{
    int row = blockIdx.x;
    const float* xp = x + (size_t)row * DM;
    float4 v = ((const float4*)xp)[threadIdx.x];
    float ss = v.x*v.x + v.y*v.y + v.z*v.z + v.w*v.w;
    #pragma unroll
    for (int m = 32; m; m >>= 1) ss += __shfl_xor(ss, m, 64);
    __shared__ float red[4];
    if ((threadIdx.x & 63) == 0) red[threadIdx.x >> 6] = ss;
    __syncthreads();
    float tot = red[0] + red[1] + red[2] + red[3];
    float ri = rsqrtf(tot * (1.0f / DM) + 1e-6f);
    float4 wv = ((const float4*)nw)[threadIdx.x];
    ((ushort4*)(d + (size_t)row * DM))[threadIdx.x] =
        make_ushort4(bf16u(v.x*ri*wv.x), bf16u(v.y*ri*wv.y),
                     bf16u(v.z*ri*wv.z), bf16u(v.w*ri*wv.w));
}

// ---------------- all weight casts in ONE dispatch ---------------------------
__device__ __forceinline__ void cast8(const float* __restrict__ s,
                                      ushort* __restrict__ d, int i)
{
    float4 a = ((const float4*)s)[2*i], b = ((const float4*)s)[2*i+1];
    ((ushort4*)d)[2*i]   = make_ushort4(bf16u(a.x), bf16u(a.y), bf16u(a.z), bf16u(a.w));
    ((ushort4*)d)[2*i+1] = make_ushort4(bf16u(b.x), bf16u(b.y), bf16u(b.z), bf16u(b.w));
}
__global__ __launch_bounds__(256) void k_castw(
    const float* __restrict__ s0, ushort* __restrict__ d0,
    const float* __restrict__ s1, ushort* __restrict__ d1,
    const float* __restrict__ s2, ushort* __restrict__ d2,
    const float* __restrict__ s3, ushort* __restrict__ d3)
{
    int i = blockIdx.x * 256 + threadIdx.x;
    if (i < 524288)       cast8(s0, d0, i);
    else if (i < 1048576) cast8(s1, d1, i - 524288);
    else if (i < 1064960) cast8(s2, d2, i - 1048576);
    else                  cast8(s3, d3, i - 1064960);
}

// ---------------- MFMA NT GEMM, BK=64, XOR-swizzled LDS, XCD swizzle ---------
template<int MODE>
__global__ __launch_bounds__(256) void k_mfma(
    const ushort* __restrict__ Abf, const ushort* __restrict__ Bbf0,
    const ushort* __restrict__ Bbf1, float* __restrict__ C0,
    ushort* __restrict__ C0b, float* __restrict__ C1,
    const float* __restrict__ bias, const float* __restrict__ skip,
    int Kdim, int ldc)
{
    __shared__ __align__(16) ushort As[128*64];
    __shared__ __align__(16) ushort Bs[128*64];
    const int t = threadIdx.x, w = t >> 6, lane = t & 63;
    const int nwg = gridDim.x * gridDim.y;
    const int orig = blockIdx.y * gridDim.x + blockIdx.x;
    const int swz = (orig & 7) * (nwg >> 3) + (orig >> 3);
    const int nt = swz % gridDim.x, mt = swz / gridDim.x;
    const int mBase = mt * 128, nBase = nt * 128;
    const bool isXP = (MODE == 1) && (nt == 16);
    const ushort* __restrict__ Bbf = isXP ? Bbf1 : Bbf0;
    const int wr = (w >> 1) * 64, wc = (w & 1) * 64;
    const int sR = lane >> 3;
    const int sK = ((lane & 7) ^ sR) * 8;

    f32x4 acc[4][4];
    #pragma unroll
    for (int i = 0; i < 4; ++i)
        #pragma unroll
        for (int j = 0; j < 4; ++j)
            acc[i][j] = (f32x4){0.f, 0.f, 0.f, 0.f};

    for (int kt = 0; kt < Kdim; kt += 64) {
        #pragma unroll
        for (int s = 0; s < 4; ++s) {
            int tr = w*8 + s*32 + sR;
            gld16(Abf + (size_t)(mBase + tr) * Kdim + kt + sK,
                  As + (w*8 + s*32) * 64);
            int gr = isXP ? (tr < 63 ? tr : 63) : (nBase + tr);
            gld16(Bbf + (size_t)gr * Kdim + kt + sK,
                  Bs + (w*8 + s*32) * 64);
        }
        __syncthreads();
        #pragma unroll
        for (int kk = 0; kk < 2; ++kk) {
            short8 af[4], bfr[4];
            #pragma unroll
            for (int f = 0; f < 4; ++f) {
                int ra = wr + f*16 + (lane & 15);
                int ca = (kk*4 + (lane >> 4)) ^ (ra & 7);
                af[f]  = *(const short8*)(As + ra*64 + ca*8);
                int rb2 = wc + f*16 + (lane & 15);
                int cb2 = (kk*4 + (lane >> 4)) ^ (rb2 & 7);
                bfr[f] = *(const short8*)(Bs + rb2*64 + cb2*8);
            }
            #pragma unroll
            for (int mi = 0; mi < 4; ++mi)
                #pragma unroll
                for (int ni = 0; ni < 4; ++ni)
                    acc[mi][ni] = __builtin_amdgcn_mfma_f32_16x16x32_bf16(
                        af[mi], bfr[ni], acc[mi][ni], 0, 0, 0);
        }
        __syncthreads();
    }

    const int rb = (lane >> 4) * 4, cbl = lane & 15;
    #pragma unroll
    for (int mi = 0; mi < 4; ++mi) {
        #pragma unroll
        for (int ni = 0; ni < 4; ++ni) {
            int ltcol = wc + ni*16 + cbl;
            int col = nBase + ltcol;
            #pragma unroll
            for (int j = 0; j < 4; ++j) {
                int row = mBase + wr + mi*16 + rb + j;
                float v = acc[mi][ni][j];
                if constexpr (MODE == 0) {
                    C0b[(size_t)row * ldc + col] = bf16u(v);
                } else if constexpr (MODE == 1) {
                    if (isXP) {
                        if (ltcol < NS) C1[(size_t)row * NS + ltcol] = v;
                    } else {
                        float z = v + bias[col];
                        C0[(size_t)row * ldc + col] =
                            (z > 20.f) ? z : logf(1.f + expf(z));
                    }
                } else {
                    C0[(size_t)row * ldc + col] = v + skip[(size_t)row * ldc + col];
                }
            }
        }
    }
}

// ---------------- causal depthwise conv1d (K=4) + SiLU, bf16 in --------------
__global__ __launch_bounds__(256) void k_conv(const ushort* __restrict__ xrb,
    const float* __restrict__ cw, const float* __restrict__ cb,
    float* __restrict__ xc, ushort* __restrict__ xcb)
{
    int gid = blockIdx.x * 256 + threadIdx.x;
    int d = (gid & 511) * 4;
    int tt = (gid >> 9) & 1023;
    int b = gid >> 19;
    float4 w[4];
    #pragma unroll
    for (int c = 0; c < 4; ++c) w[c] = *(const float4*)(cw + (size_t)(d + c) * 4);
    float4 acc = *(const float4*)(cb + d);
    const ushort* base = xrb + (size_t)b * L_DIM * (2*DI) + d;
    #pragma unroll
    for (int j = 0; j < 4; ++j) {
        int ti = tt - 3 + j;
        if (ti < 0) continue;
        ushort4 xu = *(const ushort4*)(base + (size_t)ti * (2*DI));
        const float* w0 = (const float*)&w[0];
        const float* w1 = (const float*)&w[1];
        const float* w2 = (const float*)&w[2];
        const float* w3 = (const float*)&w[3];
        acc.x = fmaf(w0[j], bf2f(xu.x), acc.x);
        acc.y = fmaf(w1[j], bf2f(xu.y), acc.y);
        acc.z = fmaf(w2[j], bf2f(xu.z), acc.z);
        acc.w = fmaf(w3[j], bf2f(xu.w), acc.w);
    }
    acc.x = acc.x / (1.f + expf(-acc.x));
    acc.y = acc.y / (1.f + expf(-acc.y));
    acc.z = acc.z / (1.f + expf(-acc.z));
    acc.w = acc.w / (1.f + expf(-acc.w));
    size_t o = (size_t)(b * L_DIM + tt) * DI + d;
    *(float4*)(xc + o) = acc;
    *(ushort4*)(xcb + o) = make_ushort4(bf16u(acc.x), bf16u(acc.y),
                                        bf16u(acc.z), bf16u(acc.w));
}

// -------- both transposes in ONE dispatch ------------------------------------
__global__ __launch_bounds__(256) void k_tr4(const float* __restrict__ dtb,
    float* __restrict__ dtt, const float* __restrict__ xc,
    float* __restrict__ xct)
{
    __shared__ float tile[64][65];
    const int r0 = blockIdx.y * 64, c0 = blockIdx.x * 64;
    const int z = blockIdx.z;
    const float* s;
    float* d;
    if (z < 2) { s = dtb + (size_t)z * L_DIM * DI;       d = dtt + (size_t)z * DI * L_DIM; }
    else       { s = xc  + (size_t)(z-2) * L_DIM * DI;   d = xct + (size_t)(z-2) * DI * L_DIM; }
    const int tx = threadIdx.x & 15, ty = threadIdx.x >> 4;
    #pragma unroll
    for (int p = 0; p < 4; ++p) {
        float4 v = *(const float4*)(s + (size_t)(r0 + ty + p*16) * DI + c0 + tx*4);
        tile[ty + p*16][tx*4+0] = v.x; tile[ty + p*16][tx*4+1] = v.y;
        tile[ty + p*16][tx*4+2] = v.z; tile[ty + p*16][tx*4+3] = v.w;
    }
    __syncthreads();
    #pragma unroll
    for (int p = 0; p < 4; ++p) {
        int oc = ty + p*16;
        float4 v = make_float4(tile[tx*4+0][oc], tile[tx*4+1][oc],
                               tile[tx*4+2][oc], tile[tx*4+3][oc]);
        *(float4*)(d + (size_t)(c0 + oc) * L_DIM + r0 + tx*4) = v;
    }
}

// ------ back-transpose + silu(res) gate (bf16 gate) + bf16 out ---------------
__global__ __launch_bounds__(256) void k_trg(const float* __restrict__ yt,
    const ushort* __restrict__ xrb, ushort* __restrict__ ybf)
{
    __shared__ float tile[64][65];
    const int r0 = blockIdx.y * 64, c0 = blockIdx.x * 64;
    const int z = blockIdx.z;
    const float* s = yt + (size_t)z * DI * L_DIM;
    const int tx = threadIdx.x & 15, ty = threadIdx.x >> 4;
    #pragma unroll
    for (int p = 0; p < 4; ++p) {
        float4 v = *(const float4*)(s + (size_t)(r0 + ty + p*16) * L_DIM + c0 + tx*4);
        tile[ty + p*16][tx*4+0] = v.x; tile[ty + p*16][tx*4+1] = v.y;
        tile[ty + p*16][tx*4+2] = v.z; tile[ty + p*16][tx*4+3] = v.w;
    }
    __syncthreads();
    #pragma unroll
    for (int p = 0; p < 4; ++p) {
        int oc = ty + p*16;
        int row = z * L_DIM + c0 + oc;
        float4 v = make_float4(tile[tx*4+0][oc], tile[tx*4+1][oc],
                               tile[tx*4+2][oc], tile[tx*4+3][oc]);
        ushort4 gu = *(const ushort4*)(xrb + (size_t)row * (2*DI) + DI + r0 + tx*4);
        float gx = bf2f(gu.x), gy = bf2f(gu.y), gz = bf2f(gu.z), gw = bf2f(gu.w);
        v.x *= gx / (1.f + expf(-gx));
        v.y *= gy / (1.f + expf(-gy));
        v.z *= gz / (1.f + expf(-gz));
        v.w *= gw / (1.f + expf(-gw));
        *(ushort4*)(ybf + (size_t)row * DI + r0 + tx*4) =
            make_ushort4(bf16u(v.x), bf16u(v.y), bf16u(v.z), bf16u(v.w));
    }
}

__device__ __forceinline__ float rl(float v, int lane)
{
    return __int_as_float(__builtin_amdgcn_readlane(__float_as_int(v), lane));
}
__device__ __forceinline__ float exp2_fast(float x)
{
    float r;
    asm("v_exp_f32 %0, %1" : "=v"(r) : "v"(x));
    return r;
}

// ---------------- selective scan v9: 4-stage DPP + batched P-sum -------------
// Per step: 4-stage DPP leaves 16-lane partial sums in lanes 15/31/47/63;
// those park in Psh[w][t][0..3] (1 masked ds_write). Once per 64 steps each
// lane reads Psh[w][lane][0..3] (coalesced b128, conflict-free) + 3 adds ->
// y for 64 timesteps. Deletes per-step row_bcast x2 + readlane63 + writelane.
__global__ __launch_bounds__(256) void k_scan9(const float* __restrict__ dtt,
    const float* __restrict__ xct, const float* __restrict__ Bss,
    const float* __restrict__ A_log, const float* __restrict__ Dp,
    float* __restrict__ yt)
{
    __shared__ float Bsh[64][68];
    __shared__ __align__(16) float Psh[4][64][4];
    const int lane = threadIdx.x & 63;
    const int widx = threadIdx.x >> 6;
    const int b = blockIdx.x >> 9;
    const int d = (blockIdx.x & 511) * 4 + widx;
    const float aL2 = -expf(A_log[(size_t)d * NS + lane]) * 1.44269504f;
    const float Dv = Dp[d];
    const float* dtp = dtt + ((size_t)b * DI + d) * L_DIM;
    const float* xcp = xct + ((size_t)b * DI + d) * L_DIM;
    const float* Bp  = Bss + (size_t)b * L_DIM * NS;
    float* yp = yt + ((size_t)b * DI + d) * L_DIM;
    const int lr = threadIdx.x >> 2;
    const int lc = (threadIdx.x & 3) * 16;
    const int pg = lane >> 4;
    const bool pwrite = (lane & 15) == 15;
    float h = 0.f;

    for (int t0 = 0; t0 < L_DIM; t0 += 64) {
        const float* bsrc = Bp + (size_t)(t0 + lr) * NS + lc;
        float4 b0 = *(const float4*)(bsrc);
        float4 b1 = *(const float4*)(bsrc + 4);
        float4 b2 = *(const float4*)(bsrc + 8);
        float4 b3 = *(const float4*)(bsrc + 12);
        float dt_v = dtp[t0 + lane];
        float xc_v = xcp[t0 + lane];
        __syncthreads();
        *(float4*)&Bsh[lr][lc]      = b0;
        *(float4*)&Bsh[lr][lc + 4]  = b1;
        *(float4*)&Bsh[lr][lc + 8]  = b2;
        *(float4*)&Bsh[lr][lc + 12] = b3;
        __syncthreads();
        #pragma unroll
        for (int q = 0; q < 64; q += 4) {
            float Bv0 = Bsh[q+0][lane];
            float Bv1 = Bsh[q+1][lane];
            float Bv2 = Bsh[q+2][lane];
            float Bv3 = Bsh[q+3][lane];
            float s0, s1, s2, s3;
            {
                float p, ad;
                p  = rl(xc_v, q+0) * Bv0;
                ad = exp2_fast(aL2 * rl(dt_v, q+0));
                h = fmaf(ad, h, p); s0 = h;
                p  = rl(xc_v, q+1) * Bv1;
                ad = exp2_fast(aL2 * rl(dt_v, q+1));
                h = fmaf(ad, h, p); s1 = h;
                p  = rl(xc_v, q+2) * Bv2;
                ad = exp2_fast(aL2 * rl(dt_v, q+2));
                h = fmaf(ad, h, p); s2 = h;
                p  = rl(xc_v, q+3) * Bv3;
                ad = exp2_fast(aL2 * rl(dt_v, q+3));
                h = fmaf(ad, h, p); s3 = h;
            }
            // 4-stage DPP: lane 15 of each 16-lane group = group partial sum
            asm("v_add_f32_dpp %0, %0, %0 row_shr:1 row_mask:0xf bank_mask:0xf\n\t"
                "v_add_f32_dpp %1, %1, %1 row_shr:1 row_mask:0xf bank_mask:0xf\n\t"
                "v_add_f32_dpp %2, %2, %2 row_shr:1 row_mask:0xf bank_mask:0xf\n\t"
                "v_add_f32_dpp %3, %3, %3 row_shr:1 row_mask:0xf bank_mask:0xf\n\t"
                "v_add_f32_dpp %0, %0, %0 row_shr:2 row_mask:0xf bank_mask:0xf\n\t"
                "v_add_f32_dpp %1, %1, %1 row_shr:2 row_mask:0xf bank_mask:0xf\n\t"
                "v_add_f32_dpp %2, %2, %2 row_shr:2 row_mask:0xf bank_mask:0xf\n\t"
                "v_add_f32_dpp %3, %3, %3 row_shr:2 row_mask:0xf bank_mask:0xf\n\t"
                "v_add_f32_dpp %0, %0, %0 row_shr:4 row_mask:0xf bank_mask:0xf\n\t"
                "v_add_f32_dpp %1, %1, %1 row_shr:4 row_mask:0xf bank_mask:0xf\n\t"
                "v_add_f32_dpp %2, %2, %2 row_shr:4 row_mask:0xf bank_mask:0xf\n\t"
                "v_add_f32_dpp %3, %3, %3 row_shr:4 row_mask:0xf bank_mask:0xf\n\t"
                "v_add_f32_dpp %0, %0, %0 row_shr:8 row_mask:0xf bank_mask:0xf\n\t"
                "v_add_f32_dpp %1, %1, %1 row_shr:8 row_mask:0xf bank_mask:0xf\n\t"
                "v_add_f32_dpp %2, %2, %2 row_shr:8 row_mask:0xf bank_mask:0xf\n\t"
                "v_add_f32_dpp %3, %3, %3 row_shr:8 row_mask:0xf bank_mask:0xf"
                : "+v"(s0), "+v"(s1), "+v"(s2), "+v"(s3));
            if (pwrite) {
                Psh[widx][q+0][pg] = s0;
                Psh[widx][q+1][pg] = s1;
                Psh[widx][q+2][pg] = s2;
                Psh[widx][q+3][pg] = s3;
            }
        }
        asm volatile("s_waitcnt lgkmcnt(0)" ::: "memory");
        __builtin_amdgcn_sched_barrier(0);
        float4 pv = *(const float4*)&Psh[widx][lane][0];
        yp[t0 + lane] = fmaf(Dv, xc_v, (pv.x + pv.y) + (pv.z + pv.w));
    }
}

extern "C" void kernel_launch(void* const* d_in, const int* in_sizes, int n_in,
                              void* d_out, int out_size, void* d_ws, size_t ws_size,
                              hipStream_t stream)
{
    const float* x        = (const float*)d_in[0];
    const float* norm_w   = (const float*)d_in[1];
    const float* in_projw = (const float*)d_in[2];
    const float* conv_w   = (const float*)d_in[3];
    const float* conv_b   = (const float*)d_in[4];
    const float* x_projw  = (const float*)d_in[5];
    const float* dt_w     = (const float*)d_in[6];
    const float* dt_b     = (const float*)d_in[7];
    const float* A_log    = (const float*)d_in[8];
    const float* D_param  = (const float*)d_in[9];
    const float* out_projw= (const float*)d_in[10];
    float* out = (float*)d_out;

    float* ws = (float*)d_ws;
    ushort* xr_bf = (ushort*)ws;                    // 8M u16 (16MB)
    float* xc   = ws + (size_t)4*1024*1024;         // 4M f32
    float* dtb  = xc + (size_t)4*1024*1024;         // 4M f32 (yt alias)
    float* Bss  = dtb + (size_t)4*1024*1024;        // 128K f32
    float* dtt  = Bss + 131072;                     // 4M f32
    float* xct  = dtt + (size_t)4*1024*1024;        // 4M f32
    ushort* xn_bf  = (ushort*)(xct + (size_t)4*1024*1024); // 2M u16
    ushort* xc_bf  = xn_bf + (size_t)2*1024*1024;          // 4M u16
    ushort* xpw_bf = xc_bf + (size_t)4*1024*1024;          // 128K u16
    ushort* opw_bf = xpw_bf + 131072;                      // 2M u16
    ushort* inpw_bf = (ushort*)dtt;   // dead before dtt written (post-GEMM1)
    ushort* dtw_bf  = (ushort*)xct;   // dead before xct written (post-GEMM1)
    ushort* y_bf    = (ushort*)xc;    // xc dead after transposes
    float* yt = dtb;

    k_castw<<<5184, 256, 0, stream>>>(in_projw, inpw_bf, dt_w, dtw_bf,
                                      x_projw + (size_t)64*2048, xpw_bf,
                                      out_projw, opw_bf);
    k_rms_xn<<<2048, 256, 0, stream>>>(x, norm_w, xn_bf);
    k_mfma<0><<<dim3(32, 16), 256, 0, stream>>>(xn_bf, inpw_bf, nullptr,
                                                nullptr, xr_bf, nullptr,
                                                nullptr, nullptr, 1024, 4096);
    k_conv<<<4096, 256, 0, stream>>>(xr_bf, conv_w, conv_b, xc, xc_bf);
    k_mfma<1><<<dim3(17, 16), 256, 0, stream>>>(xc_bf, dtw_bf, xpw_bf,
                                                dtb, nullptr, Bss,
                                                dt_b, nullptr, 2048, 2048);
    k_tr4<<<dim3(32, 16, 4), 256, 0, stream>>>(dtb, dtt, xc, xct);
    k_scan9<<<1024, 256, 0, stream>>>(dtt, xct, Bss, A_log, D_param, yt);
    k_trg<<<dim3(16, 32, 2), 256, 0, stream>>>(yt, xr_bf, y_bf);
    k_mfma<2><<<dim3(8, 16), 256, 0, stream>>>(y_bf, opw_bf, nullptr,
                                               out, nullptr, nullptr,
                                               nullptr, x, 2048, 1024);
}

// Round 14
// 259.504 us; speedup vs baseline: 1.3123x; 1.0550x over previous
//
#include <hip/hip_runtime.h>
#include <hip/hip_bf16.h>
#include <math.h>

#define L_DIM 1024
#define DM 1024
#define DI 2048
#define NS 64

typedef __attribute__((ext_vector_type(8))) short short8;
typedef __attribute__((ext_vector_type(4))) float f32x4;

__device__ __forceinline__ ushort bf16u(float f)
{
    unsigned u = __float_as_uint(f);
    unsigned r = (u + 0x7fffu + ((u >> 16) & 1u)) >> 16;
    return (ushort)r;
}
__device__ __forceinline__ float bf2f(ushort u)
{
    return __uint_as_float((unsigned)u << 16);
}

__device__ __forceinline__ void gld16(const ushort* g, const ushort* l)
{
    __builtin_amdgcn_global_load_lds(
        (const __attribute__((address_space(1))) unsigned int*)g,
        (__attribute__((address_space(3))) unsigned int*)l, 16, 0, 0);
}

// -------- fused RMSNorm + bf16 cast ------------------------------------------
__global__ __launch_bounds__(256) void k_rms_xn(const float* __restrict__ x,
    const float* __restrict__ nw, ushort* __restrict__ d)
{
    int row = blockIdx.x;
    const float* xp = x + (size_t)row * DM;
    float4 v = ((const float4*)xp)[threadIdx.x];
    float ss = v.x*v.x + v.y*v.y + v.z*v.z + v.w*v.w;
    #pragma unroll
    for (int m = 32; m; m >>= 1) ss += __shfl_xor(ss, m, 64);
    __shared__ float red[4];
    if ((threadIdx.x & 63) == 0) red[threadIdx.x >> 6] = ss;
    __syncthreads();
    float tot = red[0] + red[1] + red[2] + red[3];
    float ri = rsqrtf(tot * (1.0f / DM) + 1e-6f);
    float4 wv = ((const float4*)nw)[threadIdx.x];
    ((ushort4*)(d + (size_t)row * DM))[threadIdx.x] =
        make_ushort4(bf16u(v.x*ri*wv.x), bf16u(v.y*ri*wv.y),
                     bf16u(v.z*ri*wv.z), bf16u(v.w*ri*wv.w));
}

// ---------------- all weight casts in ONE dispatch ---------------------------
__device__ __forceinline__ void cast8(const float* __restrict__ s,
                                      ushort* __restrict__ d, int i)
{
    float4 a = ((const float4*)s)[2*i], b = ((const float4*)s)[2*i+1];
    ((ushort4*)d)[2*i]   = make_ushort4(bf16u(a.x), bf16u(a.y), bf16u(a.z), bf16u(a.w));
    ((ushort4*)d)[2*i+1] = make_ushort4(bf16u(b.x), bf16u(b.y), bf16u(b.z), bf16u(b.w));
}
__global__ __launch_bounds__(256) void k_castw(
    const float* __restrict__ s0, ushort* __restrict__ d0,
    const float* __restrict__ s1, ushort* __restrict__ d1,
    const float* __restrict__ s2, ushort* __restrict__ d2,
    const float* __restrict__ s3, ushort* __restrict__ d3)
{
    int i = blockIdx.x * 256 + threadIdx.x;
    if (i < 524288)       cast8(s0, d0, i);
    else if (i < 1048576) cast8(s1, d1, i - 524288);
    else if (i < 1064960) cast8(s2, d2, i - 1048576);
    else                  cast8(s3, d3, i - 1064960);
}

// ------- MFMA NT GEMM, BM templated (128 or 64) x 128, BK=64, swizzled -------
template<int MODE, int BM>
__global__ __launch_bounds__(256) void k_mfma(
    const ushort* __restrict__ Abf, const ushort* __restrict__ Bbf0,
    const ushort* __restrict__ Bbf1, float* __restrict__ C0,
    ushort* __restrict__ C0b, float* __restrict__ C1,
    const float* __restrict__ bias, const float* __restrict__ skip,
    int Kdim, int ldc)
{
    constexpr int NI = (BM == 128) ? 4 : 2;
    constexpr int SA = BM / 32;
    __shared__ __align__(16) ushort As[BM*64];
    __shared__ __align__(16) ushort Bs[128*64];
    const int t = threadIdx.x, w = t >> 6, lane = t & 63;
    const int nwg = gridDim.x * gridDim.y;
    const int orig = blockIdx.y * gridDim.x + blockIdx.x;
    const int swz = (orig & 7) * (nwg >> 3) + (orig >> 3);
    const int nt = swz % gridDim.x, mt = swz / gridDim.x;
    const int mBase = mt * BM, nBase = nt * 128;
    const bool isXP = (MODE == 1) && (nt == 16);
    const ushort* __restrict__ Bbf = isXP ? Bbf1 : Bbf0;
    const int wr = (BM == 128) ? (w >> 1) * 64 : 0;
    const int wc = (BM == 128) ? (w & 1) * 64 : w * 32;
    const int sR = lane >> 3;
    const int sK = ((lane & 7) ^ sR) * 8;

    f32x4 acc[4][NI];
    #pragma unroll
    for (int i = 0; i < 4; ++i)
        #pragma unroll
        for (int j = 0; j < NI; ++j)
            acc[i][j] = (f32x4){0.f, 0.f, 0.f, 0.f};

    for (int kt = 0; kt < Kdim; kt += 64) {
        #pragma unroll
        for (int s = 0; s < SA; ++s) {
            int tr = w*8 + s*32 + sR;
            gld16(Abf + (size_t)(mBase + tr) * Kdim + kt + sK,
                  As + (w*8 + s*32) * 64);
        }
        #pragma unroll
        for (int s = 0; s < 4; ++s) {
            int tr = w*8 + s*32 + sR;
            int gr = isXP ? (tr < 63 ? tr : 63) : (nBase + tr);
            gld16(Bbf + (size_t)gr * Kdim + kt + sK,
                  Bs + (w*8 + s*32) * 64);
        }
        __syncthreads();
        #pragma unroll
        for (int kk = 0; kk < 2; ++kk) {
            short8 af[4], bfr[NI];
            #pragma unroll
            for (int f = 0; f < 4; ++f) {
                int ra = wr + f*16 + (lane & 15);
                int ca = (kk*4 + (lane >> 4)) ^ (ra & 7);
                af[f] = *(const short8*)(As + ra*64 + ca*8);
            }
            #pragma unroll
            for (int f = 0; f < NI; ++f) {
                int rb2 = wc + f*16 + (lane & 15);
                int cb2 = (kk*4 + (lane >> 4)) ^ (rb2 & 7);
                bfr[f] = *(const short8*)(Bs + rb2*64 + cb2*8);
            }
            #pragma unroll
            for (int mi = 0; mi < 4; ++mi)
                #pragma unroll
                for (int ni = 0; ni < NI; ++ni)
                    acc[mi][ni] = __builtin_amdgcn_mfma_f32_16x16x32_bf16(
                        af[mi], bfr[ni], acc[mi][ni], 0, 0, 0);
        }
        __syncthreads();
    }

    const int rb = (lane >> 4) * 4, cbl = lane & 15;
    #pragma unroll
    for (int mi = 0; mi < 4; ++mi) {
        #pragma unroll
        for (int ni = 0; ni < NI; ++ni) {
            int ltcol = wc + ni*16 + cbl;
            int col = nBase + ltcol;
            #pragma unroll
            for (int j = 0; j < 4; ++j) {
                int row = mBase + wr + mi*16 + rb + j;
                float v = acc[mi][ni][j];
                if constexpr (MODE == 0) {
                    C0b[(size_t)row * ldc + col] = bf16u(v);
                } else if constexpr (MODE == 1) {
                    if (isXP) {
                        if (ltcol < NS) C1[(size_t)row * NS + ltcol] = v;
                    } else {
                        float z = v + bias[col];
                        C0[(size_t)row * ldc + col] =
                            (z > 20.f) ? z : logf(1.f + expf(z));
                    }
                } else {
                    C0[(size_t)row * ldc + col] = v + skip[(size_t)row * ldc + col];
                }
            }
        }
    }
}

// ---------------- causal depthwise conv1d (K=4) + SiLU, bf16 in --------------
__global__ __launch_bounds__(256) void k_conv(const ushort* __restrict__ xrb,
    const float* __restrict__ cw, const float* __restrict__ cb,
    float* __restrict__ xc, ushort* __restrict__ xcb)
{
    int gid = blockIdx.x * 256 + threadIdx.x;
    int d = (gid & 511) * 4;
    int tt = (gid >> 9) & 1023;
    int b = gid >> 19;
    float4 w[4];
    #pragma unroll
    for (int c = 0; c < 4; ++c) w[c] = *(const float4*)(cw + (size_t)(d + c) * 4);
    float4 acc = *(const float4*)(cb + d);
    const ushort* base = xrb + (size_t)b * L_DIM * (2*DI) + d;
    #pragma unroll
    for (int j = 0; j < 4; ++j) {
        int ti = tt - 3 + j;
        if (ti < 0) continue;
        ushort4 xu = *(const ushort4*)(base + (size_t)ti * (2*DI));
        const float* w0 = (const float*)&w[0];
        const float* w1 = (const float*)&w[1];
        const float* w2 = (const float*)&w[2];
        const float* w3 = (const float*)&w[3];
        acc.x = fmaf(w0[j], bf2f(xu.x), acc.x);
        acc.y = fmaf(w1[j], bf2f(xu.y), acc.y);
        acc.z = fmaf(w2[j], bf2f(xu.z), acc.z);
        acc.w = fmaf(w3[j], bf2f(xu.w), acc.w);
    }
    acc.x = acc.x / (1.f + expf(-acc.x));
    acc.y = acc.y / (1.f + expf(-acc.y));
    acc.z = acc.z / (1.f + expf(-acc.z));
    acc.w = acc.w / (1.f + expf(-acc.w));
    size_t o = (size_t)(b * L_DIM + tt) * DI + d;
    *(float4*)(xc + o) = acc;
    *(ushort4*)(xcb + o) = make_ushort4(bf16u(acc.x), bf16u(acc.y),
                                        bf16u(acc.z), bf16u(acc.w));
}

// -------- both transposes in ONE dispatch ------------------------------------
__global__ __launch_bounds__(256) void k_tr4(const float* __restrict__ dtb,
    float* __restrict__ dtt, const float* __restrict__ xc,
    float* __restrict__ xct)
{
    __shared__ float tile[64][65];
    const int r0 = blockIdx.y * 64, c0 = blockIdx.x * 64;
    const int z = blockIdx.z;
    const float* s;
    float* d;
    if (z < 2) { s = dtb + (size_t)z * L_DIM * DI;       d = dtt + (size_t)z * DI * L_DIM; }
    else       { s = xc  + (size_t)(z-2) * L_DIM * DI;   d = xct + (size_t)(z-2) * DI * L_DIM; }
    const int tx = threadIdx.x & 15, ty = threadIdx.x >> 4;
    #pragma unroll
    for (int p = 0; p < 4; ++p) {
        float4 v = *(const float4*)(s + (size_t)(r0 + ty + p*16) * DI + c0 + tx*4);
        tile[ty + p*16][tx*4+0] = v.x; tile[ty + p*16][tx*4+1] = v.y;
        tile[ty + p*16][tx*4+2] = v.z; tile[ty + p*16][tx*4+3] = v.w;
    }
    __syncthreads();
    #pragma unroll
    for (int p = 0; p < 4; ++p) {
        int oc = ty + p*16;
        float4 v = make_float4(tile[tx*4+0][oc], tile[tx*4+1][oc],
                               tile[tx*4+2][oc], tile[tx*4+3][oc]);
        *(float4*)(d + (size_t)(c0 + oc) * L_DIM + r0 + tx*4) = v;
    }
}

// ------ back-transpose + silu(res) gate (bf16 gate) + bf16 out ---------------
__global__ __launch_bounds__(256) void k_trg(const float* __restrict__ yt,
    const ushort* __restrict__ xrb, ushort* __restrict__ ybf)
{
    __shared__ float tile[64][65];
    const int r0 = blockIdx.y * 64, c0 = blockIdx.x * 64;
    const int z = blockIdx.z;
    const float* s = yt + (size_t)z * DI * L_DIM;
    const int tx = threadIdx.x & 15, ty = threadIdx.x >> 4;
    #pragma unroll
    for (int p = 0; p < 4; ++p) {
        float4 v = *(const float4*)(s + (size_t)(r0 + ty + p*16) * L_DIM + c0 + tx*4);
        tile[ty + p*16][tx*4+0] = v.x; tile[ty + p*16][tx*4+1] = v.y;
        tile[ty + p*16][tx*4+2] = v.z; tile[ty + p*16][tx*4+3] = v.w;
    }
    __syncthreads();
    #pragma unroll
    for (int p = 0; p < 4; ++p) {
        int oc = ty + p*16;
        int row = z * L_DIM + c0 + oc;
        float4 v = make_float4(tile[tx*4+0][oc], tile[tx*4+1][oc],
                               tile[tx*4+2][oc], tile[tx*4+3][oc]);
        ushort4 gu = *(const ushort4*)(xrb + (size_t)row * (2*DI) + DI + r0 + tx*4);
        float gx = bf2f(gu.x), gy = bf2f(gu.y), gz = bf2f(gu.z), gw = bf2f(gu.w);
        v.x *= gx / (1.f + expf(-gx));
        v.y *= gy / (1.f + expf(-gy));
        v.z *= gz / (1.f + expf(-gz));
        v.w *= gw / (1.f + expf(-gw));
        *(ushort4*)(ybf + (size_t)row * DI + r0 + tx*4) =
            make_ushort4(bf16u(v.x), bf16u(v.y), bf16u(v.z), bf16u(v.w));
    }
}

__device__ __forceinline__ float rl(float v, int lane)
{
    return __int_as_float(__builtin_amdgcn_readlane(__float_as_int(v), lane));
}
__device__ __forceinline__ float exp2_fast(float x)
{
    float r;
    asm("v_exp_f32 %0, %1" : "=v"(r) : "v"(x));
    return r;
}

// ---------------- selective scan v9b: 3-stage DPP + batched P-sum ------------
// Per step: 3-stage DPP leaves 8-lane partials in lanes 7,15,...,63; park in
// Psh[w][t][0..7] (1 masked ds_write). Per 64 steps each lane reads its
// Psh[w][lane][0..7] (2x b128) + 7 adds -> y for 64 timesteps.
__global__ __launch_bounds__(256) void k_scan9(const float* __restrict__ dtt,
    const float* __restrict__ xct, const float* __restrict__ Bss,
    const float* __restrict__ A_log, const float* __restrict__ Dp,
    float* __restrict__ yt)
{
    __shared__ float Bsh[64][68];
    __shared__ __align__(16) float Psh[4][64][8];
    const int lane = threadIdx.x & 63;
    const int widx = threadIdx.x >> 6;
    const int b = blockIdx.x >> 9;
    const int d = (blockIdx.x & 511) * 4 + widx;
    const float aL2 = -expf(A_log[(size_t)d * NS + lane]) * 1.44269504f;
    const float Dv = Dp[d];
    const float* dtp = dtt + ((size_t)b * DI + d) * L_DIM;
    const float* xcp = xct + ((size_t)b * DI + d) * L_DIM;
    const float* Bp  = Bss + (size_t)b * L_DIM * NS;
    float* yp = yt + ((size_t)b * DI + d) * L_DIM;
    const int lr = threadIdx.x >> 2;
    const int lc = (threadIdx.x & 3) * 16;
    const int pg = lane >> 3;
    const bool pwrite = (lane & 7) == 7;
    float h = 0.f;

    for (int t0 = 0; t0 < L_DIM; t0 += 64) {
        const float* bsrc = Bp + (size_t)(t0 + lr) * NS + lc;
        float4 b0 = *(const float4*)(bsrc);
        float4 b1 = *(const float4*)(bsrc + 4);
        float4 b2 = *(const float4*)(bsrc + 8);
        float4 b3 = *(const float4*)(bsrc + 12);
        float dt_v = dtp[t0 + lane];
        float xc_v = xcp[t0 + lane];
        __syncthreads();
        *(float4*)&Bsh[lr][lc]      = b0;
        *(float4*)&Bsh[lr][lc + 4]  = b1;
        *(float4*)&Bsh[lr][lc + 8]  = b2;
        *(float4*)&Bsh[lr][lc + 12] = b3;
        __syncthreads();
        #pragma unroll
        for (int q = 0; q < 64; q += 4) {
            float Bv0 = Bsh[q+0][lane];
            float Bv1 = Bsh[q+1][lane];
            float Bv2 = Bsh[q+2][lane];
            float Bv3 = Bsh[q+3][lane];
            float s0, s1, s2, s3;
            {
                float p, ad;
                p  = rl(xc_v, q+0) * Bv0;
                ad = exp2_fast(aL2 * rl(dt_v, q+0));
                h = fmaf(ad, h, p); s0 = h;
                p  = rl(xc_v, q+1) * Bv1;
                ad = exp2_fast(aL2 * rl(dt_v, q+1));
                h = fmaf(ad, h, p); s1 = h;
                p  = rl(xc_v, q+2) * Bv2;
                ad = exp2_fast(aL2 * rl(dt_v, q+2));
                h = fmaf(ad, h, p); s2 = h;
                p  = rl(xc_v, q+3) * Bv3;
                ad = exp2_fast(aL2 * rl(dt_v, q+3));
                h = fmaf(ad, h, p); s3 = h;
            }
            // 3-stage DPP: lane 8k+7 = partial sum of lanes 8k..8k+7
            asm("v_add_f32_dpp %0, %0, %0 row_shr:1 row_mask:0xf bank_mask:0xf\n\t"
                "v_add_f32_dpp %1, %1, %1 row_shr:1 row_mask:0xf bank_mask:0xf\n\t"
                "v_add_f32_dpp %2, %2, %2 row_shr:1 row_mask:0xf bank_mask:0xf\n\t"
                "v_add_f32_dpp %3, %3, %3 row_shr:1 row_mask:0xf bank_mask:0xf\n\t"
                "v_add_f32_dpp %0, %0, %0 row_shr:2 row_mask:0xf bank_mask:0xf\n\t"
                "v_add_f32_dpp %1, %1, %1 row_shr:2 row_mask:0xf bank_mask:0xf\n\t"
                "v_add_f32_dpp %2, %2, %2 row_shr:2 row_mask:0xf bank_mask:0xf\n\t"
                "v_add_f32_dpp %3, %3, %3 row_shr:2 row_mask:0xf bank_mask:0xf\n\t"
                "v_add_f32_dpp %0, %0, %0 row_shr:4 row_mask:0xf bank_mask:0xf\n\t"
                "v_add_f32_dpp %1, %1, %1 row_shr:4 row_mask:0xf bank_mask:0xf\n\t"
                "v_add_f32_dpp %2, %2, %2 row_shr:4 row_mask:0xf bank_mask:0xf\n\t"
                "v_add_f32_dpp %3, %3, %3 row_shr:4 row_mask:0xf bank_mask:0xf"
                : "+v"(s0), "+v"(s1), "+v"(s2), "+v"(s3));
            if (pwrite) {
                Psh[widx][q+0][pg] = s0;
                Psh[widx][q+1][pg] = s1;
                Psh[widx][q+2][pg] = s2;
                Psh[widx][q+3][pg] = s3;
            }
        }
        asm volatile("s_waitcnt lgkmcnt(0)" ::: "memory");
        __builtin_amdgcn_sched_barrier(0);
        float4 p0 = *(const float4*)&Psh[widx][lane][0];
        float4 p1 = *(const float4*)&Psh[widx][lane][4];
        float sum = ((p0.x + p0.y) + (p0.z + p0.w))
                  + ((p1.x + p1.y) + (p1.z + p1.w));
        yp[t0 + lane] = fmaf(Dv, xc_v, sum);
    }
}

extern "C" void kernel_launch(void* const* d_in, const int* in_sizes, int n_in,
                              void* d_out, int out_size, void* d_ws, size_t ws_size,
                              hipStream_t stream)
{
    const float* x        = (const float*)d_in[0];
    const float* norm_w   = (const float*)d_in[1];
    const float* in_projw = (const float*)d_in[2];
    const float* conv_w   = (const float*)d_in[3];
    const float* conv_b   = (const float*)d_in[4];
    const float* x_projw  = (const float*)d_in[5];
    const float* dt_w     = (const float*)d_in[6];
    const float* dt_b     = (const float*)d_in[7];
    const float* A_log    = (const float*)d_in[8];
    const float* D_param  = (const float*)d_in[9];
    const float* out_projw= (const float*)d_in[10];
    float* out = (float*)d_out;

    float* ws = (float*)d_ws;
    ushort* xr_bf = (ushort*)ws;                    // 8M u16 (16MB)
    float* xc   = ws + (size_t)4*1024*1024;         // 4M f32
    float* dtb  = xc + (size_t)4*1024*1024;         // 4M f32 (yt alias)
    float* Bss  = dtb + (size_t)4*1024*1024;        // 128K f32
    float* dtt  = Bss + 131072;                     // 4M f32
    float* xct  = dtt + (size_t)4*1024*1024;        // 4M f32
    ushort* xn_bf  = (ushort*)(xct + (size_t)4*1024*1024); // 2M u16
    ushort* xc_bf  = xn_bf + (size_t)2*1024*1024;          // 4M u16
    ushort* xpw_bf = xc_bf + (size_t)4*1024*1024;          // 128K u16
    ushort* opw_bf = xpw_bf + 131072;                      // 2M u16
    ushort* inpw_bf = (ushort*)dtt;   // dead before dtt written (post-GEMM1)
    ushort* dtw_bf  = (ushort*)xct;   // dead before xct written (post-GEMM1)
    ushort* y_bf    = (ushort*)xc;    // xc dead after transposes
    float* yt = dtb;

    k_castw<<<5184, 256, 0, stream>>>(in_projw, inpw_bf, dt_w, dtw_bf,
                                      x_projw + (size_t)64*2048, xpw_bf,
                                      out_projw, opw_bf);
    k_rms_xn<<<2048, 256, 0, stream>>>(x, norm_w, xn_bf);
    k_mfma<0,128><<<dim3(32, 16), 256, 0, stream>>>(xn_bf, inpw_bf, nullptr,
                                                nullptr, xr_bf, nullptr,
                                                nullptr, nullptr, 1024, 4096);
    k_conv<<<4096, 256, 0, stream>>>(xr_bf, conv_w, conv_b, xc, xc_bf);
    k_mfma<1,128><<<dim3(17, 16), 256, 0, stream>>>(xc_bf, dtw_bf, xpw_bf,
                                                dtb, nullptr, Bss,
                                                dt_b, nullptr, 2048, 2048);
    k_tr4<<<dim3(32, 16, 4), 256, 0, stream>>>(dtb, dtt, xc, xct);
    k_scan9<<<1024, 256, 0, stream>>>(dtt, xct, Bss, A_log, D_param, yt);
    k_trg<<<dim3(16, 32, 2), 256, 0, stream>>>(yt, xr_bf, y_bf);
    k_mfma<2,64><<<dim3(8, 32), 256, 0, stream>>>(y_bf, opw_bf, nullptr,
                                               out, nullptr, nullptr,
                                               nullptr, x, 2048, 1024);
}

// Round 15
// 253.853 us; speedup vs baseline: 1.3415x; 1.0223x over previous
//
#include <hip/hip_runtime.h>
#include <hip/hip_bf16.h>
#include <math.h>

#define L_DIM 1024
#define DM 1024
#define DI 2048
#define NS 64

typedef __attribute__((ext_vector_type(8))) short short8;
typedef __attribute__((ext_vector_type(4))) float f32x4;

__device__ __forceinline__ ushort bf16u(float f)
{
    unsigned u = __float_as_uint(f);
    unsigned r = (u + 0x7fffu + ((u >> 16) & 1u)) >> 16;
    return (ushort)r;
}
__device__ __forceinline__ float bf2f(ushort u)
{
    return __uint_as_float((unsigned)u << 16);
}

__device__ __forceinline__ void gld16(const ushort* g, const ushort* l)
{
    __builtin_amdgcn_global_load_lds(
        (const __attribute__((address_space(1))) unsigned int*)g,
        (__attribute__((address_space(3))) unsigned int*)l, 16, 0, 0);
}

// -------- fused RMSNorm + bf16 cast ------------------------------------------
__global__ __launch_bounds__(256) void k_rms_xn(const float* __restrict__ x,
    const float* __restrict__ nw, ushort* __restrict__ d)
{
    int row = blockIdx.x;
    const float* xp = x + (size_t)row * DM;
    float4 v = ((const float4*)xp)[threadIdx.x];
    float ss = v.x*v.x + v.y*v.y + v.z*v.z + v.w*v.w;
    #pragma unroll
    for (int m = 32; m; m >>= 1) ss += __shfl_xor(ss, m, 64);
    __shared__ float red[4];
    if ((threadIdx.x & 63) == 0) red[threadIdx.x >> 6] = ss;
    __syncthreads();
    float tot = red[0] + red[1] + red[2] + red[3];
    float ri = rsqrtf(tot * (1.0f / DM) + 1e-6f);
    float4 wv = ((const float4*)nw)[threadIdx.x];
    ((ushort4*)(d + (size_t)row * DM))[threadIdx.x] =
        make_ushort4(bf16u(v.x*ri*wv.x), bf16u(v.y*ri*wv.y),
                     bf16u(v.z*ri*wv.z), bf16u(v.w*ri*wv.w));
}

// ---------------- all weight casts in ONE dispatch ---------------------------
__device__ __forceinline__ void cast8(const float* __restrict__ s,
                                      ushort* __restrict__ d, int i)
{
    float4 a = ((const float4*)s)[2*i], b = ((const float4*)s)[2*i+1];
    ((ushort4*)d)[2*i]   = make_ushort4(bf16u(a.x), bf16u(a.y), bf16u(a.z), bf16u(a.w));
    ((ushort4*)d)[2*i+1] = make_ushort4(bf16u(b.x), bf16u(b.y), bf16u(b.z), bf16u(b.w));
}
__global__ __launch_bounds__(256) void k_castw(
    const float* __restrict__ s0, ushort* __restrict__ d0,
    const float* __restrict__ s1, ushort* __restrict__ d1,
    const float* __restrict__ s2, ushort* __restrict__ d2,
    const float* __restrict__ s3, ushort* __restrict__ d3)
{
    int i = blockIdx.x * 256 + threadIdx.x;
    if (i < 524288)       cast8(s0, d0, i);
    else if (i < 1048576) cast8(s1, d1, i - 524288);
    else if (i < 1064960) cast8(s2, d2, i - 1048576);
    else                  cast8(s3, d3, i - 1064960);
}

// ------- MFMA NT GEMM, BM templated (128 or 64) x 128, BK=64, swizzled -------
// MODE 0: bf16 out (C0b). MODE 1: non-XP -> bf16 softplus dt (C0b); XP -> f32 Bss (C1).
// MODE 2: f32 out + skip (C0).
template<int MODE, int BM>
__global__ __launch_bounds__(256) void k_mfma(
    const ushort* __restrict__ Abf, const ushort* __restrict__ Bbf0,
    const ushort* __restrict__ Bbf1, float* __restrict__ C0,
    ushort* __restrict__ C0b, float* __restrict__ C1,
    const float* __restrict__ bias, const float* __restrict__ skip,
    int Kdim, int ldc)
{
    constexpr int NI = (BM == 128) ? 4 : 2;
    constexpr int SA = BM / 32;
    __shared__ __align__(16) ushort As[BM*64];
    __shared__ __align__(16) ushort Bs[128*64];
    const int t = threadIdx.x, w = t >> 6, lane = t & 63;
    const int nwg = gridDim.x * gridDim.y;
    const int orig = blockIdx.y * gridDim.x + blockIdx.x;
    const int swz = (orig & 7) * (nwg >> 3) + (orig >> 3);
    const int nt = swz % gridDim.x, mt = swz / gridDim.x;
    const int mBase = mt * BM, nBase = nt * 128;
    const bool isXP = (MODE == 1) && (nt == 16);
    const ushort* __restrict__ Bbf = isXP ? Bbf1 : Bbf0;
    const int wr = (BM == 128) ? (w >> 1) * 64 : 0;
    const int wc = (BM == 128) ? (w & 1) * 64 : w * 32;
    const int sR = lane >> 3;
    const int sK = ((lane & 7) ^ sR) * 8;

    f32x4 acc[4][NI];
    #pragma unroll
    for (int i = 0; i < 4; ++i)
        #pragma unroll
        for (int j = 0; j < NI; ++j)
            acc[i][j] = (f32x4){0.f, 0.f, 0.f, 0.f};

    for (int kt = 0; kt < Kdim; kt += 64) {
        #pragma unroll
        for (int s = 0; s < SA; ++s) {
            int tr = w*8 + s*32 + sR;
            gld16(Abf + (size_t)(mBase + tr) * Kdim + kt + sK,
                  As + (w*8 + s*32) * 64);
        }
        #pragma unroll
        for (int s = 0; s < 4; ++s) {
            int tr = w*8 + s*32 + sR;
            int gr = isXP ? (tr < 63 ? tr : 63) : (nBase + tr);
            gld16(Bbf + (size_t)gr * Kdim + kt + sK,
                  Bs + (w*8 + s*32) * 64);
        }
        __syncthreads();
        #pragma unroll
        for (int kk = 0; kk < 2; ++kk) {
            short8 af[4], bfr[NI];
            #pragma unroll
            for (int f = 0; f < 4; ++f) {
                int ra = wr + f*16 + (lane & 15);
                int ca = (kk*4 + (lane >> 4)) ^ (ra & 7);
                af[f] = *(const short8*)(As + ra*64 + ca*8);
            }
            #pragma unroll
            for (int f = 0; f < NI; ++f) {
                int rb2 = wc + f*16 + (lane & 15);
                int cb2 = (kk*4 + (lane >> 4)) ^ (rb2 & 7);
                bfr[f] = *(const short8*)(Bs + rb2*64 + cb2*8);
            }
            #pragma unroll
            for (int mi = 0; mi < 4; ++mi)
                #pragma unroll
                for (int ni = 0; ni < NI; ++ni)
                    acc[mi][ni] = __builtin_amdgcn_mfma_f32_16x16x32_bf16(
                        af[mi], bfr[ni], acc[mi][ni], 0, 0, 0);
        }
        __syncthreads();
    }

    const int rb = (lane >> 4) * 4, cbl = lane & 15;
    #pragma unroll
    for (int mi = 0; mi < 4; ++mi) {
        #pragma unroll
        for (int ni = 0; ni < NI; ++ni) {
            int ltcol = wc + ni*16 + cbl;
            int col = nBase + ltcol;
            #pragma unroll
            for (int j = 0; j < 4; ++j) {
                int row = mBase + wr + mi*16 + rb + j;
                float v = acc[mi][ni][j];
                if constexpr (MODE == 0) {
                    C0b[(size_t)row * ldc + col] = bf16u(v);
                } else if constexpr (MODE == 1) {
                    if (isXP) {
                        if (ltcol < NS) C1[(size_t)row * NS + ltcol] = v;
                    } else {
                        float z = v + bias[col];
                        float sp = (z > 20.f) ? z : logf(1.f + expf(z));
                        C0b[(size_t)row * ldc + col] = bf16u(sp);
                    }
                } else {
                    C0[(size_t)row * ldc + col] = v + skip[(size_t)row * ldc + col];
                }
            }
        }
    }
}

// ---------------- causal depthwise conv1d (K=4) + SiLU, bf16 in/out ----------
__global__ __launch_bounds__(256) void k_conv(const ushort* __restrict__ xrb,
    const float* __restrict__ cw, const float* __restrict__ cb,
    ushort* __restrict__ xcb)
{
    int gid = blockIdx.x * 256 + threadIdx.x;
    int d = (gid & 511) * 4;
    int tt = (gid >> 9) & 1023;
    int b = gid >> 19;
    float4 w[4];
    #pragma unroll
    for (int c = 0; c < 4; ++c) w[c] = *(const float4*)(cw + (size_t)(d + c) * 4);
    float4 acc = *(const float4*)(cb + d);
    const ushort* base = xrb + (size_t)b * L_DIM * (2*DI) + d;
    #pragma unroll
    for (int j = 0; j < 4; ++j) {
        int ti = tt - 3 + j;
        if (ti < 0) continue;
        ushort4 xu = *(const ushort4*)(base + (size_t)ti * (2*DI));
        const float* w0 = (const float*)&w[0];
        const float* w1 = (const float*)&w[1];
        const float* w2 = (const float*)&w[2];
        const float* w3 = (const float*)&w[3];
        acc.x = fmaf(w0[j], bf2f(xu.x), acc.x);
        acc.y = fmaf(w1[j], bf2f(xu.y), acc.y);
        acc.z = fmaf(w2[j], bf2f(xu.z), acc.z);
        acc.w = fmaf(w3[j], bf2f(xu.w), acc.w);
    }
    acc.x = acc.x / (1.f + expf(-acc.x));
    acc.y = acc.y / (1.f + expf(-acc.y));
    acc.z = acc.z / (1.f + expf(-acc.z));
    acc.w = acc.w / (1.f + expf(-acc.w));
    size_t o = (size_t)(b * L_DIM + tt) * DI + d;
    *(ushort4*)(xcb + o) = make_ushort4(bf16u(acc.x), bf16u(acc.y),
                                        bf16u(acc.z), bf16u(acc.w));
}

// -------- bf16 batched transpose [L][DI] -> [DI][L]: z<2 dt, z>=2 xc ---------
// XOR-swizzled ushort tile: elem (r,c) at tile[r][((c>>3)^((r>>3)&7))*8+(c&7)]
__global__ __launch_bounds__(256) void k_tr4(const ushort* __restrict__ dtb,
    ushort* __restrict__ dtt, const ushort* __restrict__ xcb,
    ushort* __restrict__ xct)
{
    __shared__ __align__(16) ushort tile[64][72];
    const int r0 = blockIdx.y * 64, c0 = blockIdx.x * 64;  // r: t, c: d
    const int z = blockIdx.z;
    const ushort* s;
    ushort* d;
    if (z < 2) { s = dtb + (size_t)z * L_DIM * DI;       d = dtt + (size_t)z * DI * L_DIM; }
    else       { s = xcb + (size_t)(z-2) * L_DIM * DI;   d = xct + (size_t)(z-2) * DI * L_DIM; }
    const int tx = threadIdx.x & 7, ty = threadIdx.x >> 3;  // 8 x 32
    #pragma unroll
    for (int p = 0; p < 2; ++p) {
        int r = ty + p*32;
        short8 v = *(const short8*)(s + (size_t)(r0 + r) * DI + c0 + tx*8);
        int g = tx ^ ((r >> 3) & 7);
        *(short8*)&tile[r][g*8] = v;
    }
    __syncthreads();
    #pragma unroll
    for (int p = 0; p < 2; ++p) {
        int crow = ty + p*32;                 // d index within tile
        ushort o[8];
        #pragma unroll
        for (int j = 0; j < 8; ++j)           // r = tx*8+j -> (r>>3)&7 == tx
            o[j] = tile[tx*8 + j][(((crow >> 3) ^ tx) << 3) + (crow & 7)];
        *(short8*)(d + (size_t)(c0 + crow) * L_DIM + r0 + tx*8) = *(short8*)o;
    }
}

// ------ back-transpose yt[b][d][t](bf16) -> y_bf[b*t][d], fused silu gate ----
__global__ __launch_bounds__(256) void k_trg(const ushort* __restrict__ yt,
    const ushort* __restrict__ xrb, ushort* __restrict__ ybf)
{
    __shared__ __align__(16) ushort tile[64][72];
    const int r0 = blockIdx.y * 64, c0 = blockIdx.x * 64;  // r: d, c: t
    const int z = blockIdx.z;
    const ushort* s = yt + (size_t)z * DI * L_DIM;
    const int tx = threadIdx.x & 7, ty = threadIdx.x >> 3;
    #pragma unroll
    for (int p = 0; p < 2; ++p) {
        int r = ty + p*32;
        short8 v = *(const short8*)(s + (size_t)(r0 + r) * L_DIM + c0 + tx*8);
        int g = tx ^ ((r >> 3) & 7);
        *(short8*)&tile[r][g*8] = v;
    }
    __syncthreads();
    #pragma unroll
    for (int p = 0; p < 2; ++p) {
        int crow = ty + p*32;                 // t index within tile
        int row = z * L_DIM + c0 + crow;      // global (b*t) row
        ushort4 gu0 = *(const ushort4*)(xrb + (size_t)row * (2*DI) + DI + r0 + tx*8);
        ushort4 gu1 = *(const ushort4*)(xrb + (size_t)row * (2*DI) + DI + r0 + tx*8 + 4);
        ushort o[8];
        const ushort* gp = (const ushort*)&gu0;
        #pragma unroll
        for (int j = 0; j < 8; ++j) {
            float yv = bf2f(tile[tx*8 + j][(((crow >> 3) ^ tx) << 3) + (crow & 7)]);
            float g = bf2f(j < 4 ? ((const ushort*)&gu0)[j] : ((const ushort*)&gu1)[j-4]);
            o[j] = bf16u(yv * g / (1.f + expf(-g)));
        }
        (void)gp;
        *(short8*)(ybf + (size_t)row * DI + r0 + tx*8) = *(short8*)o;
    }
}

__device__ __forceinline__ float rl(float v, int lane)
{
    return __int_as_float(__builtin_amdgcn_readlane(__float_as_int(v), lane));
}
__device__ __forceinline__ float exp2_fast(float x)
{
    float r;
    asm("v_exp_f32 %0, %1" : "=v"(r) : "v"(x));
    return r;
}

// ---------------- selective scan v9c: bf16 inputs/outputs --------------------
__global__ __launch_bounds__(256) void k_scan9(const ushort* __restrict__ dtt,
    const ushort* __restrict__ xct, const float* __restrict__ Bss,
    const float* __restrict__ A_log, const float* __restrict__ Dp,
    ushort* __restrict__ yt)
{
    __shared__ float Bsh[64][68];
    __shared__ __align__(16) float Psh[4][64][8];
    const int lane = threadIdx.x & 63;
    const int widx = threadIdx.x >> 6;
    const int b = blockIdx.x >> 9;
    const int d = (blockIdx.x & 511) * 4 + widx;
    const float aL2 = -expf(A_log[(size_t)d * NS + lane]) * 1.44269504f;
    const float Dv = Dp[d];
    const ushort* dtp = dtt + ((size_t)b * DI + d) * L_DIM;
    const ushort* xcp = xct + ((size_t)b * DI + d) * L_DIM;
    const float* Bp  = Bss + (size_t)b * L_DIM * NS;
    ushort* yp = yt + ((size_t)b * DI + d) * L_DIM;
    const int lr = threadIdx.x >> 2;
    const int lc = (threadIdx.x & 3) * 16;
    const int pg = lane >> 3;
    const bool pwrite = (lane & 7) == 7;
    float h = 0.f;

    for (int t0 = 0; t0 < L_DIM; t0 += 64) {
        const float* bsrc = Bp + (size_t)(t0 + lr) * NS + lc;
        float4 b0 = *(const float4*)(bsrc);
        float4 b1 = *(const float4*)(bsrc + 4);
        float4 b2 = *(const float4*)(bsrc + 8);
        float4 b3 = *(const float4*)(bsrc + 12);
        float dt_v = bf2f(dtp[t0 + lane]);
        float xc_v = bf2f(xcp[t0 + lane]);
        __syncthreads();
        *(float4*)&Bsh[lr][lc]      = b0;
        *(float4*)&Bsh[lr][lc + 4]  = b1;
        *(float4*)&Bsh[lr][lc + 8]  = b2;
        *(float4*)&Bsh[lr][lc + 12] = b3;
        __syncthreads();
        #pragma unroll
        for (int q = 0; q < 64; q += 4) {
            float Bv0 = Bsh[q+0][lane];
            float Bv1 = Bsh[q+1][lane];
            float Bv2 = Bsh[q+2][lane];
            float Bv3 = Bsh[q+3][lane];
            float s0, s1, s2, s3;
            {
                float p, ad;
                p  = rl(xc_v, q+0) * Bv0;
                ad = exp2_fast(aL2 * rl(dt_v, q+0));
                h = fmaf(ad, h, p); s0 = h;
                p  = rl(xc_v, q+1) * Bv1;
                ad = exp2_fast(aL2 * rl(dt_v, q+1));
                h = fmaf(ad, h, p); s1 = h;
                p  = rl(xc_v, q+2) * Bv2;
                ad = exp2_fast(aL2 * rl(dt_v, q+2));
                h = fmaf(ad, h, p); s2 = h;
                p  = rl(xc_v, q+3) * Bv3;
                ad = exp2_fast(aL2 * rl(dt_v, q+3));
                h = fmaf(ad, h, p); s3 = h;
            }
            asm("v_add_f32_dpp %0, %0, %0 row_shr:1 row_mask:0xf bank_mask:0xf\n\t"
                "v_add_f32_dpp %1, %1, %1 row_shr:1 row_mask:0xf bank_mask:0xf\n\t"
                "v_add_f32_dpp %2, %2, %2 row_shr:1 row_mask:0xf bank_mask:0xf\n\t"
                "v_add_f32_dpp %3, %3, %3 row_shr:1 row_mask:0xf bank_mask:0xf\n\t"
                "v_add_f32_dpp %0, %0, %0 row_shr:2 row_mask:0xf bank_mask:0xf\n\t"
                "v_add_f32_dpp %1, %1, %1 row_shr:2 row_mask:0xf bank_mask:0xf\n\t"
                "v_add_f32_dpp %2, %2, %2 row_shr:2 row_mask:0xf bank_mask:0xf\n\t"
                "v_add_f32_dpp %3, %3, %3 row_shr:2 row_mask:0xf bank_mask:0xf\n\t"
                "v_add_f32_dpp %0, %0, %0 row_shr:4 row_mask:0xf bank_mask:0xf\n\t"
                "v_add_f32_dpp %1, %1, %1 row_shr:4 row_mask:0xf bank_mask:0xf\n\t"
                "v_add_f32_dpp %2, %2, %2 row_shr:4 row_mask:0xf bank_mask:0xf\n\t"
                "v_add_f32_dpp %3, %3, %3 row_shr:4 row_mask:0xf bank_mask:0xf"
                : "+v"(s0), "+v"(s1), "+v"(s2), "+v"(s3));
            if (pwrite) {
                Psh[widx][q+0][pg] = s0;
                Psh[widx][q+1][pg] = s1;
                Psh[widx][q+2][pg] = s2;
                Psh[widx][q+3][pg] = s3;
            }
        }
        asm volatile("s_waitcnt lgkmcnt(0)" ::: "memory");
        __builtin_amdgcn_sched_barrier(0);
        float4 p0 = *(const float4*)&Psh[widx][lane][0];
        float4 p1 = *(const float4*)&Psh[widx][lane][4];
        float sum = ((p0.x + p0.y) + (p0.z + p0.w))
                  + ((p1.x + p1.y) + (p1.z + p1.w));
        yp[t0 + lane] = bf16u(fmaf(Dv, xc_v, sum));
    }
}

extern "C" void kernel_launch(void* const* d_in, const int* in_sizes, int n_in,
                              void* d_out, int out_size, void* d_ws, size_t ws_size,
                              hipStream_t stream)
{
    const float* x        = (const float*)d_in[0];
    const float* norm_w   = (const float*)d_in[1];
    const float* in_projw = (const float*)d_in[2];
    const float* conv_w   = (const float*)d_in[3];
    const float* conv_b   = (const float*)d_in[4];
    const float* x_projw  = (const float*)d_in[5];
    const float* dt_w     = (const float*)d_in[6];
    const float* dt_b     = (const float*)d_in[7];
    const float* A_log    = (const float*)d_in[8];
    const float* D_param  = (const float*)d_in[9];
    const float* out_projw= (const float*)d_in[10];
    float* out = (float*)d_out;

    ushort* wsu = (ushort*)d_ws;
    ushort* xr_bf  = wsu;                                   // 8M u16
    ushort* xc_bf  = xr_bf + (size_t)8*1024*1024;           // 4M u16
    ushort* dtb_bf = xc_bf + (size_t)4*1024*1024;           // 4M u16
    ushort* dtt_bf = dtb_bf + (size_t)4*1024*1024;          // 4M u16
    ushort* xct_bf = dtt_bf + (size_t)4*1024*1024;          // 4M u16
    ushort* xn_bf  = xct_bf + (size_t)4*1024*1024;          // 2M u16
    ushort* xpw_bf = xn_bf + (size_t)2*1024*1024;           // 128K u16
    ushort* opw_bf = xpw_bf + 131072;                       // 2M u16
    float*  Bss    = (float*)(opw_bf + (size_t)2*1024*1024); // 128K f32
    // aliases into dead regions:
    ushort* inpw_bf = dtt_bf;     // consumed by GEMM0, before tr4 writes dtt
    ushort* dtw_bf  = xct_bf;     // consumed by GEMM1, before tr4 writes xct
    ushort* y_bf    = xc_bf;      // xc dead after tr4
    ushort* yt_bf   = dtb_bf;     // dtb dead after tr4

    k_castw<<<5184, 256, 0, stream>>>(in_projw, inpw_bf, dt_w, dtw_bf,
                                      x_projw + (size_t)64*2048, xpw_bf,
                                      out_projw, opw_bf);
    k_rms_xn<<<2048, 256, 0, stream>>>(x, norm_w, xn_bf);
    k_mfma<0,128><<<dim3(32, 16), 256, 0, stream>>>(xn_bf, inpw_bf, nullptr,
                                                nullptr, xr_bf, nullptr,
                                                nullptr, nullptr, 1024, 4096);
    k_conv<<<4096, 256, 0, stream>>>(xr_bf, conv_w, conv_b, xc_bf);
    k_mfma<1,128><<<dim3(17, 16), 256, 0, stream>>>(xc_bf, dtw_bf, xpw_bf,
                                                nullptr, dtb_bf, Bss,
                                                dt_b, nullptr, 2048, 2048);
    k_tr4<<<dim3(32, 16, 4), 256, 0, stream>>>(dtb_bf, dtt_bf, xc_bf, xct_bf);
    k_scan9<<<1024, 256, 0, stream>>>(dtt_bf, xct_bf, Bss, A_log, D_param, yt_bf);
    k_trg<<<dim3(16, 32, 2), 256, 0, stream>>>(yt_bf, xr_bf, y_bf);
    k_mfma<2,64><<<dim3(8, 32), 256, 0, stream>>>(y_bf, opw_bf, nullptr,
                                               out, nullptr, nullptr,
                                               nullptr, x, 2048, 1024);
}

// Round 16
// 234.186 us; speedup vs baseline: 1.4542x; 1.0840x over previous
//
#include <hip/hip_runtime.h>
#include <hip/hip_bf16.h>
#include <math.h>

#define L_DIM 1024
#define DM 1024
#define DI 2048
#define NS 64

typedef __attribute__((ext_vector_type(8))) short short8;
typedef __attribute__((ext_vector_type(4))) float f32x4;

__device__ __forceinline__ ushort bf16u(float f)
{
    unsigned u = __float_as_uint(f);
    unsigned r = (u + 0x7fffu + ((u >> 16) & 1u)) >> 16;
    return (ushort)r;
}
__device__ __forceinline__ float bf2f(ushort u)
{
    return __uint_as_float((unsigned)u << 16);
}

__device__ __forceinline__ void gld16(const ushort* g, const ushort* l)
{
    __builtin_amdgcn_global_load_lds(
        (const __attribute__((address_space(1))) unsigned int*)g,
        (__attribute__((address_space(3))) unsigned int*)l, 16, 0, 0);
}

// -------- fused RMSNorm + bf16 cast ------------------------------------------
__global__ __launch_bounds__(256) void k_rms_xn(const float* __restrict__ x,
    const float* __restrict__ nw, ushort* __restrict__ d)
{
    int row = blockIdx.x;
    const float* xp = x + (size_t)row * DM;
    float4 v = ((const float4*)xp)[threadIdx.x];
    float ss = v.x*v.x + v.y*v.y + v.z*v.z + v.w*v.w;
    #pragma unroll
    for (int m = 32; m; m >>= 1) ss += __shfl_xor(ss, m, 64);
    __shared__ float red[4];
    if ((threadIdx.x & 63) == 0) red[threadIdx.x >> 6] = ss;
    __syncthreads();
    float tot = red[0] + red[1] + red[2] + red[3];
    float ri = rsqrtf(tot * (1.0f / DM) + 1e-6f);
    float4 wv = ((const float4*)nw)[threadIdx.x];
    ((ushort4*)(d + (size_t)row * DM))[threadIdx.x] =
        make_ushort4(bf16u(v.x*ri*wv.x), bf16u(v.y*ri*wv.y),
                     bf16u(v.z*ri*wv.z), bf16u(v.w*ri*wv.w));
}

// ---------------- all weight casts in ONE dispatch ---------------------------
__device__ __forceinline__ void cast8(const float* __restrict__ s,
                                      ushort* __restrict__ d, int i)
{
    float4 a = ((const float4*)s)[2*i], b = ((const float4*)s)[2*i+1];
    ((ushort4*)d)[2*i]   = make_ushort4(bf16u(a.x), bf16u(a.y), bf16u(a.z), bf16u(a.w));
    ((ushort4*)d)[2*i+1] = make_ushort4(bf16u(b.x), bf16u(b.y), bf16u(b.z), bf16u(b.w));
}
__global__ __launch_bounds__(256) void k_castw(
    const float* __restrict__ s0, ushort* __restrict__ d0,
    const float* __restrict__ s1, ushort* __restrict__ d1,
    const float* __restrict__ s2, ushort* __restrict__ d2,
    const float* __restrict__ s3, ushort* __restrict__ d3)
{
    int i = blockIdx.x * 256 + threadIdx.x;
    if (i < 524288)       cast8(s0, d0, i);
    else if (i < 1048576) cast8(s1, d1, i - 524288);
    else if (i < 1064960) cast8(s2, d2, i - 1048576);
    else                  cast8(s3, d3, i - 1064960);
}

// ------- MFMA NT GEMM, BM templated (128 or 64) x 128, BK=64, swizzled -------
// MODE 0: bf16 out (C0b, row-major ldc).
// MODE 1: non-XP -> softplus dt written TRANSPOSED bf16 into C0b[b][col][t];
//         XP -> f32 Bss (C1).
// MODE 2: f32 out + skip (C0).
template<int MODE, int BM>
__global__ __launch_bounds__(256) void k_mfma(
    const ushort* __restrict__ Abf, const ushort* __restrict__ Bbf0,
    const ushort* __restrict__ Bbf1, float* __restrict__ C0,
    ushort* __restrict__ C0b, float* __restrict__ C1,
    const float* __restrict__ bias, const float* __restrict__ skip,
    int Kdim, int ldc)
{
    constexpr int NI = (BM == 128) ? 4 : 2;
    constexpr int SA = BM / 32;
    __shared__ __align__(16) ushort As[BM*64];
    __shared__ __align__(16) ushort Bs[128*64];
    const int t = threadIdx.x, w = t >> 6, lane = t & 63;
    const int nwg = gridDim.x * gridDim.y;
    const int orig = blockIdx.y * gridDim.x + blockIdx.x;
    const int swz = (orig & 7) * (nwg >> 3) + (orig >> 3);
    const int nt = swz % gridDim.x, mt = swz / gridDim.x;
    const int mBase = mt * BM, nBase = nt * 128;
    const bool isXP = (MODE == 1) && (nt == 16);
    const ushort* __restrict__ Bbf = isXP ? Bbf1 : Bbf0;
    const int wr = (BM == 128) ? (w >> 1) * 64 : 0;
    const int wc = (BM == 128) ? (w & 1) * 64 : w * 32;
    const int sR = lane >> 3;
    const int sK = ((lane & 7) ^ sR) * 8;

    f32x4 acc[4][NI];
    #pragma unroll
    for (int i = 0; i < 4; ++i)
        #pragma unroll
        for (int j = 0; j < NI; ++j)
            acc[i][j] = (f32x4){0.f, 0.f, 0.f, 0.f};

    for (int kt = 0; kt < Kdim; kt += 64) {
        #pragma unroll
        for (int s = 0; s < SA; ++s) {
            int tr = w*8 + s*32 + sR;
            gld16(Abf + (size_t)(mBase + tr) * Kdim + kt + sK,
                  As + (w*8 + s*32) * 64);
        }
        #pragma unroll
        for (int s = 0; s < 4; ++s) {
            int tr = w*8 + s*32 + sR;
            int gr = isXP ? (tr < 63 ? tr : 63) : (nBase + tr);
            gld16(Bbf + (size_t)gr * Kdim + kt + sK,
                  Bs + (w*8 + s*32) * 64);
        }
        __syncthreads();
        #pragma unroll
        for (int kk = 0; kk < 2; ++kk) {
            short8 af[4], bfr[NI];
            #pragma unroll
            for (int f = 0; f < 4; ++f) {
                int ra = wr + f*16 + (lane & 15);
                int ca = (kk*4 + (lane >> 4)) ^ (ra & 7);
                af[f] = *(const short8*)(As + ra*64 + ca*8);
            }
            #pragma unroll
            for (int f = 0; f < NI; ++f) {
                int rb2 = wc + f*16 + (lane & 15);
                int cb2 = (kk*4 + (lane >> 4)) ^ (rb2 & 7);
                bfr[f] = *(const short8*)(Bs + rb2*64 + cb2*8);
            }
            #pragma unroll
            for (int mi = 0; mi < 4; ++mi)
                #pragma unroll
                for (int ni = 0; ni < NI; ++ni)
                    acc[mi][ni] = __builtin_amdgcn_mfma_f32_16x16x32_bf16(
                        af[mi], bfr[ni], acc[mi][ni], 0, 0, 0);
        }
        __syncthreads();
    }

    const int rb = (lane >> 4) * 4, cbl = lane & 15;
    #pragma unroll
    for (int mi = 0; mi < 4; ++mi) {
        #pragma unroll
        for (int ni = 0; ni < NI; ++ni) {
            int ltcol = wc + ni*16 + cbl;
            int col = nBase + ltcol;
            int row0 = mBase + wr + mi*16 + rb;
            if constexpr (MODE == 0) {
                #pragma unroll
                for (int j = 0; j < 4; ++j)
                    C0b[(size_t)(row0+j) * ldc + col] = bf16u(acc[mi][ni][j]);
            } else if constexpr (MODE == 1) {
                if (isXP) {
                    if (ltcol < NS) {
                        #pragma unroll
                        for (int j = 0; j < 4; ++j)
                            C1[(size_t)(row0+j) * NS + ltcol] = acc[mi][ni][j];
                    }
                } else {
                    ushort o[4];
                    #pragma unroll
                    for (int j = 0; j < 4; ++j) {
                        float z = acc[mi][ni][j] + bias[col];
                        float sp = (z > 20.f) ? z : logf(1.f + expf(z));
                        o[j] = bf16u(sp);
                    }
                    int b_ = row0 >> 10, trow = row0 & 1023;
                    *(ushort4*)(C0b + ((size_t)b_ * DI + col) * L_DIM + trow) =
                        *(ushort4*)o;
                }
            } else {
                #pragma unroll
                for (int j = 0; j < 4; ++j)
                    C0[(size_t)(row0+j) * ldc + col] =
                        acc[mi][ni][j] + skip[(size_t)(row0+j) * ldc + col];
            }
        }
    }
}

// ---------------- causal depthwise conv1d (K=4) + SiLU, bf16 in/out ----------
__global__ __launch_bounds__(256) void k_conv(const ushort* __restrict__ xrb,
    const float* __restrict__ cw, const float* __restrict__ cb,
    ushort* __restrict__ xcb)
{
    int gid = blockIdx.x * 256 + threadIdx.x;
    int d = (gid & 511) * 4;
    int tt = (gid >> 9) & 1023;
    int b = gid >> 19;
    float4 w[4];
    #pragma unroll
    for (int c = 0; c < 4; ++c) w[c] = *(const float4*)(cw + (size_t)(d + c) * 4);
    float4 acc = *(const float4*)(cb + d);
    const ushort* base = xrb + (size_t)b * L_DIM * (2*DI) + d;
    #pragma unroll
    for (int j = 0; j < 4; ++j) {
        int ti = tt - 3 + j;
        if (ti < 0) continue;
        ushort4 xu = *(const ushort4*)(base + (size_t)ti * (2*DI));
        const float* w0 = (const float*)&w[0];
        const float* w1 = (const float*)&w[1];
        const float* w2 = (const float*)&w[2];
        const float* w3 = (const float*)&w[3];
        acc.x = fmaf(w0[j], bf2f(xu.x), acc.x);
        acc.y = fmaf(w1[j], bf2f(xu.y), acc.y);
        acc.z = fmaf(w2[j], bf2f(xu.z), acc.z);
        acc.w = fmaf(w3[j], bf2f(xu.w), acc.w);
    }
    acc.x = acc.x / (1.f + expf(-acc.x));
    acc.y = acc.y / (1.f + expf(-acc.y));
    acc.z = acc.z / (1.f + expf(-acc.z));
    acc.w = acc.w / (1.f + expf(-acc.w));
    size_t o = (size_t)(b * L_DIM + tt) * DI + d;
    *(ushort4*)(xcb + o) = make_ushort4(bf16u(acc.x), bf16u(acc.y),
                                        bf16u(acc.z), bf16u(acc.w));
}

// -------- bf16 batched transpose xc[L][DI] -> xct[DI][L], z = batch ----------
__global__ __launch_bounds__(256) void k_tr2(const ushort* __restrict__ xcb,
    ushort* __restrict__ xct)
{
    __shared__ __align__(16) ushort tile[64][72];
    const int r0 = blockIdx.y * 64, c0 = blockIdx.x * 64;  // r: t, c: d
    const int z = blockIdx.z;
    const ushort* s = xcb + (size_t)z * L_DIM * DI;
    ushort* d = xct + (size_t)z * DI * L_DIM;
    const int tx = threadIdx.x & 7, ty = threadIdx.x >> 3;  // 8 x 32
    #pragma unroll
    for (int p = 0; p < 2; ++p) {
        int r = ty + p*32;
        short8 v = *(const short8*)(s + (size_t)(r0 + r) * DI + c0 + tx*8);
        int g = tx ^ ((r >> 3) & 7);
        *(short8*)&tile[r][g*8] = v;
    }
    __syncthreads();
    #pragma unroll
    for (int p = 0; p < 2; ++p) {
        int crow = ty + p*32;                 // d index within tile
        ushort o[8];
        #pragma unroll
        for (int j = 0; j < 8; ++j)
            o[j] = tile[tx*8 + j][(((crow >> 3) ^ tx) << 3) + (crow & 7)];
        *(short8*)(d + (size_t)(c0 + crow) * L_DIM + r0 + tx*8) = *(short8*)o;
    }
}

// ------ back-transpose yt[b][d][t](bf16) -> y_bf[b*t][d], fused silu gate ----
__global__ __launch_bounds__(256) void k_trg(const ushort* __restrict__ yt,
    const ushort* __restrict__ xrb, ushort* __restrict__ ybf)
{
    __shared__ __align__(16) ushort tile[64][72];
    const int r0 = blockIdx.y * 64, c0 = blockIdx.x * 64;  // r: d, c: t
    const int z = blockIdx.z;
    const ushort* s = yt + (size_t)z * DI * L_DIM;
    const int tx = threadIdx.x & 7, ty = threadIdx.x >> 3;
    #pragma unroll
    for (int p = 0; p < 2; ++p) {
        int r = ty + p*32;
        short8 v = *(const short8*)(s + (size_t)(r0 + r) * L_DIM + c0 + tx*8);
        int g = tx ^ ((r >> 3) & 7);
        *(short8*)&tile[r][g*8] = v;
    }
    __syncthreads();
    #pragma unroll
    for (int p = 0; p < 2; ++p) {
        int crow = ty + p*32;                 // t index within tile
        int row = z * L_DIM + c0 + crow;      // global (b*t) row
        ushort4 gu0 = *(const ushort4*)(xrb + (size_t)row * (2*DI) + DI + r0 + tx*8);
        ushort4 gu1 = *(const ushort4*)(xrb + (size_t)row * (2*DI) + DI + r0 + tx*8 + 4);
        ushort o[8];
        #pragma unroll
        for (int j = 0; j < 8; ++j) {
            float yv = bf2f(tile[tx*8 + j][(((crow >> 3) ^ tx) << 3) + (crow & 7)]);
            float g = bf2f(j < 4 ? ((const ushort*)&gu0)[j] : ((const ushort*)&gu1)[j-4]);
            o[j] = bf16u(yv * g / (1.f + expf(-g)));
        }
        *(short8*)(ybf + (size_t)row * DI + r0 + tx*8) = *(short8*)o;
    }
}

__device__ __forceinline__ float exp2_fast(float x)
{
    float r;
    asm("v_exp_f32 %0, %1" : "=v"(r) : "v"(x));
    return r;
}

// ---------------- selective scan v10: LDS-broadcast dt/xc, 3-stage DPP -------
// dt/xc broadcasts via wave-uniform ds_read_b128 of per-wave Dsh/Xsh (replaces
// 2 v_readlane per step with 0.5 DS-instr per step).
__global__ __launch_bounds__(256) void k_scan10(const ushort* __restrict__ dtt,
    const ushort* __restrict__ xct, const float* __restrict__ Bss,
    const float* __restrict__ A_log, const float* __restrict__ Dp,
    ushort* __restrict__ yt)
{
    __shared__ float Bsh[64][68];
    __shared__ __align__(16) float Psh[4][64][8];
    __shared__ __align__(16) float Dsh[4][64];
    __shared__ __align__(16) float Xsh[4][64];
    const int lane = threadIdx.x & 63;
    const int widx = threadIdx.x >> 6;
    const int b = blockIdx.x >> 9;
    const int d = (blockIdx.x & 511) * 4 + widx;
    const float aL2 = -expf(A_log[(size_t)d * NS + lane]) * 1.44269504f;
    const float Dv = Dp[d];
    const ushort* dtp = dtt + ((size_t)b * DI + d) * L_DIM;
    const ushort* xcp = xct + ((size_t)b * DI + d) * L_DIM;
    const float* Bp  = Bss + (size_t)b * L_DIM * NS;
    ushort* yp = yt + ((size_t)b * DI + d) * L_DIM;
    const int lr = threadIdx.x >> 2;
    const int lc = (threadIdx.x & 3) * 16;
    const int pg = lane >> 3;
    const bool pwrite = (lane & 7) == 7;
    float h = 0.f;

    for (int t0 = 0; t0 < L_DIM; t0 += 64) {
        const float* bsrc = Bp + (size_t)(t0 + lr) * NS + lc;
        float4 b0 = *(const float4*)(bsrc);
        float4 b1 = *(const float4*)(bsrc + 4);
        float4 b2 = *(const float4*)(bsrc + 8);
        float4 b3 = *(const float4*)(bsrc + 12);
        float dt_v = bf2f(dtp[t0 + lane]);
        float xc_v = bf2f(xcp[t0 + lane]);
        __syncthreads();
        *(float4*)&Bsh[lr][lc]      = b0;
        *(float4*)&Bsh[lr][lc + 4]  = b1;
        *(float4*)&Bsh[lr][lc + 8]  = b2;
        *(float4*)&Bsh[lr][lc + 12] = b3;
        Dsh[widx][lane] = dt_v;
        Xsh[widx][lane] = xc_v;
        __syncthreads();
        #pragma unroll
        for (int q = 0; q < 64; q += 4) {
            float4 dt4 = *(const float4*)&Dsh[widx][q];   // wave-uniform b128
            float4 xc4 = *(const float4*)&Xsh[widx][q];
            float Bv0 = Bsh[q+0][lane];
            float Bv1 = Bsh[q+1][lane];
            float Bv2 = Bsh[q+2][lane];
            float Bv3 = Bsh[q+3][lane];
            float s0, s1, s2, s3;
            {
                float p, ad;
                p  = xc4.x * Bv0;
                ad = exp2_fast(aL2 * dt4.x);
                h = fmaf(ad, h, p); s0 = h;
                p  = xc4.y * Bv1;
                ad = exp2_fast(aL2 * dt4.y);
                h = fmaf(ad, h, p); s1 = h;
                p  = xc4.z * Bv2;
                ad = exp2_fast(aL2 * dt4.z);
                h = fmaf(ad, h, p); s2 = h;
                p  = xc4.w * Bv3;
                ad = exp2_fast(aL2 * dt4.w);
                h = fmaf(ad, h, p); s3 = h;
            }
            asm("v_add_f32_dpp %0, %0, %0 row_shr:1 row_mask:0xf bank_mask:0xf\n\t"
                "v_add_f32_dpp %1, %1, %1 row_shr:1 row_mask:0xf bank_mask:0xf\n\t"
                "v_add_f32_dpp %2, %2, %2 row_shr:1 row_mask:0xf bank_mask:0xf\n\t"
                "v_add_f32_dpp %3, %3, %3 row_shr:1 row_mask:0xf bank_mask:0xf\n\t"
                "v_add_f32_dpp %0, %0, %0 row_shr:2 row_mask:0xf bank_mask:0xf\n\t"
                "v_add_f32_dpp %1, %1, %1 row_shr:2 row_mask:0xf bank_mask:0xf\n\t"
                "v_add_f32_dpp %2, %2, %2 row_shr:2 row_mask:0xf bank_mask:0xf\n\t"
                "v_add_f32_dpp %3, %3, %3 row_shr:2 row_mask:0xf bank_mask:0xf\n\t"
                "v_add_f32_dpp %0, %0, %0 row_shr:4 row_mask:0xf bank_mask:0xf\n\t"
                "v_add_f32_dpp %1, %1, %1 row_shr:4 row_mask:0xf bank_mask:0xf\n\t"
                "v_add_f32_dpp %2, %2, %2 row_shr:4 row_mask:0xf bank_mask:0xf\n\t"
                "v_add_f32_dpp %3, %3, %3 row_shr:4 row_mask:0xf bank_mask:0xf"
                : "+v"(s0), "+v"(s1), "+v"(s2), "+v"(s3));
            if (pwrite) {
                Psh[widx][q+0][pg] = s0;
                Psh[widx][q+1][pg] = s1;
                Psh[widx][q+2][pg] = s2;
                Psh[widx][q+3][pg] = s3;
            }
        }
        asm volatile("s_waitcnt lgkmcnt(0)" ::: "memory");
        __builtin_amdgcn_sched_barrier(0);
        float4 p0 = *(const float4*)&Psh[widx][lane][0];
        float4 p1 = *(const float4*)&Psh[widx][lane][4];
        float sum = ((p0.x + p0.y) + (p0.z + p0.w))
                  + ((p1.x + p1.y) + (p1.z + p1.w));
        yp[t0 + lane] = bf16u(fmaf(Dv, xc_v, sum));
    }
}

extern "C" void kernel_launch(void* const* d_in, const int* in_sizes, int n_in,
                              void* d_out, int out_size, void* d_ws, size_t ws_size,
                              hipStream_t stream)
{
    const float* x        = (const float*)d_in[0];
    const float* norm_w   = (const float*)d_in[1];
    const float* in_projw = (const float*)d_in[2];
    const float* conv_w   = (const float*)d_in[3];
    const float* conv_b   = (const float*)d_in[4];
    const float* x_projw  = (const float*)d_in[5];
    const float* dt_w     = (const float*)d_in[6];
    const float* dt_b     = (const float*)d_in[7];
    const float* A_log    = (const float*)d_in[8];
    const float* D_param  = (const float*)d_in[9];
    const float* out_projw= (const float*)d_in[10];
    float* out = (float*)d_out;

    ushort* wsu = (ushort*)d_ws;
    ushort* xr_bf  = wsu;                                   // 8M u16
    ushort* xc_bf  = xr_bf + (size_t)8*1024*1024;           // 4M u16
    ushort* dtb_bf = xc_bf + (size_t)4*1024*1024;           // 4M u16 (yt alias)
    ushort* dtt_bf = dtb_bf + (size_t)4*1024*1024;          // 4M u16
    ushort* xct_bf = dtt_bf + (size_t)4*1024*1024;          // 4M u16
    ushort* xn_bf  = xct_bf + (size_t)4*1024*1024;          // 2M u16
    ushort* xpw_bf = xn_bf + (size_t)2*1024*1024;           // 128K u16
    ushort* opw_bf = xpw_bf + 131072;                       // 2M u16
    float*  Bss    = (float*)(opw_bf + (size_t)2*1024*1024); // 128K f32
    // aliases into dead regions:
    ushort* inpw_bf = dtt_bf;     // consumed by GEMM0, before GEMM1 writes dtt
    ushort* dtw_bf  = xct_bf;     // consumed by GEMM1, before tr2 writes xct
    ushort* y_bf    = xc_bf;      // xc dead after tr2
    ushort* yt_bf   = dtb_bf;     // scratch for scan output

    k_castw<<<5184, 256, 0, stream>>>(in_projw, inpw_bf, dt_w, dtw_bf,
                                      x_projw + (size_t)64*2048, xpw_bf,
                                      out_projw, opw_bf);
    k_rms_xn<<<2048, 256, 0, stream>>>(x, norm_w, xn_bf);
    k_mfma<0,128><<<dim3(32, 16), 256, 0, stream>>>(xn_bf, inpw_bf, nullptr,
                                                nullptr, xr_bf, nullptr,
                                                nullptr, nullptr, 1024, 4096);
    k_conv<<<4096, 256, 0, stream>>>(xr_bf, conv_w, conv_b, xc_bf);
    // GEMM1: dt written transposed directly into dtt_bf[b][d][t]; Bss f32
    k_mfma<1,128><<<dim3(17, 16), 256, 0, stream>>>(xc_bf, dtw_bf, xpw_bf,
                                                nullptr, dtt_bf, Bss,
                                                dt_b, nullptr, 2048, 2048);
    k_tr2<<<dim3(32, 16, 2), 256, 0, stream>>>(xc_bf, xct_bf);
    k_scan10<<<1024, 256, 0, stream>>>(dtt_bf, xct_bf, Bss, A_log, D_param, yt_bf);
    k_trg<<<dim3(16, 32, 2), 256, 0, stream>>>(yt_bf, xr_bf, y_bf);
    k_mfma<2,64><<<dim3(8, 32), 256, 0, stream>>>(y_bf, opw_bf, nullptr,
                                               out, nullptr, nullptr,
                                               nullptr, x, 2048, 1024);
}

// Round 17
// 232.361 us; speedup vs baseline: 1.4656x; 1.0079x over previous
//
#include <hip/hip_runtime.h>
#include <hip/hip_bf16.h>
#include <math.h>

#define L_DIM 1024
#define DM 1024
#define DI 2048
#define NS 64

typedef __attribute__((ext_vector_type(8))) short short8;
typedef __attribute__((ext_vector_type(4))) float f32x4;

__device__ __forceinline__ ushort bf16u(float f)
{
    unsigned u = __float_as_uint(f);
    unsigned r = (u + 0x7fffu + ((u >> 16) & 1u)) >> 16;
    return (ushort)r;
}
__device__ __forceinline__ float bf2f(ushort u)
{
    return __uint_as_float((unsigned)u << 16);
}

__device__ __forceinline__ void gld16(const ushort* g, const ushort* l)
{
    __builtin_amdgcn_global_load_lds(
        (const __attribute__((address_space(1))) unsigned int*)g,
        (__attribute__((address_space(3))) unsigned int*)l, 16, 0, 0);
}

// -------- fused RMSNorm + bf16 cast ------------------------------------------
__global__ __launch_bounds__(256) void k_rms_xn(const float* __restrict__ x,
    const float* __restrict__ nw, ushort* __restrict__ d)
{
    int row = blockIdx.x;
    const float* xp = x + (size_t)row * DM;
    float4 v = ((const float4*)xp)[threadIdx.x];
    float ss = v.x*v.x + v.y*v.y + v.z*v.z + v.w*v.w;
    #pragma unroll
    for (int m = 32; m; m >>= 1) ss += __shfl_xor(ss, m, 64);
    __shared__ float red[4];
    if ((threadIdx.x & 63) == 0) red[threadIdx.x >> 6] = ss;
    __syncthreads();
    float tot = red[0] + red[1] + red[2] + red[3];
    float ri = rsqrtf(tot * (1.0f / DM) + 1e-6f);
    float4 wv = ((const float4*)nw)[threadIdx.x];
    ((ushort4*)(d + (size_t)row * DM))[threadIdx.x] =
        make_ushort4(bf16u(v.x*ri*wv.x), bf16u(v.y*ri*wv.y),
                     bf16u(v.z*ri*wv.z), bf16u(v.w*ri*wv.w));
}

// ---------------- all weight casts in ONE dispatch ---------------------------
__device__ __forceinline__ void cast8(const float* __restrict__ s,
                                      ushort* __restrict__ d, int i)
{
    float4 a = ((const float4*)s)[2*i], b = ((const float4*)s)[2*i+1];
    ((ushort4*)d)[2*i]   = make_ushort4(bf16u(a.x), bf16u(a.y), bf16u(a.z), bf16u(a.w));
    ((ushort4*)d)[2*i+1] = make_ushort4(bf16u(b.x), bf16u(b.y), bf16u(b.z), bf16u(b.w));
}
__global__ __launch_bounds__(256) void k_castw(
    const float* __restrict__ s0, ushort* __restrict__ d0,
    const float* __restrict__ s1, ushort* __restrict__ d1,
    const float* __restrict__ s2, ushort* __restrict__ d2,
    const float* __restrict__ s3, ushort* __restrict__ d3)
{
    int i = blockIdx.x * 256 + threadIdx.x;
    if (i < 524288)       cast8(s0, d0, i);
    else if (i < 1048576) cast8(s1, d1, i - 524288);
    else if (i < 1064960) cast8(s2, d2, i - 1048576);
    else                  cast8(s3, d3, i - 1064960);
}

// ------- MFMA NT GEMM, BM templated (128 or 64) x 128, BK=64, swizzled -------
// MODE 0: bf16 out (C0b, row-major ldc).
// MODE 1: non-XP -> softplus dt TRANSPOSED bf16 into C0b[b][col][t];
//         XP -> f32 B TRANSPOSED into C1[b][n][t] (BssT).
// MODE 2: f32 out + skip (C0).
template<int MODE, int BM>
__global__ __launch_bounds__(256) void k_mfma(
    const ushort* __restrict__ Abf, const ushort* __restrict__ Bbf0,
    const ushort* __restrict__ Bbf1, float* __restrict__ C0,
    ushort* __restrict__ C0b, float* __restrict__ C1,
    const float* __restrict__ bias, const float* __restrict__ skip,
    int Kdim, int ldc)
{
    constexpr int NI = (BM == 128) ? 4 : 2;
    constexpr int SA = BM / 32;
    __shared__ __align__(16) ushort As[BM*64];
    __shared__ __align__(16) ushort Bs[128*64];
    const int t = threadIdx.x, w = t >> 6, lane = t & 63;
    const int nwg = gridDim.x * gridDim.y;
    const int orig = blockIdx.y * gridDim.x + blockIdx.x;
    const int swz = (orig & 7) * (nwg >> 3) + (orig >> 3);
    const int nt = swz % gridDim.x, mt = swz / gridDim.x;
    const int mBase = mt * BM, nBase = nt * 128;
    const bool isXP = (MODE == 1) && (nt == 16);
    const ushort* __restrict__ Bbf = isXP ? Bbf1 : Bbf0;
    const int wr = (BM == 128) ? (w >> 1) * 64 : 0;
    const int wc = (BM == 128) ? (w & 1) * 64 : w * 32;
    const int sR = lane >> 3;
    const int sK = ((lane & 7) ^ sR) * 8;

    f32x4 acc[4][NI];
    #pragma unroll
    for (int i = 0; i < 4; ++i)
        #pragma unroll
        for (int j = 0; j < NI; ++j)
            acc[i][j] = (f32x4){0.f, 0.f, 0.f, 0.f};

    for (int kt = 0; kt < Kdim; kt += 64) {
        #pragma unroll
        for (int s = 0; s < SA; ++s) {
            int tr = w*8 + s*32 + sR;
            gld16(Abf + (size_t)(mBase + tr) * Kdim + kt + sK,
                  As + (w*8 + s*32) * 64);
        }
        #pragma unroll
        for (int s = 0; s < 4; ++s) {
            int tr = w*8 + s*32 + sR;
            int gr = isXP ? (tr < 63 ? tr : 63) : (nBase + tr);
            gld16(Bbf + (size_t)gr * Kdim + kt + sK,
                  Bs + (w*8 + s*32) * 64);
        }
        __syncthreads();
        #pragma unroll
        for (int kk = 0; kk < 2; ++kk) {
            short8 af[4], bfr[NI];
            #pragma unroll
            for (int f = 0; f < 4; ++f) {
                int ra = wr + f*16 + (lane & 15);
                int ca = (kk*4 + (lane >> 4)) ^ (ra & 7);
                af[f] = *(const short8*)(As + ra*64 + ca*8);
            }
            #pragma unroll
            for (int f = 0; f < NI; ++f) {
                int rb2 = wc + f*16 + (lane & 15);
                int cb2 = (kk*4 + (lane >> 4)) ^ (rb2 & 7);
                bfr[f] = *(const short8*)(Bs + rb2*64 + cb2*8);
            }
            #pragma unroll
            for (int mi = 0; mi < 4; ++mi)
                #pragma unroll
                for (int ni = 0; ni < NI; ++ni)
                    acc[mi][ni] = __builtin_amdgcn_mfma_f32_16x16x32_bf16(
                        af[mi], bfr[ni], acc[mi][ni], 0, 0, 0);
        }
        __syncthreads();
    }

    const int rb = (lane >> 4) * 4, cbl = lane & 15;
    #pragma unroll
    for (int mi = 0; mi < 4; ++mi) {
        #pragma unroll
        for (int ni = 0; ni < NI; ++ni) {
            int ltcol = wc + ni*16 + cbl;
            int col = nBase + ltcol;
            int row0 = mBase + wr + mi*16 + rb;
            if constexpr (MODE == 0) {
                #pragma unroll
                for (int j = 0; j < 4; ++j)
                    C0b[(size_t)(row0+j) * ldc + col] = bf16u(acc[mi][ni][j]);
            } else if constexpr (MODE == 1) {
                int b_ = row0 >> 10, trow = row0 & 1023;
                if (isXP) {
                    if (ltcol < NS) {
                        f32x4 v = acc[mi][ni];
                        *(f32x4*)(C1 + ((size_t)b_ * NS + ltcol) * L_DIM + trow) = v;
                    }
                } else {
                    ushort o[4];
                    #pragma unroll
                    for (int j = 0; j < 4; ++j) {
                        float z = acc[mi][ni][j] + bias[col];
                        float sp = (z > 20.f) ? z : logf(1.f + expf(z));
                        o[j] = bf16u(sp);
                    }
                    *(ushort4*)(C0b + ((size_t)b_ * DI + col) * L_DIM + trow) =
                        *(ushort4*)o;
                }
            } else {
                #pragma unroll
                for (int j = 0; j < 4; ++j)
                    C0[(size_t)(row0+j) * ldc + col] =
                        acc[mi][ni][j] + skip[(size_t)(row0+j) * ldc + col];
            }
        }
    }
}

// ---------------- causal depthwise conv1d (K=4) + SiLU, bf16 in/out ----------
__global__ __launch_bounds__(256) void k_conv(const ushort* __restrict__ xrb,
    const float* __restrict__ cw, const float* __restrict__ cb,
    ushort* __restrict__ xcb)
{
    int gid = blockIdx.x * 256 + threadIdx.x;
    int d = (gid & 511) * 4;
    int tt = (gid >> 9) & 1023;
    int b = gid >> 19;
    float4 w[4];
    #pragma unroll
    for (int c = 0; c < 4; ++c) w[c] = *(const float4*)(cw + (size_t)(d + c) * 4);
    float4 acc = *(const float4*)(cb + d);
    const ushort* base = xrb + (size_t)b * L_DIM * (2*DI) + d;
    #pragma unroll
    for (int j = 0; j < 4; ++j) {
        int ti = tt - 3 + j;
        if (ti < 0) continue;
        ushort4 xu = *(const ushort4*)(base + (size_t)ti * (2*DI));
        const float* w0 = (const float*)&w[0];
        const float* w1 = (const float*)&w[1];
        const float* w2 = (const float*)&w[2];
        const float* w3 = (const float*)&w[3];
        acc.x = fmaf(w0[j], bf2f(xu.x), acc.x);
        acc.y = fmaf(w1[j], bf2f(xu.y), acc.y);
        acc.z = fmaf(w2[j], bf2f(xu.z), acc.z);
        acc.w = fmaf(w3[j], bf2f(xu.w), acc.w);
    }
    acc.x = acc.x / (1.f + expf(-acc.x));
    acc.y = acc.y / (1.f + expf(-acc.y));
    acc.z = acc.z / (1.f + expf(-acc.z));
    acc.w = acc.w / (1.f + expf(-acc.w));
    size_t o = (size_t)(b * L_DIM + tt) * DI + d;
    *(ushort4*)(xcb + o) = make_ushort4(bf16u(acc.x), bf16u(acc.y),
                                        bf16u(acc.z), bf16u(acc.w));
}

// -------- bf16 batched transpose xc[L][DI] -> xct[DI][L], z = batch ----------
__global__ __launch_bounds__(256) void k_tr2(const ushort* __restrict__ xcb,
    ushort* __restrict__ xct)
{
    __shared__ __align__(16) ushort tile[64][72];
    const int r0 = blockIdx.y * 64, c0 = blockIdx.x * 64;  // r: t, c: d
    const int z = blockIdx.z;
    const ushort* s = xcb + (size_t)z * L_DIM * DI;
    ushort* d = xct + (size_t)z * DI * L_DIM;
    const int tx = threadIdx.x & 7, ty = threadIdx.x >> 3;  // 8 x 32
    #pragma unroll
    for (int p = 0; p < 2; ++p) {
        int r = ty + p*32;
        short8 v = *(const short8*)(s + (size_t)(r0 + r) * DI + c0 + tx*8);
        int g = tx ^ ((r >> 3) & 7);
        *(short8*)&tile[r][g*8] = v;
    }
    __syncthreads();
    #pragma unroll
    for (int p = 0; p < 2; ++p) {
        int crow = ty + p*32;                 // d index within tile
        ushort o[8];
        #pragma unroll
        for (int j = 0; j < 8; ++j)
            o[j] = tile[tx*8 + j][(((crow >> 3) ^ tx) << 3) + (crow & 7)];
        *(short8*)(d + (size_t)(c0 + crow) * L_DIM + r0 + tx*8) = *(short8*)o;
    }
}

// ------ back-transpose yt[b][d][t](bf16) -> y_bf[b*t][d], fused silu gate ----
__global__ __launch_bounds__(256) void k_trg(const ushort* __restrict__ yt,
    const ushort* __restrict__ xrb, ushort* __restrict__ ybf)
{
    __shared__ __align__(16) ushort tile[64][72];
    const int r0 = blockIdx.y * 64, c0 = blockIdx.x * 64;  // r: d, c: t
    const int z = blockIdx.z;
    const ushort* s = yt + (size_t)z * DI * L_DIM;
    const int tx = threadIdx.x & 7, ty = threadIdx.x >> 3;
    #pragma unroll
    for (int p = 0; p < 2; ++p) {
        int r = ty + p*32;
        short8 v = *(const short8*)(s + (size_t)(r0 + r) * L_DIM + c0 + tx*8);
        int g = tx ^ ((r >> 3) & 7);
        *(short8*)&tile[r][g*8] = v;
    }
    __syncthreads();
    #pragma unroll
    for (int p = 0; p < 2; ++p) {
        int crow = ty + p*32;                 // t index within tile
        int row = z * L_DIM + c0 + crow;      // global (b*t) row
        ushort4 gu0 = *(const ushort4*)(xrb + (size_t)row * (2*DI) + DI + r0 + tx*8);
        ushort4 gu1 = *(const ushort4*)(xrb + (size_t)row * (2*DI) + DI + r0 + tx*8 + 4);
        ushort o[8];
        #pragma unroll
        for (int j = 0; j < 8; ++j) {
            float yv = bf2f(tile[tx*8 + j][(((crow >> 3) ^ tx) << 3) + (crow & 7)]);
            float g = bf2f(j < 4 ? ((const ushort*)&gu0)[j] : ((const ushort*)&gu1)[j-4]);
            o[j] = bf16u(yv * g / (1.f + expf(-g)));
        }
        *(short8*)(ybf + (size_t)row * DI + r0 + tx*8) = *(short8*)o;
    }
}

__device__ __forceinline__ float exp2_fast(float x)
{
    float r;
    asm("v_exp_f32 %0, %1" : "=v"(r) : "v"(x));
    return r;
}

// ---------------- selective scan v11: BshT[n][t] + b128 B-reads --------------
// B staged transposed (from BssT[b][n][t]); per 4-step group ONE ds_read_b128
// per lane (BshT[lane][q..q+3]) replaces 4 ds_read_b32. DS/step ~1.75 -> ~1.0.
__global__ __launch_bounds__(256) void k_scan11(const ushort* __restrict__ dtt,
    const ushort* __restrict__ xct, const float* __restrict__ BssT,
    const float* __restrict__ A_log, const float* __restrict__ Dp,
    ushort* __restrict__ yt)
{
    __shared__ __align__(16) float BshT[64][68];
    __shared__ __align__(16) float Psh[4][64][8];
    __shared__ __align__(16) float Dsh[4][64];
    __shared__ __align__(16) float Xsh[4][64];
    const int lane = threadIdx.x & 63;
    const int widx = threadIdx.x >> 6;
    const int b = blockIdx.x >> 9;
    const int d = (blockIdx.x & 511) * 4 + widx;
    const float aL2 = -expf(A_log[(size_t)d * NS + lane]) * 1.44269504f;
    const float Dv = Dp[d];
    const ushort* dtp = dtt + ((size_t)b * DI + d) * L_DIM;
    const ushort* xcp = xct + ((size_t)b * DI + d) * L_DIM;
    const float* BpT = BssT + ((size_t)b * NS + lane) * L_DIM;  // row n=lane
    ushort* yp = yt + ((size_t)b * DI + d) * L_DIM;
    const int pg = lane >> 3;
    const bool pwrite = (lane & 7) == 7;
    float h = 0.f;

    for (int t0 = 0; t0 < L_DIM; t0 += 64) {
        // stage: each lane loads 16 t-values of its own n-row (L2-resident)
        const float* bsrc = BpT + t0 + widx*16;
        float4 b0 = *(const float4*)(bsrc);
        float4 b1 = *(const float4*)(bsrc + 4);
        float4 b2 = *(const float4*)(bsrc + 8);
        float4 b3 = *(const float4*)(bsrc + 12);
        float dt_v = bf2f(dtp[t0 + lane]);
        float xc_v = bf2f(xcp[t0 + lane]);
        __syncthreads();
        *(float4*)&BshT[lane][widx*16]      = b0;
        *(float4*)&BshT[lane][widx*16 + 4]  = b1;
        *(float4*)&BshT[lane][widx*16 + 8]  = b2;
        *(float4*)&BshT[lane][widx*16 + 12] = b3;
        Dsh[widx][lane] = dt_v;
        Xsh[widx][lane] = xc_v;
        __syncthreads();
        #pragma unroll
        for (int q = 0; q < 64; q += 4) {
            float4 dt4 = *(const float4*)&Dsh[widx][q];   // wave-uniform b128
            float4 xc4 = *(const float4*)&Xsh[widx][q];
            float4 Bq  = *(const float4*)&BshT[lane][q];  // per-lane b128
            float s0, s1, s2, s3;
            {
                float p, ad;
                p  = xc4.x * Bq.x;
                ad = exp2_fast(aL2 * dt4.x);
                h = fmaf(ad, h, p); s0 = h;
                p  = xc4.y * Bq.y;
                ad = exp2_fast(aL2 * dt4.y);
                h = fmaf(ad, h, p); s1 = h;
                p  = xc4.z * Bq.z;
                ad = exp2_fast(aL2 * dt4.z);
                h = fmaf(ad, h, p); s2 = h;
                p  = xc4.w * Bq.w;
                ad = exp2_fast(aL2 * dt4.w);
                h = fmaf(ad, h, p); s3 = h;
            }
            asm("v_add_f32_dpp %0, %0, %0 row_shr:1 row_mask:0xf bank_mask:0xf\n\t"
                "v_add_f32_dpp %1, %1, %1 row_shr:1 row_mask:0xf bank_mask:0xf\n\t"
                "v_add_f32_dpp %2, %2, %2 row_shr:1 row_mask:0xf bank_mask:0xf\n\t"
                "v_add_f32_dpp %3, %3, %3 row_shr:1 row_mask:0xf bank_mask:0xf\n\t"
                "v_add_f32_dpp %0, %0, %0 row_shr:2 row_mask:0xf bank_mask:0xf\n\t"
                "v_add_f32_dpp %1, %1, %1 row_shr:2 row_mask:0xf bank_mask:0xf\n\t"
                "v_add_f32_dpp %2, %2, %2 row_shr:2 row_mask:0xf bank_mask:0xf\n\t"
                "v_add_f32_dpp %3, %3, %3 row_shr:2 row_mask:0xf bank_mask:0xf\n\t"
                "v_add_f32_dpp %0, %0, %0 row_shr:4 row_mask:0xf bank_mask:0xf\n\t"
                "v_add_f32_dpp %1, %1, %1 row_shr:4 row_mask:0xf bank_mask:0xf\n\t"
                "v_add_f32_dpp %2, %2, %2 row_shr:4 row_mask:0xf bank_mask:0xf\n\t"
                "v_add_f32_dpp %3, %3, %3 row_shr:4 row_mask:0xf bank_mask:0xf"
                : "+v"(s0), "+v"(s1), "+v"(s2), "+v"(s3));
            if (pwrite) {
                Psh[widx][q+0][pg] = s0;
                Psh[widx][q+1][pg] = s1;
                Psh[widx][q+2][pg] = s2;
                Psh[widx][q+3][pg] = s3;
            }
        }
        asm volatile("s_waitcnt lgkmcnt(0)" ::: "memory");
        __builtin_amdgcn_sched_barrier(0);
        float4 p0 = *(const float4*)&Psh[widx][lane][0];
        float4 p1 = *(const float4*)&Psh[widx][lane][4];
        float sum = ((p0.x + p0.y) + (p0.z + p0.w))
                  + ((p1.x + p1.y) + (p1.z + p1.w));
        yp[t0 + lane] = bf16u(fmaf(Dv, xc_v, sum));
    }
}

extern "C" void kernel_launch(void* const* d_in, const int* in_sizes, int n_in,
                              void* d_out, int out_size, void* d_ws, size_t ws_size,
                              hipStream_t stream)
{
    const float* x        = (const float*)d_in[0];
    const float* norm_w   = (const float*)d_in[1];
    const float* in_projw = (const float*)d_in[2];
    const float* conv_w   = (const float*)d_in[3];
    const float* conv_b   = (const float*)d_in[4];
    const float* x_projw  = (const float*)d_in[5];
    const float* dt_w     = (const float*)d_in[6];
    const float* dt_b     = (const float*)d_in[7];
    const float* A_log    = (const float*)d_in[8];
    const float* D_param  = (const float*)d_in[9];
    const float* out_projw= (const float*)d_in[10];
    float* out = (float*)d_out;

    ushort* wsu = (ushort*)d_ws;
    ushort* xr_bf  = wsu;                                   // 8M u16
    ushort* xc_bf  = xr_bf + (size_t)8*1024*1024;           // 4M u16
    ushort* dtb_bf = xc_bf + (size_t)4*1024*1024;           // 4M u16 (yt alias)
    ushort* dtt_bf = dtb_bf + (size_t)4*1024*1024;          // 4M u16
    ushort* xct_bf = dtt_bf + (size_t)4*1024*1024;          // 4M u16
    ushort* xn_bf  = xct_bf + (size_t)4*1024*1024;          // 2M u16
    ushort* xpw_bf = xn_bf + (size_t)2*1024*1024;           // 128K u16
    ushort* opw_bf = xpw_bf + 131072;                       // 2M u16
    float*  BssT   = (float*)(opw_bf + (size_t)2*1024*1024); // 128K f32 [b][n][t]
    // aliases into dead regions:
    ushort* inpw_bf = dtt_bf;     // consumed by GEMM0, before GEMM1 writes dtt
    ushort* dtw_bf  = xct_bf;     // consumed by GEMM1, before tr2 writes xct
    ushort* y_bf    = xc_bf;      // xc dead after tr2
    ushort* yt_bf   = dtb_bf;     // scratch for scan output

    k_castw<<<5184, 256, 0, stream>>>(in_projw, inpw_bf, dt_w, dtw_bf,
                                      x_projw + (size_t)64*2048, xpw_bf,
                                      out_projw, opw_bf);
    k_rms_xn<<<2048, 256, 0, stream>>>(x, norm_w, xn_bf);
    k_mfma<0,128><<<dim3(32, 16), 256, 0, stream>>>(xn_bf, inpw_bf, nullptr,
                                                nullptr, xr_bf, nullptr,
                                                nullptr, nullptr, 1024, 4096);
    k_conv<<<4096, 256, 0, stream>>>(xr_bf, conv_w, conv_b, xc_bf);
    // GEMM1: dt transposed bf16 into dtt_bf[b][d][t]; B transposed f32 BssT
    k_mfma<1,128><<<dim3(17, 16), 256, 0, stream>>>(xc_bf, dtw_bf, xpw_bf,
                                                nullptr, dtt_bf, BssT,
                                                dt_b, nullptr, 2048, 2048);
    k_tr2<<<dim3(32, 16, 2), 256, 0, stream>>>(xc_bf, xct_bf);
    k_scan11<<<1024, 256, 0, stream>>>(dtt_bf, xct_bf, BssT, A_log, D_param, yt_bf);
    k_trg<<<dim3(16, 32, 2), 256, 0, stream>>>(yt_bf, xr_bf, y_bf);
    k_mfma<2,64><<<dim3(8, 32), 256, 0, stream>>>(y_bf, opw_bf, nullptr,
                                               out, nullptr, nullptr,
                                               nullptr, x, 2048, 1024);
}

// Round 19
// 219.639 us; speedup vs baseline: 1.5505x; 1.0579x over previous
//
#include <hip/hip_runtime.h>
#include <hip/hip_bf16.h>
#include <math.h>

#define L_DIM 1024
#define DM 1024
#define DI 2048
#define NS 64

typedef __attribute__((ext_vector_type(8))) short short8;
typedef __attribute__((ext_vector_type(4))) float f32x4;

__device__ __forceinline__ ushort bf16u(float f)
{
    unsigned u = __float_as_uint(f);
    unsigned r = (u + 0x7fffu + ((u >> 16) & 1u)) >> 16;
    return (ushort)r;
}
__device__ __forceinline__ float bf2f(ushort u)
{
    return __uint_as_float((unsigned)u << 16);
}

__device__ __forceinline__ void gld16(const ushort* g, const ushort* l)
{
    __builtin_amdgcn_global_load_lds(
        (const __attribute__((address_space(1))) unsigned int*)g,
        (__attribute__((address_space(3))) unsigned int*)l, 16, 0, 0);
}

// -------- fused RMSNorm + bf16 cast ------------------------------------------
__global__ __launch_bounds__(256) void k_rms_xn(const float* __restrict__ x,
    const float* __restrict__ nw, ushort* __restrict__ d)
{
    int row = blockIdx.x;
    const float* xp = x + (size_t)row * DM;
    float4 v = ((const float4*)xp)[threadIdx.x];
    float ss = v.x*v.x + v.y*v.y + v.z*v.z + v.w*v.w;
    #pragma unroll
    for (int m = 32; m; m >>= 1) ss += __shfl_xor(ss, m, 64);
    __shared__ float red[4];
    if ((threadIdx.x & 63) == 0) red[threadIdx.x >> 6] = ss;
    __syncthreads();
    float tot = red[0] + red[1] + red[2] + red[3];
    float ri = rsqrtf(tot * (1.0f / DM) + 1e-6f);
    float4 wv = ((const float4*)nw)[threadIdx.x];
    ((ushort4*)(d + (size_t)row * DM))[threadIdx.x] =
        make_ushort4(bf16u(v.x*ri*wv.x), bf16u(v.y*ri*wv.y),
                     bf16u(v.z*ri*wv.z), bf16u(v.w*ri*wv.w));
}

// ---------------- all weight casts in ONE dispatch ---------------------------
__device__ __forceinline__ void cast8(const float* __restrict__ s,
                                      ushort* __restrict__ d, int i)
{
    float4 a = ((const float4*)s)[2*i], b = ((const float4*)s)[2*i+1];
    ((ushort4*)d)[2*i]   = make_ushort4(bf16u(a.x), bf16u(a.y), bf16u(a.z), bf16u(a.w));
    ((ushort4*)d)[2*i+1] = make_ushort4(bf16u(b.x), bf16u(b.y), bf16u(b.z), bf16u(b.w));
}
__global__ __launch_bounds__(256) void k_castw(
    const float* __restrict__ s0, ushort* __restrict__ d0,
    const float* __restrict__ s1, ushort* __restrict__ d1,
    const float* __restrict__ s2, ushort* __restrict__ d2,
    const float* __restrict__ s3, ushort* __restrict__ d3)
{
    int i = blockIdx.x * 256 + threadIdx.x;
    if (i < 524288)       cast8(s0, d0, i);
    else if (i < 1048576) cast8(s1, d1, i - 524288);
    else if (i < 1064960) cast8(s2, d2, i - 1048576);
    else                  cast8(s3, d3, i - 1064960);
}

// ------- MFMA NT GEMM, BM templated (128 or 64) x 128, BK=64, swizzled -------
// MODE 0: bf16 out (C0b, row-major ldc).
// MODE 1: non-XP -> softplus dt TRANSPOSED bf16 into C0b[b][col][t];
//         XP -> f32 B TRANSPOSED into C1[b][n][t] (BssT).
// MODE 2: f32 out + skip (C0).
template<int MODE, int BM>
__global__ __launch_bounds__(256) void k_mfma(
    const ushort* __restrict__ Abf, const ushort* __restrict__ Bbf0,
    const ushort* __restrict__ Bbf1, float* __restrict__ C0,
    ushort* __restrict__ C0b, float* __restrict__ C1,
    const float* __restrict__ bias, const float* __restrict__ skip,
    int Kdim, int ldc)
{
    constexpr int NI = (BM == 128) ? 4 : 2;
    constexpr int SA = BM / 32;
    __shared__ __align__(16) ushort As[BM*64];
    __shared__ __align__(16) ushort Bs[128*64];
    const int t = threadIdx.x, w = t >> 6, lane = t & 63;
    const int nwg = gridDim.x * gridDim.y;
    const int orig = blockIdx.y * gridDim.x + blockIdx.x;
    const int swz = (orig & 7) * (nwg >> 3) + (orig >> 3);
    const int nt = swz % gridDim.x, mt = swz / gridDim.x;
    const int mBase = mt * BM, nBase = nt * 128;
    const bool isXP = (MODE == 1) && (nt == 16);
    const ushort* __restrict__ Bbf = isXP ? Bbf1 : Bbf0;
    const int wr = (BM == 128) ? (w >> 1) * 64 : 0;
    const int wc = (BM == 128) ? (w & 1) * 64 : w * 32;
    const int sR = lane >> 3;
    const int sK = ((lane & 7) ^ sR) * 8;

    f32x4 acc[4][NI];
    #pragma unroll
    for (int i = 0; i < 4; ++i)
        #pragma unroll
        for (int j = 0; j < NI; ++j)
            acc[i][j] = (f32x4){0.f, 0.f, 0.f, 0.f};

    for (int kt = 0; kt < Kdim; kt += 64) {
        #pragma unroll
        for (int s = 0; s < SA; ++s) {
            int tr = w*8 + s*32 + sR;
            gld16(Abf + (size_t)(mBase + tr) * Kdim + kt + sK,
                  As + (w*8 + s*32) * 64);
        }
        #pragma unroll
        for (int s = 0; s < 4; ++s) {
            int tr = w*8 + s*32 + sR;
            int gr = isXP ? (tr < 63 ? tr : 63) : (nBase + tr);
            gld16(Bbf + (size_t)gr * Kdim + kt + sK,
                  Bs + (w*8 + s*32) * 64);
        }
        __syncthreads();
        #pragma unroll
        for (int kk = 0; kk < 2; ++kk) {
            short8 af[4], bfr[NI];
            #pragma unroll
            for (int f = 0; f < 4; ++f) {
                int ra = wr + f*16 + (lane & 15);
                int ca = (kk*4 + (lane >> 4)) ^ (ra & 7);
                af[f] = *(const short8*)(As + ra*64 + ca*8);
            }
            #pragma unroll
            for (int f = 0; f < NI; ++f) {
                int rb2 = wc + f*16 + (lane & 15);
                int cb2 = (kk*4 + (lane >> 4)) ^ (rb2 & 7);
                bfr[f] = *(const short8*)(Bs + rb2*64 + cb2*8);
            }
            #pragma unroll
            for (int mi = 0; mi < 4; ++mi)
                #pragma unroll
                for (int ni = 0; ni < NI; ++ni)
                    acc[mi][ni] = __builtin_amdgcn_mfma_f32_16x16x32_bf16(
                        af[mi], bfr[ni], acc[mi][ni], 0, 0, 0);
        }
        __syncthreads();
    }

    const int rb = (lane >> 4) * 4, cbl = lane & 15;
    #pragma unroll
    for (int mi = 0; mi < 4; ++mi) {
        #pragma unroll
        for (int ni = 0; ni < NI; ++ni) {
            int ltcol = wc + ni*16 + cbl;
            int col = nBase + ltcol;
            int row0 = mBase + wr + mi*16 + rb;
            if constexpr (MODE == 0) {
                #pragma unroll
                for (int j = 0; j < 4; ++j)
                    C0b[(size_t)(row0+j) * ldc + col] = bf16u(acc[mi][ni][j]);
            } else if constexpr (MODE == 1) {
                int b_ = row0 >> 10, trow = row0 & 1023;
                if (isXP) {
                    if (ltcol < NS) {
                        f32x4 v = acc[mi][ni];
                        *(f32x4*)(C1 + ((size_t)b_ * NS + ltcol) * L_DIM + trow) = v;
                    }
                } else {
                    ushort o[4];
                    #pragma unroll
                    for (int j = 0; j < 4; ++j) {
                        float z = acc[mi][ni][j] + bias[col];
                        float sp = (z > 20.f) ? z : logf(1.f + expf(z));
                        o[j] = bf16u(sp);
                    }
                    *(ushort4*)(C0b + ((size_t)b_ * DI + col) * L_DIM + trow) =
                        *(ushort4*)o;
                }
            } else {
                #pragma unroll
                for (int j = 0; j < 4; ++j)
                    C0[(size_t)(row0+j) * ldc + col] =
                        acc[mi][ni][j] + skip[(size_t)(row0+j) * ldc + col];
            }
        }
    }
}

// ----- fused causal conv1d(K=4)+SiLU -> xc row-major AND xct transposed ------
__global__ __launch_bounds__(256) void k_convt(const ushort* __restrict__ xrb,
    const float* __restrict__ cw, const float* __restrict__ cb,
    ushort* __restrict__ xcb, ushort* __restrict__ xct)
{
    __shared__ __align__(16) ushort in[68][72];   // rows 0..66 = t0-3..t0+63
    __shared__ __align__(16) ushort ot[64][72];   // conv output, swizzled
    const int dt_ = blockIdx.x;                   // d tile (32)
    const int tt_ = blockIdx.y;                   // t tile (16)
    const int b   = blockIdx.z;
    const int d0 = dt_ * 64, t0 = tt_ * 64;
    const int tx = threadIdx.x & 7, ty = threadIdx.x >> 3;   // 8 x 32
    const ushort* src = xrb + (size_t)b * L_DIM * (2*DI) + d0;

    // stage 67 rows (t0-3 .. t0+63); LDS row r = t index t0-3+r
    for (int r = threadIdx.x >> 3; r < 67; r += 32) {
        int tg = t0 - 3 + r;
        short8 v;
        if (tg < 0) {
            v = (short8){0,0,0,0,0,0,0,0};
        } else {
            v = *(const short8*)(src + (size_t)tg * (2*DI) + tx*8);
        }
        *(short8*)&in[r][tx*8] = v;
    }
    // conv weights for this thread's 8 d's
    float wj[4][8];
    float bias8[8];
    #pragma unroll
    for (int j = 0; j < 8; ++j) {
        int dg = d0 + tx*8 + j;
        bias8[j] = cb[dg];
        #pragma unroll
        for (int c = 0; c < 4; ++c) wj[c][j] = cw[(size_t)dg * 4 + c];
    }
    __syncthreads();

    #pragma unroll
    for (int p = 0; p < 2; ++p) {
        int r = ty + p*32;                        // local t index
        short8 x0 = *(const short8*)&in[r + 0][tx*8];   // t-3
        short8 x1 = *(const short8*)&in[r + 1][tx*8];   // t-2
        short8 x2 = *(const short8*)&in[r + 2][tx*8];   // t-1
        short8 x3 = *(const short8*)&in[r + 3][tx*8];   // t
        ushort o[8];
        #pragma unroll
        for (int j = 0; j < 8; ++j) {
            float a = bias8[j];
            a = fmaf(wj[0][j], bf2f(((const ushort*)&x0)[j]), a);
            a = fmaf(wj[1][j], bf2f(((const ushort*)&x1)[j]), a);
            a = fmaf(wj[2][j], bf2f(((const ushort*)&x2)[j]), a);
            a = fmaf(wj[3][j], bf2f(((const ushort*)&x3)[j]), a);
            a = a / (1.f + expf(-a));
            o[j] = bf16u(a);
        }
        // row-major write (for GEMM1 A)
        *(short8*)(xcb + ((size_t)(b * L_DIM + t0 + r) * DI) + d0 + tx*8) =
            *(short8*)o;
        // swizzled LDS stash for the transpose
        int g = tx ^ ((r >> 3) & 7);
        *(short8*)&ot[r][g*8] = *(short8*)o;
    }
    __syncthreads();
    #pragma unroll
    for (int p = 0; p < 2; ++p) {
        int crow = ty + p*32;                     // d index within tile
        ushort o[8];
        #pragma unroll
        for (int j = 0; j < 8; ++j)
            o[j] = ot[tx*8 + j][(((crow >> 3) ^ tx) << 3) + (crow & 7)];
        *(short8*)(xct + ((size_t)b * DI + d0 + crow) * L_DIM + t0 + tx*8) =
            *(short8*)o;
    }
}

// ------ back-transpose yt[b][d][t](bf16) -> y_bf[b*t][d], fused silu gate ----
__global__ __launch_bounds__(256) void k_trg(const ushort* __restrict__ yt,
    const ushort* __restrict__ xrb, ushort* __restrict__ ybf)
{
    __shared__ __align__(16) ushort tile[64][72];
    const int r0 = blockIdx.y * 64, c0 = blockIdx.x * 64;  // r: d, c: t
    const int z = blockIdx.z;
    const ushort* s = yt + (size_t)z * DI * L_DIM;
    const int tx = threadIdx.x & 7, ty = threadIdx.x >> 3;
    #pragma unroll
    for (int p = 0; p < 2; ++p) {
        int r = ty + p*32;
        short8 v = *(const short8*)(s + (size_t)(r0 + r) * L_DIM + c0 + tx*8);
        int g = tx ^ ((r >> 3) & 7);
        *(short8*)&tile[r][g*8] = v;
    }
    __syncthreads();
    #pragma unroll
    for (int p = 0; p < 2; ++p) {
        int crow = ty + p*32;                 // t index within tile
        int row = z * L_DIM + c0 + crow;      // global (b*t) row
        ushort4 gu0 = *(const ushort4*)(xrb + (size_t)row * (2*DI) + DI + r0 + tx*8);
        ushort4 gu1 = *(const ushort4*)(xrb + (size_t)row * (2*DI) + DI + r0 + tx*8 + 4);
        ushort o[8];
        #pragma unroll
        for (int j = 0; j < 8; ++j) {
            float yv = bf2f(tile[tx*8 + j][(((crow >> 3) ^ tx) << 3) + (crow & 7)]);
            float g = bf2f(j < 4 ? ((const ushort*)&gu0)[j] : ((const ushort*)&gu1)[j-4]);
            o[j] = bf16u(yv * g / (1.f + expf(-g)));
        }
        *(short8*)(ybf + (size_t)row * DI + r0 + tx*8) = *(short8*)o;
    }
}

__device__ __forceinline__ float exp2_fast(float x)
{
    float r;
    asm("v_exp_f32 %0, %1" : "=v"(r) : "v"(x));
    return r;
}

// ---------------- selective scan v11: BshT[n][t] + b128 B-reads --------------
__global__ __launch_bounds__(256) void k_scan11(const ushort* __restrict__ dtt,
    const ushort* __restrict__ xct, const float* __restrict__ BssT,
    const float* __restrict__ A_log, const float* __restrict__ Dp,
    ushort* __restrict__ yt)
{
    __shared__ __align__(16) float BshT[64][68];
    __shared__ __align__(16) float Psh[4][64][8];
    __shared__ __align__(16) float Dsh[4][64];
    __shared__ __align__(16) float Xsh[4][64];
    const int lane = threadIdx.x & 63;
    const int widx = threadIdx.x >> 6;
    const int b = blockIdx.x >> 9;
    const int d = (blockIdx.x & 511) * 4 + widx;
    const float aL2 = -expf(A_log[(size_t)d * NS + lane]) * 1.44269504f;
    const float Dv = Dp[d];
    const ushort* dtp = dtt + ((size_t)b * DI + d) * L_DIM;
    const ushort* xcp = xct + ((size_t)b * DI + d) * L_DIM;
    const float* BpT = BssT + ((size_t)b * NS + lane) * L_DIM;
    ushort* yp = yt + ((size_t)b * DI + d) * L_DIM;
    const int pg = lane >> 3;
    const bool pwrite = (lane & 7) == 7;
    float h = 0.f;

    for (int t0 = 0; t0 < L_DIM; t0 += 64) {
        const float* bsrc = BpT + t0 + widx*16;
        float4 b0 = *(const float4*)(bsrc);
        float4 b1 = *(const float4*)(bsrc + 4);
        float4 b2 = *(const float4*)(bsrc + 8);
        float4 b3 = *(const float4*)(bsrc + 12);
        float dt_v = bf2f(dtp[t0 + lane]);
        float xc_v = bf2f(xcp[t0 + lane]);
        __syncthreads();
        *(float4*)&BshT[lane][widx*16]      = b0;
        *(float4*)&BshT[lane][widx*16 + 4]  = b1;
        *(float4*)&BshT[lane][widx*16 + 8]  = b2;
        *(float4*)&BshT[lane][widx*16 + 12] = b3;
        Dsh[widx][lane] = dt_v;
        Xsh[widx][lane] = xc_v;
        __syncthreads();
        #pragma unroll
        for (int q = 0; q < 64; q += 4) {
            float4 dt4 = *(const float4*)&Dsh[widx][q];
            float4 xc4 = *(const float4*)&Xsh[widx][q];
            float4 Bq  = *(const float4*)&BshT[lane][q];
            float s0, s1, s2, s3;
            {
                float p, ad;
                p  = xc4.x * Bq.x;
                ad = exp2_fast(aL2 * dt4.x);
                h = fmaf(ad, h, p); s0 = h;
                p  = xc4.y * Bq.y;
                ad = exp2_fast(aL2 * dt4.y);
                h = fmaf(ad, h, p); s1 = h;
                p  = xc4.z * Bq.z;
                ad = exp2_fast(aL2 * dt4.z);
                h = fmaf(ad, h, p); s2 = h;
                p  = xc4.w * Bq.w;
                ad = exp2_fast(aL2 * dt4.w);
                h = fmaf(ad, h, p); s3 = h;
            }
            asm("v_add_f32_dpp %0, %0, %0 row_shr:1 row_mask:0xf bank_mask:0xf\n\t"
                "v_add_f32_dpp %1, %1, %1 row_shr:1 row_mask:0xf bank_mask:0xf\n\t"
                "v_add_f32_dpp %2, %2, %2 row_shr:1 row_mask:0xf bank_mask:0xf\n\t"
                "v_add_f32_dpp %3, %3, %3 row_shr:1 row_mask:0xf bank_mask:0xf\n\t"
                "v_add_f32_dpp %0, %0, %0 row_shr:2 row_mask:0xf bank_mask:0xf\n\t"
                "v_add_f32_dpp %1, %1, %1 row_shr:2 row_mask:0xf bank_mask:0xf\n\t"
                "v_add_f32_dpp %2, %2, %2 row_shr:2 row_mask:0xf bank_mask:0xf\n\t"
                "v_add_f32_dpp %3, %3, %3 row_shr:2 row_mask:0xf bank_mask:0xf\n\t"
                "v_add_f32_dpp %0, %0, %0 row_shr:4 row_mask:0xf bank_mask:0xf\n\t"
                "v_add_f32_dpp %1, %1, %1 row_shr:4 row_mask:0xf bank_mask:0xf\n\t"
                "v_add_f32_dpp %2, %2, %2 row_shr:4 row_mask:0xf bank_mask:0xf\n\t"
                "v_add_f32_dpp %3, %3, %3 row_shr:4 row_mask:0xf bank_mask:0xf"
                : "+v"(s0), "+v"(s1), "+v"(s2), "+v"(s3));
            if (pwrite) {
                Psh[widx][q+0][pg] = s0;
                Psh[widx][q+1][pg] = s1;
                Psh[widx][q+2][pg] = s2;
                Psh[widx][q+3][pg] = s3;
            }
        }
        asm volatile("s_waitcnt lgkmcnt(0)" ::: "memory");
        __builtin_amdgcn_sched_barrier(0);
        float4 p0 = *(const float4*)&Psh[widx][lane][0];
        float4 p1 = *(const float4*)&Psh[widx][lane][4];
        float sum = ((p0.x + p0.y) + (p0.z + p0.w))
                  + ((p1.x + p1.y) + (p1.z + p1.w));
        yp[t0 + lane] = bf16u(fmaf(Dv, xc_v, sum));
    }
}

extern "C" void kernel_launch(void* const* d_in, const int* in_sizes, int n_in,
                              void* d_out, int out_size, void* d_ws, size_t ws_size,
                              hipStream_t stream)
{
    const float* x        = (const float*)d_in[0];
    const float* norm_w   = (const float*)d_in[1];
    const float* in_projw = (const float*)d_in[2];
    const float* conv_w   = (const float*)d_in[3];
    const float* conv_b   = (const float*)d_in[4];
    const float* x_projw  = (const float*)d_in[5];
    const float* dt_w     = (const float*)d_in[6];
    const float* dt_b     = (const float*)d_in[7];
    const float* A_log    = (const float*)d_in[8];
    const float* D_param  = (const float*)d_in[9];
    const float* out_projw= (const float*)d_in[10];
    float* out = (float*)d_out;

    ushort* wsu = (ushort*)d_ws;
    ushort* xr_bf  = wsu;                                   // 8M u16
    ushort* xc_bf  = xr_bf + (size_t)8*1024*1024;           // 4M u16
    ushort* dtb_bf = xc_bf + (size_t)4*1024*1024;           // 4M u16 (yt alias)
    ushort* dtt_bf = dtb_bf + (size_t)4*1024*1024;          // 4M u16
    ushort* xct_bf = dtt_bf + (size_t)4*1024*1024;          // 4M u16
    ushort* xn_bf  = xct_bf + (size_t)4*1024*1024;          // 2M u16
    ushort* xpw_bf = xn_bf + (size_t)2*1024*1024;           // 128K u16
    ushort* opw_bf = xpw_bf + 131072;                       // 2M u16
    float*  BssT   = (float*)(opw_bf + (size_t)2*1024*1024); // 128K f32 [b][n][t]
    ushort* dtw_bf = (ushort*)(BssT + 131072);              // fresh 4M u16
    // aliases into dead regions:
    ushort* inpw_bf = dtt_bf;     // consumed by GEMM0, before GEMM1 writes dtt
    ushort* y_bf    = xc_bf;      // xc dead after GEMM1 (xct is separate now)
    ushort* yt_bf   = dtb_bf;     // scratch for scan output

    k_castw<<<5184, 256, 0, stream>>>(in_projw, inpw_bf, dt_w, dtw_bf,
                                      x_projw + (size_t)64*2048, xpw_bf,
                                      out_projw, opw_bf);
    k_rms_xn<<<2048, 256, 0, stream>>>(x, norm_w, xn_bf);
    k_mfma<0,128><<<dim3(32, 16), 256, 0, stream>>>(xn_bf, inpw_bf, nullptr,
                                                nullptr, xr_bf, nullptr,
                                                nullptr, nullptr, 1024, 4096);
    // fused conv+SiLU -> xc (row-major) + xct (transposed)
    k_convt<<<dim3(32, 16, 2), 256, 0, stream>>>(xr_bf, conv_w, conv_b,
                                                 xc_bf, xct_bf);
    // GEMM1: dt transposed bf16 into dtt_bf[b][d][t]; B transposed f32 BssT
    k_mfma<1,128><<<dim3(17, 16), 256, 0, stream>>>(xc_bf, dtw_bf, xpw_bf,
                                                nullptr, dtt_bf, BssT,
                                                dt_b, nullptr, 2048, 2048);
    k_scan11<<<1024, 256, 0, stream>>>(dtt_bf, xct_bf, BssT, A_log, D_param, yt_bf);
    k_trg<<<dim3(16, 32, 2), 256, 0, stream>>>(yt_bf, xr_bf, y_bf);
    k_mfma<2,64><<<dim3(8, 32), 256, 0, stream>>>(y_bf, opw_bf, nullptr,
                                               out, nullptr, nullptr,
                                               nullptr, x, 2048, 1024);
}